// Round 1
// baseline (1201.103 us; speedup 1.0000x reference)
//
#include <hip/hip_runtime.h>
#include <hip/hip_bf16.h>

// Sizes are fixed by the problem.
#define NROWS   16384
#define IN_DIM  1024
#define ENC_DIM 256
#define KCW     8192
#define NSTRIPS 8

// ---------------------------------------------------------------------------
// Generic tiled fp32 GEMM: C[M,N] = act(A[M,K] @ B[K,N] + bias[N])
// 128x128 tile, BK=8, 256 threads, 8x8 micro-tile per thread (split 4+4).
// ---------------------------------------------------------------------------
template<int RELU>
__global__ __launch_bounds__(256)
void gemm_bias(const float* __restrict__ A, const float* __restrict__ B,
               const float* __restrict__ bias, float* __restrict__ C,
               int M, int K, int N) {
    __shared__ __align__(16) float As[8][128];
    __shared__ __align__(16) float Bs[8][128];
    const int tid = threadIdx.x;
    const int tx = tid & 15;   // column group 0..15
    const int ty = tid >> 4;   // row group 0..15
    const int brow = blockIdx.y * 128;
    const int bcol = blockIdx.x * 128;

    float acc[8][8];
#pragma unroll
    for (int i = 0; i < 8; i++)
#pragma unroll
        for (int j = 0; j < 8; j++) acc[i][j] = 0.f;

    const int lrowA = tid >> 1;        // 0..127
    const int lkA   = (tid & 1) * 4;   // 0 or 4
    const int lkB   = tid >> 5;        // 0..7
    const int lcolB = (tid & 31) * 4;  // 0..124

    for (int k0 = 0; k0 < K; k0 += 8) {
        float4 a4 = *(const float4*)(A + (size_t)(brow + lrowA) * K + k0 + lkA);
        float4 b4 = *(const float4*)(B + (size_t)(k0 + lkB) * N + bcol + lcolB);
        As[lkA + 0][lrowA] = a4.x;
        As[lkA + 1][lrowA] = a4.y;
        As[lkA + 2][lrowA] = a4.z;
        As[lkA + 3][lrowA] = a4.w;
        *(float4*)&Bs[lkB][lcolB] = b4;
        __syncthreads();
#pragma unroll
        for (int k = 0; k < 8; k++) {
            float ar[8], br[8];
            *(float4*)&ar[0] = *(const float4*)&As[k][ty * 4];
            *(float4*)&ar[4] = *(const float4*)&As[k][64 + ty * 4];
            *(float4*)&br[0] = *(const float4*)&Bs[k][tx * 4];
            *(float4*)&br[4] = *(const float4*)&Bs[k][64 + tx * 4];
#pragma unroll
            for (int i = 0; i < 8; i++)
#pragma unroll
                for (int j = 0; j < 8; j++)
                    acc[i][j] = fmaf(ar[i], br[j], acc[i][j]);
        }
        __syncthreads();
    }

#pragma unroll
    for (int i = 0; i < 8; i++) {
        int row = brow + ((i < 4) ? (ty * 4 + i) : (64 + ty * 4 + i - 4));
#pragma unroll
        for (int jh = 0; jh < 2; jh++) {
            int col = bcol + ((jh == 0) ? tx * 4 : 64 + tx * 4);
            float4 b4 = *(const float4*)(bias + col);
            float4 v;
            v.x = acc[i][jh * 4 + 0] + b4.x;
            v.y = acc[i][jh * 4 + 1] + b4.y;
            v.z = acc[i][jh * 4 + 2] + b4.z;
            v.w = acc[i][jh * 4 + 3] + b4.w;
            if (RELU) {
                v.x = fmaxf(v.x, 0.f); v.y = fmaxf(v.y, 0.f);
                v.z = fmaxf(v.z, 0.f); v.w = fmaxf(v.w, 0.f);
            }
            *(float4*)(C + (size_t)row * N + col) = v;
        }
    }
}

// ---------------------------------------------------------------------------
// Row squared-norms (256-wide rows): one wave per row, balanced binary tree.
// ---------------------------------------------------------------------------
__global__ void rownorm2(const float* __restrict__ A, float* __restrict__ out,
                         int rows) {
    int gid = blockIdx.x * blockDim.x + threadIdx.x;
    int wid = gid >> 6, lane = gid & 63;
    if (wid >= rows) return;
    float4 v = *(const float4*)(A + (size_t)wid * 256 + lane * 4);
    float s = (v.x * v.x + v.y * v.y) + (v.z * v.z + v.w * v.w);
#pragma unroll
    for (int off = 1; off < 64; off <<= 1) s += __shfl_xor(s, off);
    if (lane == 0) out[wid] = s;
}

// ---------------------------------------------------------------------------
// VQ: for each row of enc, running lex-min of (dist, index) over a strip of
// codewords. GEMM-structured: 128 rows x 128 cw tiles, K=256 reduction.
// dist computed exactly as reference: sqrt(max((x2+c2) - 2*dot, 0)).
// ---------------------------------------------------------------------------
__global__ __launch_bounds__(256)
void vq_kernel(const float* __restrict__ enc, const float* __restrict__ cw,
               const float* __restrict__ c2, const float* __restrict__ x2,
               float* __restrict__ part_d, int* __restrict__ part_i) {
    __shared__ __align__(16) float As[8][128];
    __shared__ __align__(16) float Bs[8][128];
    __shared__ float rd[128][17];
    __shared__ int   ri[128][17];
    const int tid = threadIdx.x;
    const int tx = tid & 15, ty = tid >> 4;
    const int strip = blockIdx.x;          // 0..7, each 1024 codewords
    const int brow = blockIdx.y * 128;
    const int lrow = tid >> 1;
    const int lk = (tid & 1) * 4;

    float bestd[8];
    int   besti[8];
    float myx2[8];
#pragma unroll
    for (int i = 0; i < 8; i++) {
        bestd[i] = 3.4e38f;
        besti[i] = 0x7fffffff;
        int r = (i < 4) ? (ty * 4 + i) : (64 + ty * 4 + i - 4);
        myx2[i] = x2[brow + r];
    }

    for (int t = 0; t < 8; ++t) {
        const int cwBase = strip * 1024 + t * 128;
        float acc[8][8];
#pragma unroll
        for (int i = 0; i < 8; i++)
#pragma unroll
            for (int j = 0; j < 8; j++) acc[i][j] = 0.f;

        for (int k0 = 0; k0 < 256; k0 += 8) {
            float4 a4 = *(const float4*)(enc + (size_t)(brow + lrow) * 256 + k0 + lk);
            float4 b4 = *(const float4*)(cw + (size_t)(cwBase + lrow) * 256 + k0 + lk);
            As[lk + 0][lrow] = a4.x;
            As[lk + 1][lrow] = a4.y;
            As[lk + 2][lrow] = a4.z;
            As[lk + 3][lrow] = a4.w;
            Bs[lk + 0][lrow] = b4.x;
            Bs[lk + 1][lrow] = b4.y;
            Bs[lk + 2][lrow] = b4.z;
            Bs[lk + 3][lrow] = b4.w;
            __syncthreads();
#pragma unroll
            for (int k = 0; k < 8; k++) {
                float ar[8], br[8];
                *(float4*)&ar[0] = *(const float4*)&As[k][ty * 4];
                *(float4*)&ar[4] = *(const float4*)&As[k][64 + ty * 4];
                *(float4*)&br[0] = *(const float4*)&Bs[k][tx * 4];
                *(float4*)&br[4] = *(const float4*)&Bs[k][64 + tx * 4];
#pragma unroll
                for (int i = 0; i < 8; i++)
#pragma unroll
                    for (int j = 0; j < 8; j++)
                        acc[i][j] = fmaf(ar[i], br[j], acc[i][j]);
            }
            __syncthreads();
        }

#pragma unroll
        for (int j = 0; j < 8; j++) {
            int c = cwBase + ((j < 4) ? (tx * 4 + j) : (64 + tx * 4 + j - 4));
            float c2v = c2[c];
#pragma unroll
            for (int i = 0; i < 8; i++) {
                float d2 = (myx2[i] + c2v) - 2.0f * acc[i][j];
                float dist = sqrtf(fmaxf(d2, 0.f));
                if (dist < bestd[i] || (dist == bestd[i] && c < besti[i])) {
                    bestd[i] = dist;
                    besti[i] = c;
                }
            }
        }
    }

#pragma unroll
    for (int i = 0; i < 8; i++) {
        int r = (i < 4) ? (ty * 4 + i) : (64 + ty * 4 + i - 4);
        rd[r][tx] = bestd[i];
        ri[r][tx] = besti[i];
    }
    __syncthreads();
    if (tid < 128) {
        float bd = rd[tid][0];
        int bi = ri[tid][0];
#pragma unroll
        for (int s = 1; s < 16; s++) {
            float d = rd[tid][s];
            int ii = ri[tid][s];
            if (d < bd || (d == bd && ii < bi)) { bd = d; bi = ii; }
        }
        part_d[(size_t)strip * NROWS + brow + tid] = bd;
        part_i[(size_t)strip * NROWS + brow + tid] = bi;
    }
}

// ---------------------------------------------------------------------------
// Combine strip partials; emit index (as float), distance, and int index.
// ---------------------------------------------------------------------------
__global__ void vq_combine(const float* __restrict__ part_d,
                           const int* __restrict__ part_i,
                           float* __restrict__ outIdx,
                           float* __restrict__ outDist,
                           int* __restrict__ idx32) {
    int r = blockIdx.x * blockDim.x + threadIdx.x;
    if (r >= NROWS) return;
    float bd = part_d[r];
    int bi = part_i[r];
#pragma unroll
    for (int s = 1; s < NSTRIPS; s++) {
        float d = part_d[(size_t)s * NROWS + r];
        int ii = part_i[(size_t)s * NROWS + r];
        if (d < bd || (d == bd && ii < bi)) { bd = d; bi = ii; }
    }
    outIdx[r] = (float)bi;
    outDist[r] = bd;
    idx32[r] = bi;
}

// ---------------------------------------------------------------------------
// Gather decoded codewords + codewords into the output rows.
// One block per row: 256 threads copy 1024 floats (rec) + 256 floats (quant).
// ---------------------------------------------------------------------------
__global__ void gather_out(const int* __restrict__ idx32,
                           const float* __restrict__ rec_all,
                           const float* __restrict__ cw,
                           float* __restrict__ outRec,
                           float* __restrict__ outQ) {
    int row = blockIdx.x;
    int j = idx32[row];
    const float4* src = (const float4*)(rec_all + (size_t)j * IN_DIM);
    float4* dst = (float4*)(outRec + (size_t)row * IN_DIM);
    dst[threadIdx.x] = src[threadIdx.x];
    if (threadIdx.x < 64) {
        ((float4*)(outQ + (size_t)row * ENC_DIM))[threadIdx.x] =
            ((const float4*)(cw + (size_t)j * ENC_DIM))[threadIdx.x];
    }
}

extern "C" void kernel_launch(void* const* d_in, const int* in_sizes, int n_in,
                              void* d_out, int out_size, void* d_ws, size_t ws_size,
                              hipStream_t stream) {
    const float* x   = (const float*)d_in[0];
    const float* ew1 = (const float*)d_in[1];
    const float* eb1 = (const float*)d_in[2];
    const float* ew2 = (const float*)d_in[3];
    const float* eb2 = (const float*)d_in[4];
    const float* cw  = (const float*)d_in[5];
    const float* dw1 = (const float*)d_in[6];
    const float* db1 = (const float*)d_in[7];
    const float* dw2 = (const float*)d_in[8];
    const float* db2 = (const float*)d_in[9];
    float* out = (float*)d_out;
    float* ws  = (float*)d_ws;

    // workspace layout (floats)
    float* h       = ws;                    // 16384*256 = 4,194,304
    float* enc     = ws + 4194304;          // 4,194,304
    float* g_all   = ws + 8388608;          // 8192*256 = 2,097,152
    float* rec_all = ws + 10485760;         // 8192*1024 = 8,388,608
    float* c2      = ws + 18874368;         // 8192
    float* x2      = ws + 18882560;         // 16384
    float* part_d  = ws + 18898944;         // 8*16384 = 131072
    int*   idx32   = (int*)(ws + 19030016); // 16384
    int*   part_i  = (int*)(ws + 19046400); // 131072
    // total: 19,177,472 floats = 76.7 MB

    // output layout (floats): [idx(N)][dist(N)][rec(N*1024)][quant(N*256)]
    float* outIdx  = out;
    float* outDist = out + NROWS;
    float* outRec  = out + 2 * NROWS;
    float* outQ    = out + 2 * NROWS + (size_t)NROWS * IN_DIM;

    // Encoder
    gemm_bias<1><<<dim3(2, 128), 256, 0, stream>>>(x, ew1, eb1, h, NROWS, IN_DIM, ENC_DIM);
    gemm_bias<1><<<dim3(2, 128), 256, 0, stream>>>(h, ew2, eb2, enc, NROWS, ENC_DIM, ENC_DIM);

    // Norms
    rownorm2<<<KCW / 4, 256, 0, stream>>>(cw, c2, KCW);
    rownorm2<<<NROWS / 4, 256, 0, stream>>>(enc, x2, NROWS);

    // VQ argmin (8 strips x 128 row-tiles)
    vq_kernel<<<dim3(NSTRIPS, 128), 256, 0, stream>>>(enc, cw, c2, x2, part_d, part_i);
    vq_combine<<<NROWS / 256, 256, 0, stream>>>(part_d, part_i, outIdx, outDist, idx32);

    // Decoder over the 8192 codewords (cheaper than over 16384 rows)
    gemm_bias<1><<<dim3(2, 64), 256, 0, stream>>>(cw, dw1, db1, g_all, KCW, ENC_DIM, ENC_DIM);
    gemm_bias<0><<<dim3(8, 64), 256, 0, stream>>>(g_all, dw2, db2, rec_all, KCW, ENC_DIM, IN_DIM);

    // Gather final outputs
    gather_out<<<NROWS, 256, 0, stream>>>(idx32, rec_all, cw, outRec, outQ);
}

// Round 2
// 793.228 us; speedup vs baseline: 1.5142x; 1.5142x over previous
//
#include <hip/hip_runtime.h>
#include <hip/hip_bf16.h>

#define NROWS   16384
#define IN_DIM  1024
#define ENC_DIM 256
#define KCW     8192
#define NCB     64          // codeword col-blocks of 128

typedef __attribute__((ext_vector_type(8))) short short8v;
typedef __attribute__((ext_vector_type(4))) float f32x4;

// ---------------------------------------------------------------------------
// fp32 tiled GEMM (unchanged from round 1): C = act(A@B + bias)
// ---------------------------------------------------------------------------
template<int RELU>
__global__ __launch_bounds__(256)
void gemm_bias(const float* __restrict__ A, const float* __restrict__ B,
               const float* __restrict__ bias, float* __restrict__ C,
               int M, int K, int N) {
    __shared__ __align__(16) float As[8][128];
    __shared__ __align__(16) float Bs[8][128];
    const int tid = threadIdx.x;
    const int tx = tid & 15;
    const int ty = tid >> 4;
    const int brow = blockIdx.y * 128;
    const int bcol = blockIdx.x * 128;

    float acc[8][8];
#pragma unroll
    for (int i = 0; i < 8; i++)
#pragma unroll
        for (int j = 0; j < 8; j++) acc[i][j] = 0.f;

    const int lrowA = tid >> 1;
    const int lkA   = (tid & 1) * 4;
    const int lkB   = tid >> 5;
    const int lcolB = (tid & 31) * 4;

    for (int k0 = 0; k0 < K; k0 += 8) {
        float4 a4 = *(const float4*)(A + (size_t)(brow + lrowA) * K + k0 + lkA);
        float4 b4 = *(const float4*)(B + (size_t)(k0 + lkB) * N + bcol + lcolB);
        As[lkA + 0][lrowA] = a4.x;
        As[lkA + 1][lrowA] = a4.y;
        As[lkA + 2][lrowA] = a4.z;
        As[lkA + 3][lrowA] = a4.w;
        *(float4*)&Bs[lkB][lcolB] = b4;
        __syncthreads();
#pragma unroll
        for (int k = 0; k < 8; k++) {
            float ar[8], br[8];
            *(float4*)&ar[0] = *(const float4*)&As[k][ty * 4];
            *(float4*)&ar[4] = *(const float4*)&As[k][64 + ty * 4];
            *(float4*)&br[0] = *(const float4*)&Bs[k][tx * 4];
            *(float4*)&br[4] = *(const float4*)&Bs[k][64 + tx * 4];
#pragma unroll
            for (int i = 0; i < 8; i++)
#pragma unroll
                for (int j = 0; j < 8; j++)
                    acc[i][j] = fmaf(ar[i], br[j], acc[i][j]);
        }
        __syncthreads();
    }

#pragma unroll
    for (int i = 0; i < 8; i++) {
        int row = brow + ((i < 4) ? (ty * 4 + i) : (64 + ty * 4 + i - 4));
#pragma unroll
        for (int jh = 0; jh < 2; jh++) {
            int col = bcol + ((jh == 0) ? tx * 4 : 64 + tx * 4);
            float4 b4 = *(const float4*)(bias + col);
            float4 v;
            v.x = acc[i][jh * 4 + 0] + b4.x;
            v.y = acc[i][jh * 4 + 1] + b4.y;
            v.z = acc[i][jh * 4 + 2] + b4.z;
            v.w = acc[i][jh * 4 + 3] + b4.w;
            if (RELU) {
                v.x = fmaxf(v.x, 0.f); v.y = fmaxf(v.y, 0.f);
                v.z = fmaxf(v.z, 0.f); v.w = fmaxf(v.w, 0.f);
            }
            *(float4*)(C + (size_t)row * N + col) = v;
        }
    }
}

// ---------------------------------------------------------------------------
// Row squared-norms (256-wide rows)
// ---------------------------------------------------------------------------
__global__ void rownorm2(const float* __restrict__ A, float* __restrict__ out,
                         int rows) {
    int gid = blockIdx.x * blockDim.x + threadIdx.x;
    int wid = gid >> 6, lane = gid & 63;
    if (wid >= rows) return;
    float4 v = *(const float4*)(A + (size_t)wid * 256 + lane * 4);
    float s = (v.x * v.x + v.y * v.y) + (v.z * v.z + v.w * v.w);
#pragma unroll
    for (int off = 1; off < 64; off <<= 1) s += __shfl_xor(s, off);
    if (lane == 0) out[wid] = s;
}

// ---------------------------------------------------------------------------
// Split fp32 [rows][256] into bf16 hi|lo [rows][512]  (dst[r][k]=hi, [r][256+k]=lo)
// ---------------------------------------------------------------------------
__device__ __forceinline__ unsigned short f2bf_rne(float x) {
    unsigned u = __float_as_uint(x);
    unsigned r = (u + 0x7fffu + ((u >> 16) & 1u)) >> 16;
    return (unsigned short)r;
}
__device__ __forceinline__ float bf2f(unsigned short h) {
    return __uint_as_float(((unsigned)h) << 16);
}

__global__ void split_bf16(const float* __restrict__ src,
                           unsigned short* __restrict__ dst, int n4) {
    int e = blockIdx.x * 256 + threadIdx.x;   // float4 index
    if (e >= n4) return;
    int row = e >> 6, kq = (e & 63) * 4;
    float4 v = ((const float4*)src)[e];
    ushort4 hi, lo;
    hi.x = f2bf_rne(v.x); lo.x = f2bf_rne(v.x - bf2f(hi.x));
    hi.y = f2bf_rne(v.y); lo.y = f2bf_rne(v.y - bf2f(hi.y));
    hi.z = f2bf_rne(v.z); lo.z = f2bf_rne(v.z - bf2f(hi.z));
    hi.w = f2bf_rne(v.w); lo.w = f2bf_rne(v.w - bf2f(hi.w));
    *(ushort4*)&dst[(size_t)row * 512 + kq]       = hi;
    *(ushort4*)&dst[(size_t)row * 512 + 256 + kq] = lo;
}

// ---------------------------------------------------------------------------
// top-2 helpers: lexicographic (d, idx) order
// ---------------------------------------------------------------------------
__device__ __forceinline__ int lex_lt(float d, int i, float D, int I) {
    return (d < D) || (d == D && i < I);
}
// merge ordered pair (c1,k1)<=(c2,k2) into ordered state (b1,j1,b2,j2)
__device__ __forceinline__ void top2_merge(float& b1, int& j1, float& b2, int& j2,
                                           float c1, int k1, float c2, int k2) {
    if (lex_lt(c1, k1, b1, j1)) {
        float nb2; int nj2;
        if (lex_lt(b1, j1, c2, k2)) { nb2 = b1; nj2 = j1; }
        else                        { nb2 = c2; nj2 = k2; }
        b1 = c1; j1 = k1; b2 = nb2; j2 = nj2;
    } else {
        if (lex_lt(c1, k1, b2, j2)) { b2 = c1; j2 = k1; }
    }
}

__device__ __forceinline__ void gload16(const void* g, void* l) {
    __builtin_amdgcn_global_load_lds(
        (__attribute__((address_space(1))) void*)g,
        (__attribute__((address_space(3))) void*)l, 16, 0, 0);
}

// ---------------------------------------------------------------------------
// VQ MFMA kernel: approx d2-key GEMM (3-term split bf16, K'=768) + per-row
// per-colblock top-2.  Ranking key = c2 - 2*dot (x2 & sqrt omitted: per-row
// constant / monotone; exact rescore happens in combine).
// grid = (64 colblocks, 128 rowblocks), 256 threads (4 waves, 2x2 of 64x64).
// ---------------------------------------------------------------------------
__global__ __launch_bounds__(256)
void vq_mfma(const unsigned short* __restrict__ Ae,
             const unsigned short* __restrict__ Be,
             const float* __restrict__ c2,
             float4* __restrict__ part) {
    __shared__ __align__(16) unsigned short As[128][64];
    __shared__ __align__(16) unsigned short Bs[128][64];
    __shared__ float sd1[128][2]; __shared__ int si1[128][2];
    __shared__ float sd2[128][2]; __shared__ int si2[128][2];

    const int tid  = threadIdx.x;
    const int lane = tid & 63;
    const int wid  = tid >> 6;
    const int wr   = wid >> 1, wc = wid & 1;
    const int brow = blockIdx.y * 128;
    const int bcol = blockIdx.x * 128;

    f32x4 acc[4][4] = {};

    const int flat_r[4] = { (0 * 2048 + tid * 8) >> 6, (1 * 2048 + tid * 8) >> 6,
                            (2 * 2048 + tid * 8) >> 6, (3 * 2048 + tid * 8) >> 6 };
    const int flat_k = (tid * 8) & 63;

    for (int ks = 0; ks < 12; ++ks) {
        const int term = ks >> 2, kq = ks & 3;
        const int ka0 = (term == 2 ? 256 : 0) + kq * 64;
        const int kb0 = (term == 1 ? 256 : 0) + kq * 64;
#pragma unroll
        for (int l = 0; l < 4; ++l) {
            gload16(Ae + (size_t)(brow + flat_r[l]) * 512 + ka0 + flat_k,
                    (char*)&As[0][0] + l * 4096 + tid * 16);
            gload16(Be + (size_t)(bcol + flat_r[l]) * 512 + kb0 + flat_k,
                    (char*)&Bs[0][0] + l * 4096 + tid * 16);
        }
        __syncthreads();
        const int arow = wr * 64 + (lane & 15);
        const int brw  = wc * 64 + (lane & 15);
        const int koff = (lane >> 4) * 8;
#pragma unroll
        for (int kk = 0; kk < 2; ++kk) {
            short8v af[4], bfv[4];
#pragma unroll
            for (int mi = 0; mi < 4; mi++)
                af[mi] = *(const short8v*)&As[arow + mi * 16][kk * 32 + koff];
#pragma unroll
            for (int ni = 0; ni < 4; ni++)
                bfv[ni] = *(const short8v*)&Bs[brw + ni * 16][kk * 32 + koff];
#pragma unroll
            for (int mi = 0; mi < 4; mi++)
#pragma unroll
                for (int ni = 0; ni < 4; ni++)
                    acc[mi][ni] = __builtin_amdgcn_mfma_f32_16x16x32_bf16(
                        af[mi], bfv[ni], acc[mi][ni], 0, 0, 0);
        }
        __syncthreads();
    }

    // ---- epilogue: per-row top-2 over this block's 128 cols ----
    float c2v[4];
#pragma unroll
    for (int ni = 0; ni < 4; ni++)
        c2v[ni] = c2[bcol + wc * 64 + ni * 16 + (lane & 15)];

#pragma unroll
    for (int mi = 0; mi < 4; mi++) {
#pragma unroll
        for (int q = 0; q < 4; q++) {
            float b1 = 3.4e38f, b2 = 3.4e38f;
            int   j1 = 0x7fffffff, j2 = 0x7fffffff;
#pragma unroll
            for (int ni = 0; ni < 4; ni++) {
                float dk  = fmaf(-2.0f, acc[mi][ni][q], c2v[ni]);
                int   col = bcol + wc * 64 + ni * 16 + (lane & 15);
                if (lex_lt(dk, col, b1, j1)) { b2 = b1; j2 = j1; b1 = dk; j1 = col; }
                else if (lex_lt(dk, col, b2, j2)) { b2 = dk; j2 = col; }
            }
#pragma unroll
            for (int off = 1; off < 16; off <<= 1) {
                float c1 = __shfl_xor(b1, off); int k1 = __shfl_xor(j1, off);
                float cc2 = __shfl_xor(b2, off); int k2 = __shfl_xor(j2, off);
                top2_merge(b1, j1, b2, j2, c1, k1, cc2, k2);
            }
            if ((lane & 15) == 0) {
                int rl = wr * 64 + mi * 16 + (lane >> 4) * 4 + q;
                sd1[rl][wc] = b1; si1[rl][wc] = j1;
                sd2[rl][wc] = b2; si2[rl][wc] = j2;
            }
        }
    }
    __syncthreads();
    if (tid < 128) {
        float b1 = sd1[tid][0], b2 = sd2[tid][0];
        int   j1 = si1[tid][0], j2 = si2[tid][0];
        top2_merge(b1, j1, b2, j2, sd1[tid][1], si1[tid][1], sd2[tid][1], si2[tid][1]);
        float4 pk;
        pk.x = b1; pk.y = __int_as_float(j1);
        pk.z = b2; pk.w = __int_as_float(j2);
        part[(size_t)(brow + tid) * NCB + blockIdx.x] = pk;
    }
}

// ---------------------------------------------------------------------------
// Combine per-colblock top-2s -> global approx top-2 -> exact fp32 rescore
// (reference math: dist = sqrt(max(x2 + c2 - 2*dot, 0)), lex tie-break).
// One wave per row.
// ---------------------------------------------------------------------------
__global__ __launch_bounds__(256)
void vq_combine_rescore(const float4* __restrict__ part,
                        const float* __restrict__ enc,
                        const float* __restrict__ cw,
                        const float* __restrict__ c2,
                        const float* __restrict__ x2,
                        float* __restrict__ outIdx,
                        float* __restrict__ outDist,
                        int* __restrict__ idx32) {
    const int row  = blockIdx.x * 4 + (threadIdx.x >> 6);
    const int lane = threadIdx.x & 63;

    float4 pk = part[(size_t)row * NCB + lane];
    float b1 = pk.x, b2 = pk.z;
    int   j1 = __float_as_int(pk.y), j2 = __float_as_int(pk.w);
#pragma unroll
    for (int off = 1; off < 64; off <<= 1) {
        float c1 = __shfl_xor(b1, off); int k1 = __shfl_xor(j1, off);
        float cc2 = __shfl_xor(b2, off); int k2 = __shfl_xor(j2, off);
        top2_merge(b1, j1, b2, j2, c1, k1, cc2, k2);
    }

    // exact fp32 rescore of j1, j2
    float4 e4 = ((const float4*)(enc + (size_t)row * 256))[lane];
    float4 w1 = ((const float4*)(cw + (size_t)j1 * 256))[lane];
    float4 w2 = ((const float4*)(cw + (size_t)j2 * 256))[lane];
    float s1 = fmaf(e4.x, w1.x, fmaf(e4.y, w1.y, fmaf(e4.z, w1.z, e4.w * w1.w)));
    float s2 = fmaf(e4.x, w2.x, fmaf(e4.y, w2.y, fmaf(e4.z, w2.z, e4.w * w2.w)));
#pragma unroll
    for (int off = 1; off < 64; off <<= 1) {
        s1 += __shfl_xor(s1, off);
        s2 += __shfl_xor(s2, off);
    }
    float xv = x2[row];
    float d1 = sqrtf(fmaxf(xv + c2[j1] - 2.0f * s1, 0.f));
    float d2 = sqrtf(fmaxf(xv + c2[j2] - 2.0f * s2, 0.f));
    float bd; int bi;
    if (lex_lt(d1, j1, d2, j2)) { bd = d1; bi = j1; }
    else                        { bd = d2; bi = j2; }
    if (lane == 0) {
        outIdx[row]  = (float)bi;
        outDist[row] = bd;
        idx32[row]   = bi;
    }
}

// ---------------------------------------------------------------------------
// Gather decoded codewords + codewords into output rows.
// ---------------------------------------------------------------------------
__global__ void gather_out(const int* __restrict__ idx32,
                           const float* __restrict__ rec_all,
                           const float* __restrict__ cw,
                           float* __restrict__ outRec,
                           float* __restrict__ outQ) {
    int row = blockIdx.x;
    int j = idx32[row];
    const float4* src = (const float4*)(rec_all + (size_t)j * IN_DIM);
    float4* dst = (float4*)(outRec + (size_t)row * IN_DIM);
    dst[threadIdx.x] = src[threadIdx.x];
    if (threadIdx.x < 64) {
        ((float4*)(outQ + (size_t)row * ENC_DIM))[threadIdx.x] =
            ((const float4*)(cw + (size_t)j * ENC_DIM))[threadIdx.x];
    }
}

extern "C" void kernel_launch(void* const* d_in, const int* in_sizes, int n_in,
                              void* d_out, int out_size, void* d_ws, size_t ws_size,
                              hipStream_t stream) {
    const float* x   = (const float*)d_in[0];
    const float* ew1 = (const float*)d_in[1];
    const float* eb1 = (const float*)d_in[2];
    const float* ew2 = (const float*)d_in[3];
    const float* eb2 = (const float*)d_in[4];
    const float* cw  = (const float*)d_in[5];
    const float* dw1 = (const float*)d_in[6];
    const float* db1 = (const float*)d_in[7];
    const float* dw2 = (const float*)d_in[8];
    const float* db2 = (const float*)d_in[9];
    float* out = (float*)d_out;
    float* ws  = (float*)d_ws;

    // workspace layout (float offsets), with aliasing:
    //  [0,        4194304)  h (enc1 out)      -> later: part float4[16384*64] -> later rec_all lo
    //  [4194304,  8388608)  enc               -> later rec_all hi
    //  [8388608, 12582912)  Ae bf16[16384*512]-> later g_all (first 2097152 f)
    //  [12582912,14680064)  Be bf16[8192*512]
    //  [14680064, ...)      c2, x2, idx32
    float*          h       = ws;
    float4*         part    = (float4*)ws;
    float*          rec_all = ws;                       // [0, 8388608)
    float*          enc     = ws + 4194304;
    unsigned short* Ae      = (unsigned short*)(ws + 8388608);
    float*          g_all   = ws + 8388608;
    unsigned short* Be      = (unsigned short*)(ws + 12582912);
    float*          c2      = ws + 14680064;
    float*          x2      = ws + 14688256;
    int*            idx32   = (int*)(ws + 14704640);

    float* outIdx  = out;
    float* outDist = out + NROWS;
    float* outRec  = out + 2 * NROWS;
    float* outQ    = out + 2 * NROWS + (size_t)NROWS * IN_DIM;

    // Encoder (fp32)
    gemm_bias<1><<<dim3(2, 128), 256, 0, stream>>>(x, ew1, eb1, h, NROWS, IN_DIM, ENC_DIM);
    gemm_bias<1><<<dim3(2, 128), 256, 0, stream>>>(h, ew2, eb2, enc, NROWS, ENC_DIM, ENC_DIM);

    // Norms (fp32, reference-matching)
    rownorm2<<<KCW / 4, 256, 0, stream>>>(cw, c2, KCW);
    rownorm2<<<NROWS / 4, 256, 0, stream>>>(enc, x2, NROWS);

    // Split into bf16 hi|lo
    split_bf16<<<(NROWS * 64) / 256, 256, 0, stream>>>(enc, Ae, NROWS * 64);
    split_bf16<<<(KCW * 64) / 256, 256, 0, stream>>>(cw, Be, KCW * 64);

    // VQ approx (MFMA) + exact rescore
    vq_mfma<<<dim3(NCB, 128), 256, 0, stream>>>(Ae, Be, c2, part);
    vq_combine_rescore<<<NROWS / 4, 256, 0, stream>>>(part, enc, cw, c2, x2,
                                                      outIdx, outDist, idx32);

    // Decoder over codewords (fp32) — after combine (aliases dead regions)
    gemm_bias<1><<<dim3(2, 64), 256, 0, stream>>>(cw, dw1, db1, g_all, KCW, ENC_DIM, ENC_DIM);
    gemm_bias<0><<<dim3(8, 64), 256, 0, stream>>>(g_all, dw2, db2, rec_all, KCW, ENC_DIM, IN_DIM);

    // Gather final outputs
    gather_out<<<NROWS, 256, 0, stream>>>(idx32, rec_all, cw, outRec, outQ);
}

// Round 3
// 703.366 us; speedup vs baseline: 1.7076x; 1.1278x over previous
//
#include <hip/hip_runtime.h>
#include <hip/hip_bf16.h>

#define NROWS   16384
#define IN_DIM  1024
#define ENC_DIM 256
#define KCW     8192
#define NCB     64          // codeword col-blocks of 128

typedef __attribute__((ext_vector_type(8))) short short8v;
typedef __attribute__((ext_vector_type(4))) float f32x4;

// ---------------------------------------------------------------------------
// fp32 tiled GEMM: C = act(A@B + bias)
// ---------------------------------------------------------------------------
template<int RELU>
__global__ __launch_bounds__(256)
void gemm_bias(const float* __restrict__ A, const float* __restrict__ B,
               const float* __restrict__ bias, float* __restrict__ C,
               int M, int K, int N) {
    __shared__ __align__(16) float As[8][128];
    __shared__ __align__(16) float Bs[8][128];
    const int tid = threadIdx.x;
    const int tx = tid & 15;
    const int ty = tid >> 4;
    const int brow = blockIdx.y * 128;
    const int bcol = blockIdx.x * 128;

    float acc[8][8];
#pragma unroll
    for (int i = 0; i < 8; i++)
#pragma unroll
        for (int j = 0; j < 8; j++) acc[i][j] = 0.f;

    const int lrowA = tid >> 1;
    const int lkA   = (tid & 1) * 4;
    const int lkB   = tid >> 5;
    const int lcolB = (tid & 31) * 4;

    for (int k0 = 0; k0 < K; k0 += 8) {
        float4 a4 = *(const float4*)(A + (size_t)(brow + lrowA) * K + k0 + lkA);
        float4 b4 = *(const float4*)(B + (size_t)(k0 + lkB) * N + bcol + lcolB);
        As[lkA + 0][lrowA] = a4.x;
        As[lkA + 1][lrowA] = a4.y;
        As[lkA + 2][lrowA] = a4.z;
        As[lkA + 3][lrowA] = a4.w;
        *(float4*)&Bs[lkB][lcolB] = b4;
        __syncthreads();
#pragma unroll
        for (int k = 0; k < 8; k++) {
            float ar[8], br[8];
            *(float4*)&ar[0] = *(const float4*)&As[k][ty * 4];
            *(float4*)&ar[4] = *(const float4*)&As[k][64 + ty * 4];
            *(float4*)&br[0] = *(const float4*)&Bs[k][tx * 4];
            *(float4*)&br[4] = *(const float4*)&Bs[k][64 + tx * 4];
#pragma unroll
            for (int i = 0; i < 8; i++)
#pragma unroll
                for (int j = 0; j < 8; j++)
                    acc[i][j] = fmaf(ar[i], br[j], acc[i][j]);
        }
        __syncthreads();
    }

#pragma unroll
    for (int i = 0; i < 8; i++) {
        int row = brow + ((i < 4) ? (ty * 4 + i) : (64 + ty * 4 + i - 4));
#pragma unroll
        for (int jh = 0; jh < 2; jh++) {
            int col = bcol + ((jh == 0) ? tx * 4 : 64 + tx * 4);
            float4 b4 = *(const float4*)(bias + col);
            float4 v;
            v.x = acc[i][jh * 4 + 0] + b4.x;
            v.y = acc[i][jh * 4 + 1] + b4.y;
            v.z = acc[i][jh * 4 + 2] + b4.z;
            v.w = acc[i][jh * 4 + 3] + b4.w;
            if (RELU) {
                v.x = fmaxf(v.x, 0.f); v.y = fmaxf(v.y, 0.f);
                v.z = fmaxf(v.z, 0.f); v.w = fmaxf(v.w, 0.f);
            }
            *(float4*)(C + (size_t)row * N + col) = v;
        }
    }
}

// ---------------------------------------------------------------------------
// Row squared-norms (256-wide rows)
// ---------------------------------------------------------------------------
__global__ void rownorm2(const float* __restrict__ A, float* __restrict__ out,
                         int rows) {
    int gid = blockIdx.x * blockDim.x + threadIdx.x;
    int wid = gid >> 6, lane = gid & 63;
    if (wid >= rows) return;
    float4 v = *(const float4*)(A + (size_t)wid * 256 + lane * 4);
    float s = (v.x * v.x + v.y * v.y) + (v.z * v.z + v.w * v.w);
#pragma unroll
    for (int off = 1; off < 64; off <<= 1) s += __shfl_xor(s, off);
    if (lane == 0) out[wid] = s;
}

// ---------------------------------------------------------------------------
// Split fp32 [rows][256] -> bf16 hi|lo [rows][512], PRE-SWIZZLED:
// within each 128-byte k-chunk, byte position b holds value for b ^ ((row&7)<<4).
// global_load_lds then copies chunks linearly and ds_read applies the same XOR.
// ---------------------------------------------------------------------------
__device__ __forceinline__ unsigned short f2bf_rne(float x) {
    unsigned u = __float_as_uint(x);
    unsigned r = (u + 0x7fffu + ((u >> 16) & 1u)) >> 16;
    return (unsigned short)r;
}
__device__ __forceinline__ float bf2f(unsigned short h) {
    return __uint_as_float(((unsigned)h) << 16);
}

__global__ void split_bf16(const float* __restrict__ src,
                           unsigned short* __restrict__ dst, int n4) {
    int e = blockIdx.x * 256 + threadIdx.x;   // float4 index
    if (e >= n4) return;
    int row = e >> 6, kq = (e & 63) * 4;      // kq: k-index in floats, step 4
    float4 v = ((const float4*)src)[e];
    ushort4 hi, lo;
    hi.x = f2bf_rne(v.x); lo.x = f2bf_rne(v.x - bf2f(hi.x));
    hi.y = f2bf_rne(v.y); lo.y = f2bf_rne(v.y - bf2f(hi.y));
    hi.z = f2bf_rne(v.z); lo.z = f2bf_rne(v.z - bf2f(hi.z));
    hi.w = f2bf_rne(v.w); lo.w = f2bf_rne(v.w - bf2f(hi.w));
    const int m = (row & 7) << 4;
    char* rowp = (char*)(dst + (size_t)row * 512);
    int bh = kq * 2;                 // byte offset of hi group within row
    int bl = (256 + kq) * 2;         // byte offset of lo group within row
    int ph = (bh & ~127) | ((bh & 127) ^ m);
    int pl = (bl & ~127) | ((bl & 127) ^ m);
    *(ushort4*)(rowp + ph) = hi;
    *(ushort4*)(rowp + pl) = lo;
}

// ---------------------------------------------------------------------------
// top-2 helpers: lexicographic (d, idx) order
// ---------------------------------------------------------------------------
__device__ __forceinline__ int lex_lt(float d, int i, float D, int I) {
    return (d < D) || (d == D && i < I);
}
__device__ __forceinline__ void top2_merge(float& b1, int& j1, float& b2, int& j2,
                                           float c1, int k1, float c2, int k2) {
    if (lex_lt(c1, k1, b1, j1)) {
        float nb2; int nj2;
        if (lex_lt(b1, j1, c2, k2)) { nb2 = b1; nj2 = j1; }
        else                        { nb2 = c2; nj2 = k2; }
        b1 = c1; j1 = k1; b2 = nb2; j2 = nj2;
    } else {
        if (lex_lt(c1, k1, b2, j2)) { b2 = c1; j2 = k1; }
    }
}

__device__ __forceinline__ void gload16(const void* g, void* l) {
    __builtin_amdgcn_global_load_lds(
        (__attribute__((address_space(1))) void*)g,
        (__attribute__((address_space(3))) void*)l, 16, 0, 0);
}

// ---------------------------------------------------------------------------
// VQ MFMA kernel: 3-term split-bf16 d2-key GEMM (K'=768) + per-row top-2.
// Double-buffered LDS (2-phase pipeline), swizzled reads (conflict-free).
// grid = (64 colblocks, 128 rowblocks), 256 threads (4 waves, 2x2 of 64x64).
// ---------------------------------------------------------------------------
__global__ __launch_bounds__(256)
void vq_mfma(const unsigned short* __restrict__ Ae,
             const unsigned short* __restrict__ Be,
             const float* __restrict__ c2,
             float4* __restrict__ part) {
    __shared__ __align__(16) unsigned short As[2][128][64];
    __shared__ __align__(16) unsigned short Bs[2][128][64];
    __shared__ float sd1[128][2]; __shared__ int si1[128][2];
    __shared__ float sd2[128][2]; __shared__ int si2[128][2];

    const int tid  = threadIdx.x;
    const int lane = tid & 63;
    const int wid  = tid >> 6;
    const int wr   = wid >> 1, wc = wid & 1;
    const int brow = blockIdx.y * 128;
    const int bcol = blockIdx.x * 128;

    f32x4 acc[4][4] = {};

    const int fr = tid >> 3;            // 0..31 row sub-index (+ l*32)
    const int fk = (tid & 7) * 8;       // 0..56 elem within 64-chunk

    // stage step s (0..11) into buffer `buf`
    auto stage = [&](int s, int buf) {
        const int term = s >> 2, kq = s & 3;
        const int ka0 = (term == 2 ? 256 : 0) + kq * 64;
        const int kb0 = (term == 1 ? 256 : 0) + kq * 64;
#pragma unroll
        for (int l = 0; l < 4; ++l) {
            gload16(Ae + (size_t)(brow + l * 32 + fr) * 512 + ka0 + fk,
                    (char*)&As[buf][0][0] + l * 4096 + tid * 16);
            gload16(Be + (size_t)(bcol + l * 32 + fr) * 512 + kb0 + fk,
                    (char*)&Bs[buf][0][0] + l * 4096 + tid * 16);
        }
    };

    const int swz   = (lane & 7) << 4;          // read-side XOR (matches global pre-swizzle)
    const int arow  = wr * 64 + (lane & 15);
    const int brw   = wc * 64 + (lane & 15);
    const int klane = (lane >> 4) * 16;         // byte offset of 16B fragment

    stage(0, 0);
    __syncthreads();

    for (int s = 0; s < 12; ++s) {
        const int cur = s & 1;
        if (s + 1 < 12) stage(s + 1, cur ^ 1);
#pragma unroll
        for (int kk = 0; kk < 2; ++kk) {
            const int kb = (kk * 64 + klane) ^ swz;
            short8v af[4], bfv[4];
#pragma unroll
            for (int mi = 0; mi < 4; mi++)
                af[mi] = *(const short8v*)((const char*)&As[cur][arow + mi * 16][0] + kb);
#pragma unroll
            for (int ni = 0; ni < 4; ni++)
                bfv[ni] = *(const short8v*)((const char*)&Bs[cur][brw + ni * 16][0] + kb);
#pragma unroll
            for (int mi = 0; mi < 4; mi++)
#pragma unroll
                for (int ni = 0; ni < 4; ni++)
                    acc[mi][ni] = __builtin_amdgcn_mfma_f32_16x16x32_bf16(
                        af[mi], bfv[ni], acc[mi][ni], 0, 0, 0);
        }
        __syncthreads();
    }

    // ---- epilogue: per-row top-2 over this block's 128 cols ----
    float c2v[4];
#pragma unroll
    for (int ni = 0; ni < 4; ni++)
        c2v[ni] = c2[bcol + wc * 64 + ni * 16 + (lane & 15)];

#pragma unroll
    for (int mi = 0; mi < 4; mi++) {
#pragma unroll
        for (int q = 0; q < 4; q++) {
            float b1 = 3.4e38f, b2 = 3.4e38f;
            int   j1 = 0x7fffffff, j2 = 0x7fffffff;
#pragma unroll
            for (int ni = 0; ni < 4; ni++) {
                float dk  = fmaf(-2.0f, acc[mi][ni][q], c2v[ni]);
                int   col = bcol + wc * 64 + ni * 16 + (lane & 15);
                if (lex_lt(dk, col, b1, j1)) { b2 = b1; j2 = j1; b1 = dk; j1 = col; }
                else if (lex_lt(dk, col, b2, j2)) { b2 = dk; j2 = col; }
            }
#pragma unroll
            for (int off = 1; off < 16; off <<= 1) {
                float c1 = __shfl_xor(b1, off); int k1 = __shfl_xor(j1, off);
                float cc2 = __shfl_xor(b2, off); int k2 = __shfl_xor(j2, off);
                top2_merge(b1, j1, b2, j2, c1, k1, cc2, k2);
            }
            if ((lane & 15) == 0) {
                int rl = wr * 64 + mi * 16 + (lane >> 4) * 4 + q;
                sd1[rl][wc] = b1; si1[rl][wc] = j1;
                sd2[rl][wc] = b2; si2[rl][wc] = j2;
            }
        }
    }
    __syncthreads();
    if (tid < 128) {
        float b1 = sd1[tid][0], b2 = sd2[tid][0];
        int   j1 = si1[tid][0], j2 = si2[tid][0];
        top2_merge(b1, j1, b2, j2, sd1[tid][1], si1[tid][1], sd2[tid][1], si2[tid][1]);
        float4 pk;
        pk.x = b1; pk.y = __int_as_float(j1);
        pk.z = b2; pk.w = __int_as_float(j2);
        part[(size_t)(brow + tid) * NCB + blockIdx.x] = pk;
    }
}

// ---------------------------------------------------------------------------
// Combine per-colblock top-2s -> global approx top-2 -> exact fp32 rescore.
// ---------------------------------------------------------------------------
__global__ __launch_bounds__(256)
void vq_combine_rescore(const float4* __restrict__ part,
                        const float* __restrict__ enc,
                        const float* __restrict__ cw,
                        const float* __restrict__ c2,
                        const float* __restrict__ x2,
                        float* __restrict__ outIdx,
                        float* __restrict__ outDist,
                        int* __restrict__ idx32) {
    const int row  = blockIdx.x * 4 + (threadIdx.x >> 6);
    const int lane = threadIdx.x & 63;

    float4 pk = part[(size_t)row * NCB + lane];
    float b1 = pk.x, b2 = pk.z;
    int   j1 = __float_as_int(pk.y), j2 = __float_as_int(pk.w);
#pragma unroll
    for (int off = 1; off < 64; off <<= 1) {
        float c1 = __shfl_xor(b1, off); int k1 = __shfl_xor(j1, off);
        float cc2 = __shfl_xor(b2, off); int k2 = __shfl_xor(j2, off);
        top2_merge(b1, j1, b2, j2, c1, k1, cc2, k2);
    }

    float4 e4 = ((const float4*)(enc + (size_t)row * 256))[lane];
    float4 w1 = ((const float4*)(cw + (size_t)j1 * 256))[lane];
    float4 w2 = ((const float4*)(cw + (size_t)j2 * 256))[lane];
    float s1 = fmaf(e4.x, w1.x, fmaf(e4.y, w1.y, fmaf(e4.z, w1.z, e4.w * w1.w)));
    float s2 = fmaf(e4.x, w2.x, fmaf(e4.y, w2.y, fmaf(e4.z, w2.z, e4.w * w2.w)));
#pragma unroll
    for (int off = 1; off < 64; off <<= 1) {
        s1 += __shfl_xor(s1, off);
        s2 += __shfl_xor(s2, off);
    }
    float xv = x2[row];
    float d1 = sqrtf(fmaxf(xv + c2[j1] - 2.0f * s1, 0.f));
    float d2 = sqrtf(fmaxf(xv + c2[j2] - 2.0f * s2, 0.f));
    float bd; int bi;
    if (lex_lt(d1, j1, d2, j2)) { bd = d1; bi = j1; }
    else                        { bd = d2; bi = j2; }
    if (lane == 0) {
        outIdx[row]  = (float)bi;
        outDist[row] = bd;
        idx32[row]   = bi;
    }
}

// ---------------------------------------------------------------------------
// Gather decoded codewords + codewords into output rows.
// ---------------------------------------------------------------------------
__global__ void gather_out(const int* __restrict__ idx32,
                           const float* __restrict__ rec_all,
                           const float* __restrict__ cw,
                           float* __restrict__ outRec,
                           float* __restrict__ outQ) {
    int row = blockIdx.x;
    int j = idx32[row];
    const float4* src = (const float4*)(rec_all + (size_t)j * IN_DIM);
    float4* dst = (float4*)(outRec + (size_t)row * IN_DIM);
    dst[threadIdx.x] = src[threadIdx.x];
    if (threadIdx.x < 64) {
        ((float4*)(outQ + (size_t)row * ENC_DIM))[threadIdx.x] =
            ((const float4*)(cw + (size_t)j * ENC_DIM))[threadIdx.x];
    }
}

extern "C" void kernel_launch(void* const* d_in, const int* in_sizes, int n_in,
                              void* d_out, int out_size, void* d_ws, size_t ws_size,
                              hipStream_t stream) {
    const float* x   = (const float*)d_in[0];
    const float* ew1 = (const float*)d_in[1];
    const float* eb1 = (const float*)d_in[2];
    const float* ew2 = (const float*)d_in[3];
    const float* eb2 = (const float*)d_in[4];
    const float* cw  = (const float*)d_in[5];
    const float* dw1 = (const float*)d_in[6];
    const float* db1 = (const float*)d_in[7];
    const float* dw2 = (const float*)d_in[8];
    const float* db2 = (const float*)d_in[9];
    float* out = (float*)d_out;
    float* ws  = (float*)d_ws;

    float*          h       = ws;
    float4*         part    = (float4*)ws;
    float*          rec_all = ws;                       // [0, 8388608)
    float*          enc     = ws + 4194304;
    unsigned short* Ae      = (unsigned short*)(ws + 8388608);
    float*          g_all   = ws + 8388608;
    unsigned short* Be      = (unsigned short*)(ws + 12582912);
    float*          c2      = ws + 14680064;
    float*          x2      = ws + 14688256;
    int*            idx32   = (int*)(ws + 14704640);

    float* outIdx  = out;
    float* outDist = out + NROWS;
    float* outRec  = out + 2 * NROWS;
    float* outQ    = out + 2 * NROWS + (size_t)NROWS * IN_DIM;

    // Encoder (fp32)
    gemm_bias<1><<<dim3(2, 128), 256, 0, stream>>>(x, ew1, eb1, h, NROWS, IN_DIM, ENC_DIM);
    gemm_bias<1><<<dim3(2, 128), 256, 0, stream>>>(h, ew2, eb2, enc, NROWS, ENC_DIM, ENC_DIM);

    // Norms (fp32, reference-matching)
    rownorm2<<<KCW / 4, 256, 0, stream>>>(cw, c2, KCW);
    rownorm2<<<NROWS / 4, 256, 0, stream>>>(enc, x2, NROWS);

    // Split into swizzled bf16 hi|lo
    split_bf16<<<(NROWS * 64) / 256, 256, 0, stream>>>(enc, Ae, NROWS * 64);
    split_bf16<<<(KCW * 64) / 256, 256, 0, stream>>>(cw, Be, KCW * 64);

    // VQ approx (MFMA) + exact rescore
    vq_mfma<<<dim3(NCB, 128), 256, 0, stream>>>(Ae, Be, c2, part);
    vq_combine_rescore<<<NROWS / 4, 256, 0, stream>>>(part, enc, cw, c2, x2,
                                                      outIdx, outDist, idx32);

    // Decoder over codewords (fp32)
    gemm_bias<1><<<dim3(2, 64), 256, 0, stream>>>(cw, dw1, db1, g_all, KCW, ENC_DIM, ENC_DIM);
    gemm_bias<0><<<dim3(8, 64), 256, 0, stream>>>(g_all, dw2, db2, rec_all, KCW, ENC_DIM, IN_DIM);

    // Gather final outputs
    gather_out<<<NROWS, 256, 0, stream>>>(idx32, rec_all, cw, outRec, outQ);
}

// Round 4
// 589.301 us; speedup vs baseline: 2.0382x; 1.1936x over previous
//
#include <hip/hip_runtime.h>
#include <hip/hip_bf16.h>

#define NROWS   16384
#define IN_DIM  1024
#define ENC_DIM 256
#define KCW     8192
#define NCB     64          // codeword col-blocks of 128

typedef __attribute__((ext_vector_type(8))) short short8v;
typedef __attribute__((ext_vector_type(4))) float f32x4;

// ---------------------------------------------------------------------------
// helpers
// ---------------------------------------------------------------------------
__device__ __forceinline__ unsigned short f2bf_rne(float x) {
    unsigned u = __float_as_uint(x);
    unsigned r = (u + 0x7fffu + ((u >> 16) & 1u)) >> 16;
    return (unsigned short)r;
}
__device__ __forceinline__ float bf2f(unsigned short h) {
    return __uint_as_float(((unsigned)h) << 16);
}
__device__ __forceinline__ int lex_lt(float d, int i, float D, int I) {
    return (d < D) || (d == D && i < I);
}
__device__ __forceinline__ void top2_merge(float& b1, int& j1, float& b2, int& j2,
                                           float c1, int k1, float c2, int k2) {
    if (lex_lt(c1, k1, b1, j1)) {
        float nb2; int nj2;
        if (lex_lt(b1, j1, c2, k2)) { nb2 = b1; nj2 = j1; }
        else                        { nb2 = c2; nj2 = k2; }
        b1 = c1; j1 = k1; b2 = nb2; j2 = nj2;
    } else {
        if (lex_lt(c1, k1, b2, j2)) { b2 = c1; j2 = k1; }
    }
}
__device__ __forceinline__ void gload16(const void* g, void* l) {
    __builtin_amdgcn_global_load_lds(
        (__attribute__((address_space(1))) void*)g,
        (__attribute__((address_space(3))) void*)l, 16, 0, 0);
}

// ---------------------------------------------------------------------------
// enc1: fp32 tiled GEMM, epilogue writes ONLY the swizzled bf16 hi|lo split.
// C-split[row][512]: hi at k, lo at 256+k; bytes XOR'd by ((row&7)<<4) per
// 128-byte chunk.  M=16384, K=1024, N=256.
// ---------------------------------------------------------------------------
__global__ __launch_bounds__(256)
void gemm_enc1(const float* __restrict__ A, const float* __restrict__ B,
               const float* __restrict__ bias, unsigned short* __restrict__ Cs,
               int M, int K, int N) {
    __shared__ __align__(16) float As[8][128];
    __shared__ __align__(16) float Bs[8][128];
    const int tid = threadIdx.x;
    const int tx = tid & 15;
    const int ty = tid >> 4;
    const int brow = blockIdx.y * 128;
    const int bcol = blockIdx.x * 128;

    float acc[8][8];
#pragma unroll
    for (int i = 0; i < 8; i++)
#pragma unroll
        for (int j = 0; j < 8; j++) acc[i][j] = 0.f;

    const int lrowA = tid >> 1;
    const int lkA   = (tid & 1) * 4;
    const int lkB   = tid >> 5;
    const int lcolB = (tid & 31) * 4;

    for (int k0 = 0; k0 < K; k0 += 8) {
        float4 a4 = *(const float4*)(A + (size_t)(brow + lrowA) * K + k0 + lkA);
        float4 b4 = *(const float4*)(B + (size_t)(k0 + lkB) * N + bcol + lcolB);
        As[lkA + 0][lrowA] = a4.x;
        As[lkA + 1][lrowA] = a4.y;
        As[lkA + 2][lrowA] = a4.z;
        As[lkA + 3][lrowA] = a4.w;
        *(float4*)&Bs[lkB][lcolB] = b4;
        __syncthreads();
#pragma unroll
        for (int k = 0; k < 8; k++) {
            float ar[8], br[8];
            *(float4*)&ar[0] = *(const float4*)&As[k][ty * 4];
            *(float4*)&ar[4] = *(const float4*)&As[k][64 + ty * 4];
            *(float4*)&br[0] = *(const float4*)&Bs[k][tx * 4];
            *(float4*)&br[4] = *(const float4*)&Bs[k][64 + tx * 4];
#pragma unroll
            for (int i = 0; i < 8; i++)
#pragma unroll
                for (int j = 0; j < 8; j++)
                    acc[i][j] = fmaf(ar[i], br[j], acc[i][j]);
        }
        __syncthreads();
    }

#pragma unroll
    for (int i = 0; i < 8; i++) {
        int row = brow + ((i < 4) ? (ty * 4 + i) : (64 + ty * 4 + i - 4));
        const int m = (row & 7) << 4;
        char* rp = (char*)(Cs + (size_t)row * 512);
#pragma unroll
        for (int jh = 0; jh < 2; jh++) {
            int col = bcol + ((jh == 0) ? tx * 4 : 64 + tx * 4);
            float4 b4 = *(const float4*)(bias + col);
            float vx = fmaxf(acc[i][jh * 4 + 0] + b4.x, 0.f);
            float vy = fmaxf(acc[i][jh * 4 + 1] + b4.y, 0.f);
            float vz = fmaxf(acc[i][jh * 4 + 2] + b4.z, 0.f);
            float vw = fmaxf(acc[i][jh * 4 + 3] + b4.w, 0.f);
            ushort4 hi, lo;
            hi.x = f2bf_rne(vx); lo.x = f2bf_rne(vx - bf2f(hi.x));
            hi.y = f2bf_rne(vy); lo.y = f2bf_rne(vy - bf2f(hi.y));
            hi.z = f2bf_rne(vz); lo.z = f2bf_rne(vz - bf2f(hi.z));
            hi.w = f2bf_rne(vw); lo.w = f2bf_rne(vw - bf2f(hi.w));
            int bh = col * 2, bl = (256 + col) * 2;
            *(ushort4*)(rp + ((bh & ~127) | ((bh & 127) ^ m))) = hi;
            *(ushort4*)(rp + ((bl & ~127) | ((bl & 127) ^ m))) = lo;
        }
    }
}

// ---------------------------------------------------------------------------
// Row squared-norms (256-wide rows)
// ---------------------------------------------------------------------------
__global__ void rownorm2(const float* __restrict__ A, float* __restrict__ out,
                         int rows) {
    int gid = blockIdx.x * blockDim.x + threadIdx.x;
    int wid = gid >> 6, lane = gid & 63;
    if (wid >= rows) return;
    float4 v = *(const float4*)(A + (size_t)wid * 256 + lane * 4);
    float s = (v.x * v.x + v.y * v.y) + (v.z * v.z + v.w * v.w);
#pragma unroll
    for (int off = 1; off < 64; off <<= 1) s += __shfl_xor(s, off);
    if (lane == 0) out[wid] = s;
}

// ---------------------------------------------------------------------------
// Split fp32 [rows][256] -> swizzled bf16 hi|lo [rows][512]  (codewords)
// ---------------------------------------------------------------------------
__global__ void split_bf16(const float* __restrict__ src,
                           unsigned short* __restrict__ dst, int n4) {
    int e = blockIdx.x * 256 + threadIdx.x;
    if (e >= n4) return;
    int row = e >> 6, kq = (e & 63) * 4;
    float4 v = ((const float4*)src)[e];
    ushort4 hi, lo;
    hi.x = f2bf_rne(v.x); lo.x = f2bf_rne(v.x - bf2f(hi.x));
    hi.y = f2bf_rne(v.y); lo.y = f2bf_rne(v.y - bf2f(hi.y));
    hi.z = f2bf_rne(v.z); lo.z = f2bf_rne(v.z - bf2f(hi.z));
    hi.w = f2bf_rne(v.w); lo.w = f2bf_rne(v.w - bf2f(hi.w));
    const int m = (row & 7) << 4;
    char* rowp = (char*)(dst + (size_t)row * 512);
    int bh = kq * 2;
    int bl = (256 + kq) * 2;
    *(ushort4*)(rowp + ((bh & ~127) | ((bh & 127) ^ m))) = hi;
    *(ushort4*)(rowp + ((bl & ~127) | ((bl & 127) ^ m))) = lo;
}

// ---------------------------------------------------------------------------
// Transpose-split weights: W[256][N] fp32 -> Wt[N][512] swizzled bf16 hi|lo
// ---------------------------------------------------------------------------
__global__ void tsplit(const float* __restrict__ W,
                       unsigned short* __restrict__ Wt, int Ncols) {
    int idx = blockIdx.x * 256 + threadIdx.x;
    if (idx >= Ncols * 64) return;
    int n = idx >> 6, k4 = (idx & 63) * 4;
    float vx = W[(size_t)(k4 + 0) * Ncols + n];
    float vy = W[(size_t)(k4 + 1) * Ncols + n];
    float vz = W[(size_t)(k4 + 2) * Ncols + n];
    float vw = W[(size_t)(k4 + 3) * Ncols + n];
    ushort4 hi, lo;
    hi.x = f2bf_rne(vx); lo.x = f2bf_rne(vx - bf2f(hi.x));
    hi.y = f2bf_rne(vy); lo.y = f2bf_rne(vy - bf2f(hi.y));
    hi.z = f2bf_rne(vz); lo.z = f2bf_rne(vz - bf2f(hi.z));
    hi.w = f2bf_rne(vw); lo.w = f2bf_rne(vw - bf2f(hi.w));
    const int m = (n & 7) << 4;
    char* rp = (char*)(Wt + (size_t)n * 512);
    int bh = k4 * 2, bl = (256 + k4) * 2;
    *(ushort4*)(rp + ((bh & ~127) | ((bh & 127) ^ m))) = hi;
    *(ushort4*)(rp + ((bl & ~127) | ((bl & 127) ^ m))) = lo;
}

// ---------------------------------------------------------------------------
// Split-bf16 MFMA GEMM (K=256 via 3 terms = 12 steps of 64), 128x128 tile,
// single-buffered LDS, 4 waves.  A[M][512], Bt[N][512] both swizzled splits.
// EPI: 1 = relu, write C fp32 + Cs split;  2 = relu, write Cs split only;
//      3 = no relu, write C fp32 only.
// ---------------------------------------------------------------------------
template<int EPI>
__global__ __launch_bounds__(256)
void mm_split(const unsigned short* __restrict__ A,
              const unsigned short* __restrict__ Bt,
              const float* __restrict__ bias,
              float* __restrict__ C,
              unsigned short* __restrict__ Cs,
              int N) {
    __shared__ __align__(16) unsigned short As[128][64];
    __shared__ __align__(16) unsigned short Bs[128][64];
    const int tid = threadIdx.x;
    const int lane = tid & 63;
    const int wid = tid >> 6;
    const int wr = wid >> 1, wc = wid & 1;
    const int brow = blockIdx.y * 128;
    const int bcol = blockIdx.x * 128;

    f32x4 acc[4][4] = {};

    const int fr = tid >> 3;
    const int fk = (tid & 7) * 8;
    const int swz = (lane & 7) << 4;
    const int arow = wr * 64 + (lane & 15);
    const int brw  = wc * 64 + (lane & 15);
    const int klane = (lane >> 4) * 16;

    for (int s = 0; s < 12; ++s) {
        const int term = s >> 2, kq = s & 3;
        const int ka0 = (term == 2 ? 256 : 0) + kq * 64;
        const int kb0 = (term == 1 ? 256 : 0) + kq * 64;
        if (s) __syncthreads();
#pragma unroll
        for (int l = 0; l < 4; ++l) {
            gload16(A  + (size_t)(brow + l * 32 + fr) * 512 + ka0 + fk,
                    (char*)&As[0][0] + l * 4096 + tid * 16);
            gload16(Bt + (size_t)(bcol + l * 32 + fr) * 512 + kb0 + fk,
                    (char*)&Bs[0][0] + l * 4096 + tid * 16);
        }
        __syncthreads();
#pragma unroll
        for (int kk = 0; kk < 2; ++kk) {
            const int kb = (kk * 64 + klane) ^ swz;
            short8v af[4], bfv[4];
#pragma unroll
            for (int mi = 0; mi < 4; mi++)
                af[mi] = *(const short8v*)((const char*)&As[arow + mi * 16][0] + kb);
#pragma unroll
            for (int ni = 0; ni < 4; ni++)
                bfv[ni] = *(const short8v*)((const char*)&Bs[brw + ni * 16][0] + kb);
#pragma unroll
            for (int mi = 0; mi < 4; mi++)
#pragma unroll
                for (int ni = 0; ni < 4; ni++)
                    acc[mi][ni] = __builtin_amdgcn_mfma_f32_16x16x32_bf16(
                        af[mi], bfv[ni], acc[mi][ni], 0, 0, 0);
        }
    }

#pragma unroll
    for (int mi = 0; mi < 4; mi++) {
#pragma unroll
        for (int q = 0; q < 4; q++) {
            int row = brow + wr * 64 + mi * 16 + (lane >> 4) * 4 + q;
            const int m = (row & 7) << 4;
            char* rp = (char*)(Cs + (size_t)row * 512);
#pragma unroll
            for (int ni = 0; ni < 4; ni++) {
                int col = bcol + wc * 64 + ni * 16 + (lane & 15);
                float v = acc[mi][ni][q] + bias[col];
                if (EPI != 3) v = fmaxf(v, 0.f);
                if (EPI == 1 || EPI == 3) C[(size_t)row * N + col] = v;
                if (EPI == 1 || EPI == 2) {
                    unsigned short hi = f2bf_rne(v);
                    unsigned short lo = f2bf_rne(v - bf2f(hi));
                    int bh = col * 2, bl = (256 + col) * 2;
                    *(unsigned short*)(rp + ((bh & ~127) | ((bh & 127) ^ m))) = hi;
                    *(unsigned short*)(rp + ((bl & ~127) | ((bl & 127) ^ m))) = lo;
                }
            }
        }
    }
}

// ---------------------------------------------------------------------------
// VQ MFMA kernel: 3-term split-bf16 d2-key GEMM (K'=768) + per-row top-2.
// Single-buffered LDS (4 blocks/CU), swizzled reads, XCD-aware block swizzle.
// ---------------------------------------------------------------------------
__global__ __launch_bounds__(256)
void vq_mfma(const unsigned short* __restrict__ Ae,
             const unsigned short* __restrict__ Be,
             const float* __restrict__ c2,
             float4* __restrict__ part) {
    __shared__ __align__(16) unsigned short As[128][64];
    __shared__ __align__(16) unsigned short Bs[128][64];
    __shared__ float sd1[128][2]; __shared__ int si1[128][2];
    __shared__ float sd2[128][2]; __shared__ int si2[128][2];

    const int tid  = threadIdx.x;
    const int lane = tid & 63;
    const int wid  = tid >> 6;
    const int wr   = wid >> 1, wc = wid & 1;

    // bijective XCD swizzle: 8192 blocks, 8 XCDs -> each XCD gets 16
    // contiguous rowblocks x all 64 colblocks (A-strip L2-resident).
    const int f  = blockIdx.y * 64 + blockIdx.x;
    const int fn = (f & 7) * 1024 + (f >> 3);
    const int cb = fn & 63, rb = fn >> 6;
    const int brow = rb * 128;
    const int bcol = cb * 128;

    f32x4 acc[4][4] = {};

    const int fr = tid >> 3;
    const int fk = (tid & 7) * 8;
    const int swz   = (lane & 7) << 4;
    const int arow  = wr * 64 + (lane & 15);
    const int brw   = wc * 64 + (lane & 15);
    const int klane = (lane >> 4) * 16;

    for (int s = 0; s < 12; ++s) {
        const int term = s >> 2, kq = s & 3;
        const int ka0 = (term == 2 ? 256 : 0) + kq * 64;
        const int kb0 = (term == 1 ? 256 : 0) + kq * 64;
        if (s) __syncthreads();
#pragma unroll
        for (int l = 0; l < 4; ++l) {
            gload16(Ae + (size_t)(brow + l * 32 + fr) * 512 + ka0 + fk,
                    (char*)&As[0][0] + l * 4096 + tid * 16);
            gload16(Be + (size_t)(bcol + l * 32 + fr) * 512 + kb0 + fk,
                    (char*)&Bs[0][0] + l * 4096 + tid * 16);
        }
        __syncthreads();
#pragma unroll
        for (int kk = 0; kk < 2; ++kk) {
            const int kb = (kk * 64 + klane) ^ swz;
            short8v af[4], bfv[4];
#pragma unroll
            for (int mi = 0; mi < 4; mi++)
                af[mi] = *(const short8v*)((const char*)&As[arow + mi * 16][0] + kb);
#pragma unroll
            for (int ni = 0; ni < 4; ni++)
                bfv[ni] = *(const short8v*)((const char*)&Bs[brw + ni * 16][0] + kb);
#pragma unroll
            for (int mi = 0; mi < 4; mi++)
#pragma unroll
                for (int ni = 0; ni < 4; ni++)
                    acc[mi][ni] = __builtin_amdgcn_mfma_f32_16x16x32_bf16(
                        af[mi], bfv[ni], acc[mi][ni], 0, 0, 0);
        }
    }

    // ---- epilogue: per-row top-2 over this block's 128 cols ----
    float c2v[4];
#pragma unroll
    for (int ni = 0; ni < 4; ni++)
        c2v[ni] = c2[bcol + wc * 64 + ni * 16 + (lane & 15)];

#pragma unroll
    for (int mi = 0; mi < 4; mi++) {
#pragma unroll
        for (int q = 0; q < 4; q++) {
            float b1 = 3.4e38f, b2 = 3.4e38f;
            int   j1 = 0x7fffffff, j2 = 0x7fffffff;
#pragma unroll
            for (int ni = 0; ni < 4; ni++) {
                float dk  = fmaf(-2.0f, acc[mi][ni][q], c2v[ni]);
                int   col = bcol + wc * 64 + ni * 16 + (lane & 15);
                if (lex_lt(dk, col, b1, j1)) { b2 = b1; j2 = j1; b1 = dk; j1 = col; }
                else if (lex_lt(dk, col, b2, j2)) { b2 = dk; j2 = col; }
            }
#pragma unroll
            for (int off = 1; off < 16; off <<= 1) {
                float c1 = __shfl_xor(b1, off); int k1 = __shfl_xor(j1, off);
                float cc2 = __shfl_xor(b2, off); int k2 = __shfl_xor(j2, off);
                top2_merge(b1, j1, b2, j2, c1, k1, cc2, k2);
            }
            if ((lane & 15) == 0) {
                int rl = wr * 64 + mi * 16 + (lane >> 4) * 4 + q;
                sd1[rl][wc] = b1; si1[rl][wc] = j1;
                sd2[rl][wc] = b2; si2[rl][wc] = j2;
            }
        }
    }
    __syncthreads();
    if (tid < 128) {
        float b1 = sd1[tid][0], b2 = sd2[tid][0];
        int   j1 = si1[tid][0], j2 = si2[tid][0];
        top2_merge(b1, j1, b2, j2, sd1[tid][1], si1[tid][1], sd2[tid][1], si2[tid][1]);
        float4 pk;
        pk.x = b1; pk.y = __int_as_float(j1);
        pk.z = b2; pk.w = __int_as_float(j2);
        part[(size_t)(brow + tid) * NCB + cb] = pk;
    }
}

// ---------------------------------------------------------------------------
// Combine per-colblock top-2s -> global approx top-2 -> exact fp32 rescore.
// ---------------------------------------------------------------------------
__global__ __launch_bounds__(256)
void vq_combine_rescore(const float4* __restrict__ part,
                        const float* __restrict__ enc,
                        const float* __restrict__ cw,
                        const float* __restrict__ c2,
                        const float* __restrict__ x2,
                        float* __restrict__ outIdx,
                        float* __restrict__ outDist,
                        int* __restrict__ idx32) {
    const int row  = blockIdx.x * 4 + (threadIdx.x >> 6);
    const int lane = threadIdx.x & 63;

    float4 pk = part[(size_t)row * NCB + lane];
    float b1 = pk.x, b2 = pk.z;
    int   j1 = __float_as_int(pk.y), j2 = __float_as_int(pk.w);
#pragma unroll
    for (int off = 1; off < 64; off <<= 1) {
        float c1 = __shfl_xor(b1, off); int k1 = __shfl_xor(j1, off);
        float cc2 = __shfl_xor(b2, off); int k2 = __shfl_xor(j2, off);
        top2_merge(b1, j1, b2, j2, c1, k1, cc2, k2);
    }

    float4 e4 = ((const float4*)(enc + (size_t)row * 256))[lane];
    float4 w1 = ((const float4*)(cw + (size_t)j1 * 256))[lane];
    float4 w2 = ((const float4*)(cw + (size_t)j2 * 256))[lane];
    float s1 = fmaf(e4.x, w1.x, fmaf(e4.y, w1.y, fmaf(e4.z, w1.z, e4.w * w1.w)));
    float s2 = fmaf(e4.x, w2.x, fmaf(e4.y, w2.y, fmaf(e4.z, w2.z, e4.w * w2.w)));
#pragma unroll
    for (int off = 1; off < 64; off <<= 1) {
        s1 += __shfl_xor(s1, off);
        s2 += __shfl_xor(s2, off);
    }
    float xv = x2[row];
    float d1 = sqrtf(fmaxf(xv + c2[j1] - 2.0f * s1, 0.f));
    float d2 = sqrtf(fmaxf(xv + c2[j2] - 2.0f * s2, 0.f));
    float bd; int bi;
    if (lex_lt(d1, j1, d2, j2)) { bd = d1; bi = j1; }
    else                        { bd = d2; bi = j2; }
    if (lane == 0) {
        outIdx[row]  = (float)bi;
        outDist[row] = bd;
        idx32[row]   = bi;
    }
}

// ---------------------------------------------------------------------------
// Gather decoded codewords + codewords into output rows.
// ---------------------------------------------------------------------------
__global__ void gather_out(const int* __restrict__ idx32,
                           const float* __restrict__ rec_all,
                           const float* __restrict__ cw,
                           float* __restrict__ outRec,
                           float* __restrict__ outQ) {
    int row = blockIdx.x;
    int j = idx32[row];
    const float4* src = (const float4*)(rec_all + (size_t)j * IN_DIM);
    float4* dst = (float4*)(outRec + (size_t)row * IN_DIM);
    dst[threadIdx.x] = src[threadIdx.x];
    if (threadIdx.x < 64) {
        ((float4*)(outQ + (size_t)row * ENC_DIM))[threadIdx.x] =
            ((const float4*)(cw + (size_t)j * ENC_DIM))[threadIdx.x];
    }
}

extern "C" void kernel_launch(void* const* d_in, const int* in_sizes, int n_in,
                              void* d_out, int out_size, void* d_ws, size_t ws_size,
                              hipStream_t stream) {
    const float* x   = (const float*)d_in[0];
    const float* ew1 = (const float*)d_in[1];
    const float* eb1 = (const float*)d_in[2];
    const float* ew2 = (const float*)d_in[3];
    const float* eb2 = (const float*)d_in[4];
    const float* cw  = (const float*)d_in[5];
    const float* dw1 = (const float*)d_in[6];
    const float* db1 = (const float*)d_in[7];
    const float* dw2 = (const float*)d_in[8];
    const float* db2 = (const float*)d_in[9];
    float* out = (float*)d_out;
    float* ws  = (float*)d_ws;

    // workspace (float offsets), aliasing timeline:
    //  [0,       4194304)  enc fp32 (live: enc2..rescore)   -> rec_all (dec2+)
    //  [4194304, 8388608)  Ae split (live: enc2..vq)        -> rec_all tail
    //  [8388608,10485760)  Be split (live: split..dec1)
    //  [10485760,14680064) Ah split (enc1..enc2)            -> part (vq..rescore)
    //  [14680064,15073280) ew2t | dw1t | dw2t
    //  [15073280,17170432) Gs split (dec1..dec2)
    //  [17170432,...]      c2, x2, idx32       total ~68.9 MB
    float*          enc     = ws;
    float*          rec_all = ws;
    unsigned short* Ae      = (unsigned short*)(ws + 4194304);
    unsigned short* Be      = (unsigned short*)(ws + 8388608);
    unsigned short* Ah      = (unsigned short*)(ws + 10485760);
    float4*         part    = (float4*)(ws + 10485760);
    unsigned short* ew2t    = (unsigned short*)(ws + 14680064);
    unsigned short* dw1t    = (unsigned short*)(ws + 14745600);
    unsigned short* dw2t    = (unsigned short*)(ws + 14811136);
    unsigned short* Gs      = (unsigned short*)(ws + 15073280);
    float*          c2      = ws + 17170432;
    float*          x2      = ws + 17178624;
    int*            idx32   = (int*)(ws + 17195008);

    float* outIdx  = out;
    float* outDist = out + NROWS;
    float* outRec  = out + 2 * NROWS;
    float* outQ    = out + 2 * NROWS + (size_t)NROWS * IN_DIM;

    // Weight transpose-splits + codeword split + c2 (independent)
    tsplit<<<64, 256, 0, stream>>>(ew2, ew2t, 256);
    tsplit<<<64, 256, 0, stream>>>(dw1, dw1t, 256);
    tsplit<<<256, 256, 0, stream>>>(dw2, dw2t, 1024);
    split_bf16<<<(KCW * 64) / 256, 256, 0, stream>>>(cw, Be, KCW * 64);
    rownorm2<<<KCW / 4, 256, 0, stream>>>(cw, c2, KCW);

    // Encoder
    gemm_enc1<<<dim3(2, 128), 256, 0, stream>>>(x, ew1, eb1, Ah, NROWS, IN_DIM, ENC_DIM);
    mm_split<1><<<dim3(2, 128), 256, 0, stream>>>(Ah, ew2t, eb2, enc, Ae, ENC_DIM);
    rownorm2<<<NROWS / 4, 256, 0, stream>>>(enc, x2, NROWS);

    // VQ approx (MFMA) + exact rescore
    vq_mfma<<<dim3(NCB, 128), 256, 0, stream>>>(Ae, Be, c2, part);
    vq_combine_rescore<<<NROWS / 4, 256, 0, stream>>>(part, enc, cw, c2, x2,
                                                      outIdx, outDist, idx32);

    // Decoder over codewords (MFMA): dec1 reuses Be as its A operand
    mm_split<2><<<dim3(2, 64), 256, 0, stream>>>(Be, dw1t, db1, nullptr, Gs, ENC_DIM);
    mm_split<3><<<dim3(8, 64), 256, 0, stream>>>(Gs, dw2t, db2, rec_all, nullptr, IN_DIM);

    // Gather final outputs
    gather_out<<<NROWS, 256, 0, stream>>>(idx32, rec_all, cw, outRec, outQ);
}

// Round 5
// 548.120 us; speedup vs baseline: 2.1913x; 1.0751x over previous
//
#include <hip/hip_runtime.h>
#include <hip/hip_bf16.h>

#define NROWS   16384
#define IN_DIM  1024
#define ENC_DIM 256
#define KCW     8192
#define NCB     64          // codeword col-blocks of 128

typedef __attribute__((ext_vector_type(8))) short short8v;
typedef __attribute__((ext_vector_type(4))) float f32x4;
typedef unsigned long long u64;

// ---------------------------------------------------------------------------
// helpers
// ---------------------------------------------------------------------------
__device__ __forceinline__ unsigned short f2bf_rne(float x) {
    unsigned u = __float_as_uint(x);
    unsigned r = (u + 0x7fffu + ((u >> 16) & 1u)) >> 16;
    return (unsigned short)r;
}
__device__ __forceinline__ float bf2f(unsigned short h) {
    return __uint_as_float(((unsigned)h) << 16);
}
__device__ __forceinline__ int lex_lt(float d, int i, float D, int I) {
    return (d < D) || (d == D && i < I);
}
// order-preserving float->uint (handles negatives), then pack with col
__device__ __forceinline__ u64 packkey(float d, int col) {
    unsigned u = __float_as_uint(d);
    u = (u & 0x80000000u) ? ~u : (u | 0x80000000u);
    return ((u64)u << 32) | (unsigned)col;
}
// branchless top-2 insert / merge (all keys distinct: col in low bits)
__device__ __forceinline__ void t2ins(u64& b1, u64& b2, u64 k) {
    u64 mx = (k > b1) ? k : b1;
    b1 = (k < b1) ? k : b1;
    b2 = (mx < b2) ? mx : b2;
}
__device__ __forceinline__ void t2mrg(u64& b1, u64& b2, u64 c1, u64 c2) {
    u64 hi = (b1 > c1) ? b1 : c1;
    u64 lo2 = (b2 < c2) ? b2 : c2;
    b1 = (b1 < c1) ? b1 : c1;
    b2 = (hi < lo2) ? hi : lo2;
}
__device__ __forceinline__ void gload16(const void* g, void* l) {
    __builtin_amdgcn_global_load_lds(
        (__attribute__((address_space(1))) void*)g,
        (__attribute__((address_space(3))) void*)l, 16, 0, 0);
}

// ---------------------------------------------------------------------------
// enc1: fp32 tiled GEMM, epilogue writes ONLY the swizzled bf16 hi|lo split.
// ---------------------------------------------------------------------------
__global__ __launch_bounds__(256)
void gemm_enc1(const float* __restrict__ A, const float* __restrict__ B,
               const float* __restrict__ bias, unsigned short* __restrict__ Cs,
               int M, int K, int N) {
    __shared__ __align__(16) float As[8][128];
    __shared__ __align__(16) float Bs[8][128];
    const int tid = threadIdx.x;
    const int tx = tid & 15;
    const int ty = tid >> 4;
    const int brow = blockIdx.y * 128;
    const int bcol = blockIdx.x * 128;

    float acc[8][8];
#pragma unroll
    for (int i = 0; i < 8; i++)
#pragma unroll
        for (int j = 0; j < 8; j++) acc[i][j] = 0.f;

    const int lrowA = tid >> 1;
    const int lkA   = (tid & 1) * 4;
    const int lkB   = tid >> 5;
    const int lcolB = (tid & 31) * 4;

    for (int k0 = 0; k0 < K; k0 += 8) {
        float4 a4 = *(const float4*)(A + (size_t)(brow + lrowA) * K + k0 + lkA);
        float4 b4 = *(const float4*)(B + (size_t)(k0 + lkB) * N + bcol + lcolB);
        As[lkA + 0][lrowA] = a4.x;
        As[lkA + 1][lrowA] = a4.y;
        As[lkA + 2][lrowA] = a4.z;
        As[lkA + 3][lrowA] = a4.w;
        *(float4*)&Bs[lkB][lcolB] = b4;
        __syncthreads();
#pragma unroll
        for (int k = 0; k < 8; k++) {
            float ar[8], br[8];
            *(float4*)&ar[0] = *(const float4*)&As[k][ty * 4];
            *(float4*)&ar[4] = *(const float4*)&As[k][64 + ty * 4];
            *(float4*)&br[0] = *(const float4*)&Bs[k][tx * 4];
            *(float4*)&br[4] = *(const float4*)&Bs[k][64 + tx * 4];
#pragma unroll
            for (int i = 0; i < 8; i++)
#pragma unroll
                for (int j = 0; j < 8; j++)
                    acc[i][j] = fmaf(ar[i], br[j], acc[i][j]);
        }
        __syncthreads();
    }

#pragma unroll
    for (int i = 0; i < 8; i++) {
        int row = brow + ((i < 4) ? (ty * 4 + i) : (64 + ty * 4 + i - 4));
        const int m = (row & 7) << 4;
        char* rp = (char*)(Cs + (size_t)row * 512);
#pragma unroll
        for (int jh = 0; jh < 2; jh++) {
            int col = bcol + ((jh == 0) ? tx * 4 : 64 + tx * 4);
            float4 b4 = *(const float4*)(bias + col);
            float vx = fmaxf(acc[i][jh * 4 + 0] + b4.x, 0.f);
            float vy = fmaxf(acc[i][jh * 4 + 1] + b4.y, 0.f);
            float vz = fmaxf(acc[i][jh * 4 + 2] + b4.z, 0.f);
            float vw = fmaxf(acc[i][jh * 4 + 3] + b4.w, 0.f);
            ushort4 hi, lo;
            hi.x = f2bf_rne(vx); lo.x = f2bf_rne(vx - bf2f(hi.x));
            hi.y = f2bf_rne(vy); lo.y = f2bf_rne(vy - bf2f(hi.y));
            hi.z = f2bf_rne(vz); lo.z = f2bf_rne(vz - bf2f(hi.z));
            hi.w = f2bf_rne(vw); lo.w = f2bf_rne(vw - bf2f(hi.w));
            int bh = col * 2, bl = (256 + col) * 2;
            *(ushort4*)(rp + ((bh & ~127) | ((bh & 127) ^ m))) = hi;
            *(ushort4*)(rp + ((bl & ~127) | ((bl & 127) ^ m))) = lo;
        }
    }
}

// ---------------------------------------------------------------------------
// Row squared-norms (256-wide rows)
// ---------------------------------------------------------------------------
__global__ void rownorm2(const float* __restrict__ A, float* __restrict__ out,
                         int rows) {
    int gid = blockIdx.x * blockDim.x + threadIdx.x;
    int wid = gid >> 6, lane = gid & 63;
    if (wid >= rows) return;
    float4 v = *(const float4*)(A + (size_t)wid * 256 + lane * 4);
    float s = (v.x * v.x + v.y * v.y) + (v.z * v.z + v.w * v.w);
#pragma unroll
    for (int off = 1; off < 64; off <<= 1) s += __shfl_xor(s, off);
    if (lane == 0) out[wid] = s;
}

// ---------------------------------------------------------------------------
// Split fp32 [rows][256] -> swizzled bf16 hi|lo [rows][512]  (codewords)
// ---------------------------------------------------------------------------
__global__ void split_bf16(const float* __restrict__ src,
                           unsigned short* __restrict__ dst, int n4) {
    int e = blockIdx.x * 256 + threadIdx.x;
    if (e >= n4) return;
    int row = e >> 6, kq = (e & 63) * 4;
    float4 v = ((const float4*)src)[e];
    ushort4 hi, lo;
    hi.x = f2bf_rne(v.x); lo.x = f2bf_rne(v.x - bf2f(hi.x));
    hi.y = f2bf_rne(v.y); lo.y = f2bf_rne(v.y - bf2f(hi.y));
    hi.z = f2bf_rne(v.z); lo.z = f2bf_rne(v.z - bf2f(hi.z));
    hi.w = f2bf_rne(v.w); lo.w = f2bf_rne(v.w - bf2f(hi.w));
    const int m = (row & 7) << 4;
    char* rowp = (char*)(dst + (size_t)row * 512);
    int bh = kq * 2;
    int bl = (256 + kq) * 2;
    *(ushort4*)(rowp + ((bh & ~127) | ((bh & 127) ^ m))) = hi;
    *(ushort4*)(rowp + ((bl & ~127) | ((bl & 127) ^ m))) = lo;
}

// ---------------------------------------------------------------------------
// Transpose-split weights: W[256][N] fp32 -> Wt[N][512] swizzled bf16 hi|lo
// ---------------------------------------------------------------------------
__global__ void tsplit(const float* __restrict__ W,
                       unsigned short* __restrict__ Wt, int Ncols) {
    int idx = blockIdx.x * 256 + threadIdx.x;
    if (idx >= Ncols * 64) return;
    int n = idx >> 6, k4 = (idx & 63) * 4;
    float vx = W[(size_t)(k4 + 0) * Ncols + n];
    float vy = W[(size_t)(k4 + 1) * Ncols + n];
    float vz = W[(size_t)(k4 + 2) * Ncols + n];
    float vw = W[(size_t)(k4 + 3) * Ncols + n];
    ushort4 hi, lo;
    hi.x = f2bf_rne(vx); lo.x = f2bf_rne(vx - bf2f(hi.x));
    hi.y = f2bf_rne(vy); lo.y = f2bf_rne(vy - bf2f(hi.y));
    hi.z = f2bf_rne(vz); lo.z = f2bf_rne(vz - bf2f(hi.z));
    hi.w = f2bf_rne(vw); lo.w = f2bf_rne(vw - bf2f(hi.w));
    const int m = (n & 7) << 4;
    char* rp = (char*)(Wt + (size_t)n * 512);
    int bh = k4 * 2, bl = (256 + k4) * 2;
    *(ushort4*)(rp + ((bh & ~127) | ((bh & 127) ^ m))) = hi;
    *(ushort4*)(rp + ((bl & ~127) | ((bl & 127) ^ m))) = lo;
}

// ---------------------------------------------------------------------------
// Split-bf16 MFMA GEMM (K=256 via 3 terms = 12 steps of 64), 128x128 tile.
// EPI: 1 = relu, write C fp32 + Cs split;  2 = relu, write Cs split only;
//      3 = no relu, write C fp32 only.
// ---------------------------------------------------------------------------
template<int EPI>
__global__ __launch_bounds__(256)
void mm_split(const unsigned short* __restrict__ A,
              const unsigned short* __restrict__ Bt,
              const float* __restrict__ bias,
              float* __restrict__ C,
              unsigned short* __restrict__ Cs,
              int N) {
    __shared__ __align__(16) unsigned short As[128][64];
    __shared__ __align__(16) unsigned short Bs[128][64];
    const int tid = threadIdx.x;
    const int lane = tid & 63;
    const int wid = tid >> 6;
    const int wr = wid >> 1, wc = wid & 1;
    const int brow = blockIdx.y * 128;
    const int bcol = blockIdx.x * 128;

    f32x4 acc[4][4] = {};

    const int fr = tid >> 3;
    const int fk = (tid & 7) * 8;
    const int swz = (lane & 7) << 4;
    const int arow = wr * 64 + (lane & 15);
    const int brw  = wc * 64 + (lane & 15);
    const int klane = (lane >> 4) * 16;

    for (int s = 0; s < 12; ++s) {
        const int term = s >> 2, kq = s & 3;
        const int ka0 = (term == 2 ? 256 : 0) + kq * 64;
        const int kb0 = (term == 1 ? 256 : 0) + kq * 64;
        if (s) __syncthreads();
#pragma unroll
        for (int l = 0; l < 4; ++l) {
            gload16(A  + (size_t)(brow + l * 32 + fr) * 512 + ka0 + fk,
                    (char*)&As[0][0] + l * 4096 + tid * 16);
            gload16(Bt + (size_t)(bcol + l * 32 + fr) * 512 + kb0 + fk,
                    (char*)&Bs[0][0] + l * 4096 + tid * 16);
        }
        __syncthreads();
#pragma unroll
        for (int kk = 0; kk < 2; ++kk) {
            const int kb = (kk * 64 + klane) ^ swz;
            short8v af[4], bfv[4];
#pragma unroll
            for (int mi = 0; mi < 4; mi++)
                af[mi] = *(const short8v*)((const char*)&As[arow + mi * 16][0] + kb);
#pragma unroll
            for (int ni = 0; ni < 4; ni++)
                bfv[ni] = *(const short8v*)((const char*)&Bs[brw + ni * 16][0] + kb);
#pragma unroll
            for (int mi = 0; mi < 4; mi++)
#pragma unroll
                for (int ni = 0; ni < 4; ni++)
                    acc[mi][ni] = __builtin_amdgcn_mfma_f32_16x16x32_bf16(
                        af[mi], bfv[ni], acc[mi][ni], 0, 0, 0);
        }
    }

#pragma unroll
    for (int mi = 0; mi < 4; mi++) {
#pragma unroll
        for (int q = 0; q < 4; q++) {
            int row = brow + wr * 64 + mi * 16 + (lane >> 4) * 4 + q;
            const int m = (row & 7) << 4;
            char* rp = (char*)(Cs + (size_t)row * 512);
#pragma unroll
            for (int ni = 0; ni < 4; ni++) {
                int col = bcol + wc * 64 + ni * 16 + (lane & 15);
                float v = acc[mi][ni][q] + bias[col];
                if (EPI != 3) v = fmaxf(v, 0.f);
                if (EPI == 1 || EPI == 3) C[(size_t)row * N + col] = v;
                if (EPI == 1 || EPI == 2) {
                    unsigned short hi = f2bf_rne(v);
                    unsigned short lo = f2bf_rne(v - bf2f(hi));
                    int bh = col * 2, bl = (256 + col) * 2;
                    *(unsigned short*)(rp + ((bh & ~127) | ((bh & 127) ^ m))) = hi;
                    *(unsigned short*)(rp + ((bl & ~127) | ((bl & 127) ^ m))) = lo;
                }
            }
        }
    }
}

// ---------------------------------------------------------------------------
// VQ MFMA kernel: 3-term split-bf16 d2-key GEMM (K'=768) + per-row top-2.
// Single-buffered LDS, natural block order (cb mod 8 per XCD -> B L2-resident),
// branchless u64-packed top-2 epilogue.
// ---------------------------------------------------------------------------
__global__ __launch_bounds__(256)
void vq_mfma(const unsigned short* __restrict__ Ae,
             const unsigned short* __restrict__ Be,
             const float* __restrict__ c2,
             ulonglong2* __restrict__ part) {
    __shared__ __align__(16) unsigned short As[128][64];
    __shared__ __align__(16) unsigned short Bs[128][64];
    __shared__ u64 s1[128][2];
    __shared__ u64 s2[128][2];

    const int tid  = threadIdx.x;
    const int lane = tid & 63;
    const int wid  = tid >> 6;
    const int wr   = wid >> 1, wc = wid & 1;
    const int brow = blockIdx.y * 128;
    const int bcol = blockIdx.x * 128;

    f32x4 acc[4][4] = {};

    const int fr = tid >> 3;
    const int fk = (tid & 7) * 8;
    const int swz   = (lane & 7) << 4;
    const int arow  = wr * 64 + (lane & 15);
    const int brw   = wc * 64 + (lane & 15);
    const int klane = (lane >> 4) * 16;

    for (int s = 0; s < 12; ++s) {
        const int term = s >> 2, kq = s & 3;
        const int ka0 = (term == 2 ? 256 : 0) + kq * 64;
        const int kb0 = (term == 1 ? 256 : 0) + kq * 64;
        if (s) __syncthreads();
#pragma unroll
        for (int l = 0; l < 4; ++l) {
            gload16(Ae + (size_t)(brow + l * 32 + fr) * 512 + ka0 + fk,
                    (char*)&As[0][0] + l * 4096 + tid * 16);
            gload16(Be + (size_t)(bcol + l * 32 + fr) * 512 + kb0 + fk,
                    (char*)&Bs[0][0] + l * 4096 + tid * 16);
        }
        __syncthreads();
#pragma unroll
        for (int kk = 0; kk < 2; ++kk) {
            const int kb = (kk * 64 + klane) ^ swz;
            short8v af[4], bfv[4];
#pragma unroll
            for (int mi = 0; mi < 4; mi++)
                af[mi] = *(const short8v*)((const char*)&As[arow + mi * 16][0] + kb);
#pragma unroll
            for (int ni = 0; ni < 4; ni++)
                bfv[ni] = *(const short8v*)((const char*)&Bs[brw + ni * 16][0] + kb);
#pragma unroll
            for (int mi = 0; mi < 4; mi++)
#pragma unroll
                for (int ni = 0; ni < 4; ni++)
                    acc[mi][ni] = __builtin_amdgcn_mfma_f32_16x16x32_bf16(
                        af[mi], bfv[ni], acc[mi][ni], 0, 0, 0);
        }
    }

    // ---- epilogue: branchless per-row top-2 over this block's 128 cols ----
    float c2v[4];
#pragma unroll
    for (int ni = 0; ni < 4; ni++)
        c2v[ni] = c2[bcol + wc * 64 + ni * 16 + (lane & 15)];

#pragma unroll
    for (int mi = 0; mi < 4; mi++) {
#pragma unroll
        for (int q = 0; q < 4; q++) {
            u64 b1 = ~0ull, b2 = ~0ull;
#pragma unroll
            for (int ni = 0; ni < 4; ni++) {
                float dk  = fmaf(-2.0f, acc[mi][ni][q], c2v[ni]);
                int   col = bcol + wc * 64 + ni * 16 + (lane & 15);
                t2ins(b1, b2, packkey(dk, col));
            }
#pragma unroll
            for (int off = 1; off < 16; off <<= 1) {
                u64 c1 = __shfl_xor(b1, off);
                u64 cc2 = __shfl_xor(b2, off);
                t2mrg(b1, b2, c1, cc2);
            }
            if ((lane & 15) == 0) {
                int rl = wr * 64 + mi * 16 + (lane >> 4) * 4 + q;
                s1[rl][wc] = b1;
                s2[rl][wc] = b2;
            }
        }
    }
    __syncthreads();
    if (tid < 128) {
        u64 b1 = s1[tid][0], b2 = s2[tid][0];
        t2mrg(b1, b2, s1[tid][1], s2[tid][1]);
        ulonglong2 pk;
        pk.x = b1; pk.y = b2;
        part[(size_t)(brow + tid) * NCB + blockIdx.x] = pk;
    }
}

// ---------------------------------------------------------------------------
// Combine per-colblock top-2s -> global approx top-2 -> exact fp32 rescore.
// ---------------------------------------------------------------------------
__global__ __launch_bounds__(256)
void vq_combine_rescore(const ulonglong2* __restrict__ part,
                        const float* __restrict__ enc,
                        const float* __restrict__ cw,
                        const float* __restrict__ c2,
                        const float* __restrict__ x2,
                        float* __restrict__ outIdx,
                        float* __restrict__ outDist,
                        int* __restrict__ idx32) {
    const int row  = blockIdx.x * 4 + (threadIdx.x >> 6);
    const int lane = threadIdx.x & 63;

    ulonglong2 pk = part[(size_t)row * NCB + lane];
    u64 b1 = pk.x, b2 = pk.y;
#pragma unroll
    for (int off = 1; off < 64; off <<= 1) {
        u64 c1 = __shfl_xor(b1, off);
        u64 cc2 = __shfl_xor(b2, off);
        t2mrg(b1, b2, c1, cc2);
    }
    int j1 = (int)(b1 & 0xffffffffu);
    int j2 = (int)(b2 & 0xffffffffu);

    float4 e4 = ((const float4*)(enc + (size_t)row * 256))[lane];
    float4 w1 = ((const float4*)(cw + (size_t)j1 * 256))[lane];
    float4 w2 = ((const float4*)(cw + (size_t)j2 * 256))[lane];
    float s1 = fmaf(e4.x, w1.x, fmaf(e4.y, w1.y, fmaf(e4.z, w1.z, e4.w * w1.w)));
    float s2 = fmaf(e4.x, w2.x, fmaf(e4.y, w2.y, fmaf(e4.z, w2.z, e4.w * w2.w)));
#pragma unroll
    for (int off = 1; off < 64; off <<= 1) {
        s1 += __shfl_xor(s1, off);
        s2 += __shfl_xor(s2, off);
    }
    float xv = x2[row];
    float d1 = sqrtf(fmaxf(xv + c2[j1] - 2.0f * s1, 0.f));
    float d2 = sqrtf(fmaxf(xv + c2[j2] - 2.0f * s2, 0.f));
    float bd; int bi;
    if (lex_lt(d1, j1, d2, j2)) { bd = d1; bi = j1; }
    else                        { bd = d2; bi = j2; }
    if (lane == 0) {
        outIdx[row]  = (float)bi;
        outDist[row] = bd;
        idx32[row]   = bi;
    }
}

// ---------------------------------------------------------------------------
// Gather decoded codewords + codewords into output rows.
// ---------------------------------------------------------------------------
__global__ void gather_out(const int* __restrict__ idx32,
                           const float* __restrict__ rec_all,
                           const float* __restrict__ cw,
                           float* __restrict__ outRec,
                           float* __restrict__ outQ) {
    int row = blockIdx.x;
    int j = idx32[row];
    const float4* src = (const float4*)(rec_all + (size_t)j * IN_DIM);
    float4* dst = (float4*)(outRec + (size_t)row * IN_DIM);
    dst[threadIdx.x] = src[threadIdx.x];
    if (threadIdx.x < 64) {
        ((float4*)(outQ + (size_t)row * ENC_DIM))[threadIdx.x] =
            ((const float4*)(cw + (size_t)j * ENC_DIM))[threadIdx.x];
    }
}

extern "C" void kernel_launch(void* const* d_in, const int* in_sizes, int n_in,
                              void* d_out, int out_size, void* d_ws, size_t ws_size,
                              hipStream_t stream) {
    const float* x   = (const float*)d_in[0];
    const float* ew1 = (const float*)d_in[1];
    const float* eb1 = (const float*)d_in[2];
    const float* ew2 = (const float*)d_in[3];
    const float* eb2 = (const float*)d_in[4];
    const float* cw  = (const float*)d_in[5];
    const float* dw1 = (const float*)d_in[6];
    const float* db1 = (const float*)d_in[7];
    const float* dw2 = (const float*)d_in[8];
    const float* db2 = (const float*)d_in[9];
    float* out = (float*)d_out;
    float* ws  = (float*)d_ws;

    float*          enc     = ws;
    float*          rec_all = ws;
    unsigned short* Ae      = (unsigned short*)(ws + 4194304);
    unsigned short* Be      = (unsigned short*)(ws + 8388608);
    unsigned short* Ah      = (unsigned short*)(ws + 10485760);
    ulonglong2*     part    = (ulonglong2*)(ws + 10485760);
    unsigned short* ew2t    = (unsigned short*)(ws + 14680064);
    unsigned short* dw1t    = (unsigned short*)(ws + 14745600);
    unsigned short* dw2t    = (unsigned short*)(ws + 14811136);
    unsigned short* Gs      = (unsigned short*)(ws + 15073280);
    float*          c2      = ws + 17170432;
    float*          x2      = ws + 17178624;
    int*            idx32   = (int*)(ws + 17195008);

    float* outIdx  = out;
    float* outDist = out + NROWS;
    float* outRec  = out + 2 * NROWS;
    float* outQ    = out + 2 * NROWS + (size_t)NROWS * IN_DIM;

    // Weight transpose-splits + codeword split + c2 (independent)
    tsplit<<<64, 256, 0, stream>>>(ew2, ew2t, 256);
    tsplit<<<64, 256, 0, stream>>>(dw1, dw1t, 256);
    tsplit<<<256, 256, 0, stream>>>(dw2, dw2t, 1024);
    split_bf16<<<(KCW * 64) / 256, 256, 0, stream>>>(cw, Be, KCW * 64);
    rownorm2<<<KCW / 4, 256, 0, stream>>>(cw, c2, KCW);

    // Encoder
    gemm_enc1<<<dim3(2, 128), 256, 0, stream>>>(x, ew1, eb1, Ah, NROWS, IN_DIM, ENC_DIM);
    mm_split<1><<<dim3(2, 128), 256, 0, stream>>>(Ah, ew2t, eb2, enc, Ae, ENC_DIM);
    rownorm2<<<NROWS / 4, 256, 0, stream>>>(enc, x2, NROWS);

    // VQ approx (MFMA) + exact rescore
    vq_mfma<<<dim3(NCB, 128), 256, 0, stream>>>(Ae, Be, c2, part);
    vq_combine_rescore<<<NROWS / 4, 256, 0, stream>>>(part, enc, cw, c2, x2,
                                                      outIdx, outDist, idx32);

    // Decoder over codewords (MFMA): dec1 reuses Be as its A operand
    mm_split<2><<<dim3(2, 64), 256, 0, stream>>>(Be, dw1t, db1, nullptr, Gs, ENC_DIM);
    mm_split<3><<<dim3(8, 64), 256, 0, stream>>>(Gs, dw2t, db2, rec_all, nullptr, IN_DIM);

    // Gather final outputs
    gather_out<<<NROWS, 256, 0, stream>>>(idx32, rec_all, cw, outRec, outQ);
}

// Round 6
// 451.371 us; speedup vs baseline: 2.6610x; 1.2143x over previous
//
#include <hip/hip_runtime.h>
#include <hip/hip_bf16.h>

#define NROWS   16384
#define IN_DIM  1024
#define ENC_DIM 256
#define KCW     8192
#define NCB     64          // codeword col-blocks of 128

typedef __attribute__((ext_vector_type(8))) short short8v;
typedef __attribute__((ext_vector_type(4))) float f32x4;
typedef unsigned long long u64;

// ---------------------------------------------------------------------------
// helpers
// ---------------------------------------------------------------------------
__device__ __forceinline__ unsigned short f2bf_rne(float x) {
    unsigned u = __float_as_uint(x);
    unsigned r = (u + 0x7fffu + ((u >> 16) & 1u)) >> 16;
    return (unsigned short)r;
}
__device__ __forceinline__ float bf2f(unsigned short h) {
    return __uint_as_float(((unsigned)h) << 16);
}
__device__ __forceinline__ int lex_lt(float d, int i, float D, int I) {
    return (d < D) || (d == D && i < I);
}
// order-preserving float->uint, pack with col (low bits = first-occurrence tiebreak)
__device__ __forceinline__ u64 packkey(float d, int col) {
    unsigned u = __float_as_uint(d);
    u = (u & 0x80000000u) ? ~u : (u | 0x80000000u);
    return ((u64)u << 32) | (unsigned)col;
}
__device__ __forceinline__ void t2ins(u64& b1, u64& b2, u64 k) {
    u64 mx = (k > b1) ? k : b1;
    b1 = (k < b1) ? k : b1;
    b2 = (mx < b2) ? mx : b2;
}
__device__ __forceinline__ void t2mrg(u64& b1, u64& b2, u64 c1, u64 c2) {
    u64 hi = (b1 > c1) ? b1 : c1;
    u64 lo2 = (b2 < c2) ? b2 : c2;
    b1 = (b1 < c1) ? b1 : c1;
    b2 = (hi < lo2) ? hi : lo2;
}
__device__ __forceinline__ void gload16(const void* g, void* l) {
    __builtin_amdgcn_global_load_lds(
        (__attribute__((address_space(1))) void*)g,
        (__attribute__((address_space(3))) void*)l, 16, 0, 0);
}

// ---------------------------------------------------------------------------
// Row squared-norms (256-wide rows)
// ---------------------------------------------------------------------------
__global__ void rownorm2(const float* __restrict__ A, float* __restrict__ out,
                         int rows) {
    int gid = blockIdx.x * blockDim.x + threadIdx.x;
    int wid = gid >> 6, lane = gid & 63;
    if (wid >= rows) return;
    float4 v = *(const float4*)(A + (size_t)wid * 256 + lane * 4);
    float s = (v.x * v.x + v.y * v.y) + (v.z * v.z + v.w * v.w);
#pragma unroll
    for (int off = 1; off < 64; off <<= 1) s += __shfl_xor(s, off);
    if (lane == 0) out[wid] = s;
}

// ---------------------------------------------------------------------------
// splitK: fp32 [rows][K] -> swizzled bf16 hi|lo [rows][2K]
// (hi at k*2 bytes, lo at (K+k)*2; XOR ((row&7)<<4) within 128-byte chunks)
// ---------------------------------------------------------------------------
template<int K>
__global__ void splitK(const float* __restrict__ src,
                       unsigned short* __restrict__ dst, int n4) {
    int e = blockIdx.x * 256 + threadIdx.x;
    if (e >= n4) return;
    int row = e / (K / 4), kq = (e % (K / 4)) * 4;
    float4 v = ((const float4*)src)[e];
    ushort4 hi, lo;
    hi.x = f2bf_rne(v.x); lo.x = f2bf_rne(v.x - bf2f(hi.x));
    hi.y = f2bf_rne(v.y); lo.y = f2bf_rne(v.y - bf2f(hi.y));
    hi.z = f2bf_rne(v.z); lo.z = f2bf_rne(v.z - bf2f(hi.z));
    hi.w = f2bf_rne(v.w); lo.w = f2bf_rne(v.w - bf2f(hi.w));
    const int m = (row & 7) << 4;
    char* rowp = (char*)(dst + (size_t)row * (2 * K));
    int bh = kq * 2, bl = (K + kq) * 2;
    *(ushort4*)(rowp + ((bh & ~127) | ((bh & 127) ^ m))) = hi;
    *(ushort4*)(rowp + ((bl & ~127) | ((bl & 127) ^ m))) = lo;
}

// ---------------------------------------------------------------------------
// tsplitK: W[K][Ncols] fp32 -> Wt[Ncols][2K] swizzled bf16 hi|lo
// ---------------------------------------------------------------------------
template<int K>
__global__ void tsplitK(const float* __restrict__ W,
                        unsigned short* __restrict__ Wt, int Ncols) {
    int idx = blockIdx.x * 256 + threadIdx.x;
    if (idx >= Ncols * (K / 4)) return;
    int n = idx / (K / 4), k4 = (idx % (K / 4)) * 4;
    float vx = W[(size_t)(k4 + 0) * Ncols + n];
    float vy = W[(size_t)(k4 + 1) * Ncols + n];
    float vz = W[(size_t)(k4 + 2) * Ncols + n];
    float vw = W[(size_t)(k4 + 3) * Ncols + n];
    ushort4 hi, lo;
    hi.x = f2bf_rne(vx); lo.x = f2bf_rne(vx - bf2f(hi.x));
    hi.y = f2bf_rne(vy); lo.y = f2bf_rne(vy - bf2f(hi.y));
    hi.z = f2bf_rne(vz); lo.z = f2bf_rne(vz - bf2f(hi.z));
    hi.w = f2bf_rne(vw); lo.w = f2bf_rne(vw - bf2f(hi.w));
    const int m = (n & 7) << 4;
    char* rp = (char*)(Wt + (size_t)n * (2 * K));
    int bh = k4 * 2, bl = (K + k4) * 2;
    *(ushort4*)(rp + ((bh & ~127) | ((bh & 127) ^ m))) = hi;
    *(ushort4*)(rp + ((bl & ~127) | ((bl & 127) ^ m))) = lo;
}

// ---------------------------------------------------------------------------
// Split-bf16 MFMA GEMM: C = act(A@B^T + bias), K = 64*KQ via 3 terms
// (A_hi*B_hi + A_hi*B_lo + A_lo*B_hi), 128x128 tile, 4 waves, single-buffer.
// A[M][2K]u, Bt[N][2K]u swizzled splits; runtime row strides ars/brs/crs.
// EPI: 1 = relu, write C fp32 (width N) + Cs hi-only (crs, 256-col);
//      2 = relu, write Cs hi+lo (crs, 256-col);  3 = no relu, C fp32 only.
// ---------------------------------------------------------------------------
template<int EPI, int KQ>
__global__ __launch_bounds__(256)
void mm_split(const unsigned short* __restrict__ A,
              const unsigned short* __restrict__ Bt,
              const float* __restrict__ bias,
              float* __restrict__ C,
              unsigned short* __restrict__ Cs,
              int N, int ars, int brs, int crs) {
    __shared__ __align__(16) unsigned short As[128][64];
    __shared__ __align__(16) unsigned short Bs[128][64];
    const int tid = threadIdx.x;
    const int lane = tid & 63;
    const int wid = tid >> 6;
    const int wr = wid >> 1, wc = wid & 1;
    const int brow = blockIdx.y * 128;
    const int bcol = blockIdx.x * 128;
    constexpr int K = KQ * 64;

    f32x4 acc[4][4] = {};

    const int fr = tid >> 3;
    const int fk = (tid & 7) * 8;
    const int swz = (lane & 7) << 4;
    const int arow = wr * 64 + (lane & 15);
    const int brw  = wc * 64 + (lane & 15);
    const int klane = (lane >> 4) * 16;

    for (int s = 0; s < 3 * KQ; ++s) {
        const int term = s / KQ, kq = s % KQ;
        const int ka0 = (term == 2 ? K : 0) + kq * 64;
        const int kb0 = (term == 1 ? K : 0) + kq * 64;
        if (s) __syncthreads();
#pragma unroll
        for (int l = 0; l < 4; ++l) {
            gload16(A  + (size_t)(brow + l * 32 + fr) * ars + ka0 + fk,
                    (char*)&As[0][0] + l * 4096 + tid * 16);
            gload16(Bt + (size_t)(bcol + l * 32 + fr) * brs + kb0 + fk,
                    (char*)&Bs[0][0] + l * 4096 + tid * 16);
        }
        __syncthreads();
#pragma unroll
        for (int kk = 0; kk < 2; ++kk) {
            const int kb = (kk * 64 + klane) ^ swz;
            short8v af[4], bfv[4];
#pragma unroll
            for (int mi = 0; mi < 4; mi++)
                af[mi] = *(const short8v*)((const char*)&As[arow + mi * 16][0] + kb);
#pragma unroll
            for (int ni = 0; ni < 4; ni++)
                bfv[ni] = *(const short8v*)((const char*)&Bs[brw + ni * 16][0] + kb);
#pragma unroll
            for (int mi = 0; mi < 4; mi++)
#pragma unroll
                for (int ni = 0; ni < 4; ni++)
                    acc[mi][ni] = __builtin_amdgcn_mfma_f32_16x16x32_bf16(
                        af[mi], bfv[ni], acc[mi][ni], 0, 0, 0);
        }
    }

#pragma unroll
    for (int mi = 0; mi < 4; mi++) {
#pragma unroll
        for (int q = 0; q < 4; q++) {
            int row = brow + wr * 64 + mi * 16 + (lane >> 4) * 4 + q;
            const int m = (row & 7) << 4;
            char* rp = (char*)(Cs + (size_t)row * crs);
#pragma unroll
            for (int ni = 0; ni < 4; ni++) {
                int col = bcol + wc * 64 + ni * 16 + (lane & 15);
                float v = acc[mi][ni][q] + bias[col];
                if (EPI != 3) v = fmaxf(v, 0.f);
                if (EPI == 1 || EPI == 3) C[(size_t)row * N + col] = v;
                if (EPI == 1 || EPI == 2) {
                    unsigned short hi = f2bf_rne(v);
                    int bh = col * 2;
                    *(unsigned short*)(rp + ((bh & ~127) | ((bh & 127) ^ m))) = hi;
                    if (EPI == 2) {
                        unsigned short lo = f2bf_rne(v - bf2f(hi));
                        int bl = (256 + col) * 2;
                        *(unsigned short*)(rp + ((bl & ~127) | ((bl & 127) ^ m))) = lo;
                    }
                }
            }
        }
    }
}

// ---------------------------------------------------------------------------
// VQ MFMA kernel: HI-ONLY bf16 d2-key GEMM (K=256, 4 steps) + per-row top-2.
// Approx key error ~1e-2 << rank gaps (~10); exact top-2 rescore downstream.
// Ae compact hi-only [N][256]u (stride 256); Be hi at [0,256) of stride 512.
// ---------------------------------------------------------------------------
__global__ __launch_bounds__(256)
void vq_mfma(const unsigned short* __restrict__ Ae,
             const unsigned short* __restrict__ Be,
             const float* __restrict__ c2,
             ulonglong2* __restrict__ part) {
    __shared__ __align__(16) unsigned short As[128][64];
    __shared__ __align__(16) unsigned short Bs[128][64];
    __shared__ u64 s1[128][2];
    __shared__ u64 s2[128][2];

    const int tid  = threadIdx.x;
    const int lane = tid & 63;
    const int wid  = tid >> 6;
    const int wr   = wid >> 1, wc = wid & 1;
    const int brow = blockIdx.y * 128;
    const int bcol = blockIdx.x * 128;

    f32x4 acc[4][4] = {};

    const int fr = tid >> 3;
    const int fk = (tid & 7) * 8;
    const int swz   = (lane & 7) << 4;
    const int arow  = wr * 64 + (lane & 15);
    const int brw   = wc * 64 + (lane & 15);
    const int klane = (lane >> 4) * 16;

    for (int s = 0; s < 4; ++s) {
        const int k0 = s * 64;
        if (s) __syncthreads();
#pragma unroll
        for (int l = 0; l < 4; ++l) {
            gload16(Ae + (size_t)(brow + l * 32 + fr) * 256 + k0 + fk,
                    (char*)&As[0][0] + l * 4096 + tid * 16);
            gload16(Be + (size_t)(bcol + l * 32 + fr) * 512 + k0 + fk,
                    (char*)&Bs[0][0] + l * 4096 + tid * 16);
        }
        __syncthreads();
#pragma unroll
        for (int kk = 0; kk < 2; ++kk) {
            const int kb = (kk * 64 + klane) ^ swz;
            short8v af[4], bfv[4];
#pragma unroll
            for (int mi = 0; mi < 4; mi++)
                af[mi] = *(const short8v*)((const char*)&As[arow + mi * 16][0] + kb);
#pragma unroll
            for (int ni = 0; ni < 4; ni++)
                bfv[ni] = *(const short8v*)((const char*)&Bs[brw + ni * 16][0] + kb);
#pragma unroll
            for (int mi = 0; mi < 4; mi++)
#pragma unroll
                for (int ni = 0; ni < 4; ni++)
                    acc[mi][ni] = __builtin_amdgcn_mfma_f32_16x16x32_bf16(
                        af[mi], bfv[ni], acc[mi][ni], 0, 0, 0);
        }
    }

    // ---- epilogue: branchless per-row top-2 over this block's 128 cols ----
    float c2v[4];
#pragma unroll
    for (int ni = 0; ni < 4; ni++)
        c2v[ni] = c2[bcol + wc * 64 + ni * 16 + (lane & 15)];

#pragma unroll
    for (int mi = 0; mi < 4; mi++) {
#pragma unroll
        for (int q = 0; q < 4; q++) {
            u64 b1 = ~0ull, b2 = ~0ull;
#pragma unroll
            for (int ni = 0; ni < 4; ni++) {
                float dk  = fmaf(-2.0f, acc[mi][ni][q], c2v[ni]);
                int   col = bcol + wc * 64 + ni * 16 + (lane & 15);
                t2ins(b1, b2, packkey(dk, col));
            }
#pragma unroll
            for (int off = 1; off < 16; off <<= 1) {
                u64 c1 = __shfl_xor(b1, off);
                u64 cc2 = __shfl_xor(b2, off);
                t2mrg(b1, b2, c1, cc2);
            }
            if ((lane & 15) == 0) {
                int rl = wr * 64 + mi * 16 + (lane >> 4) * 4 + q;
                s1[rl][wc] = b1;
                s2[rl][wc] = b2;
            }
        }
    }
    __syncthreads();
    if (tid < 128) {
        u64 b1 = s1[tid][0], b2 = s2[tid][0];
        t2mrg(b1, b2, s1[tid][1], s2[tid][1]);
        ulonglong2 pk;
        pk.x = b1; pk.y = b2;
        part[(size_t)(brow + tid) * NCB + blockIdx.x] = pk;
    }
}

// ---------------------------------------------------------------------------
// Combine per-colblock top-2s -> global approx top-2 -> exact fp32 rescore.
// ---------------------------------------------------------------------------
__global__ __launch_bounds__(256)
void vq_combine_rescore(const ulonglong2* __restrict__ part,
                        const float* __restrict__ enc,
                        const float* __restrict__ cw,
                        const float* __restrict__ c2,
                        const float* __restrict__ x2,
                        float* __restrict__ outIdx,
                        float* __restrict__ outDist,
                        int* __restrict__ idx32) {
    const int row  = blockIdx.x * 4 + (threadIdx.x >> 6);
    const int lane = threadIdx.x & 63;

    ulonglong2 pk = part[(size_t)row * NCB + lane];
    u64 b1 = pk.x, b2 = pk.y;
#pragma unroll
    for (int off = 1; off < 64; off <<= 1) {
        u64 c1 = __shfl_xor(b1, off);
        u64 cc2 = __shfl_xor(b2, off);
        t2mrg(b1, b2, c1, cc2);
    }
    int j1 = (int)(b1 & 0xffffffffu);
    int j2 = (int)(b2 & 0xffffffffu);

    float4 e4 = ((const float4*)(enc + (size_t)row * 256))[lane];
    float4 w1 = ((const float4*)(cw + (size_t)j1 * 256))[lane];
    float4 w2 = ((const float4*)(cw + (size_t)j2 * 256))[lane];
    float s1 = fmaf(e4.x, w1.x, fmaf(e4.y, w1.y, fmaf(e4.z, w1.z, e4.w * w1.w)));
    float s2 = fmaf(e4.x, w2.x, fmaf(e4.y, w2.y, fmaf(e4.z, w2.z, e4.w * w2.w)));
#pragma unroll
    for (int off = 1; off < 64; off <<= 1) {
        s1 += __shfl_xor(s1, off);
        s2 += __shfl_xor(s2, off);
    }
    float xv = x2[row];
    float d1 = sqrtf(fmaxf(xv + c2[j1] - 2.0f * s1, 0.f));
    float d2 = sqrtf(fmaxf(xv + c2[j2] - 2.0f * s2, 0.f));
    float bd; int bi;
    if (lex_lt(d1, j1, d2, j2)) { bd = d1; bi = j1; }
    else                        { bd = d2; bi = j2; }
    if (lane == 0) {
        outIdx[row]  = (float)bi;
        outDist[row] = bd;
        idx32[row]   = bi;
    }
}

// ---------------------------------------------------------------------------
// Gather decoded codewords + codewords into output rows.
// ---------------------------------------------------------------------------
__global__ void gather_out(const int* __restrict__ idx32,
                           const float* __restrict__ rec_all,
                           const float* __restrict__ cw,
                           float* __restrict__ outRec,
                           float* __restrict__ outQ) {
    int row = blockIdx.x;
    int j = idx32[row];
    const float4* src = (const float4*)(rec_all + (size_t)j * IN_DIM);
    float4* dst = (float4*)(outRec + (size_t)row * IN_DIM);
    dst[threadIdx.x] = src[threadIdx.x];
    if (threadIdx.x < 64) {
        ((float4*)(outQ + (size_t)row * ENC_DIM))[threadIdx.x] =
            ((const float4*)(cw + (size_t)j * ENC_DIM))[threadIdx.x];
    }
}

extern "C" void kernel_launch(void* const* d_in, const int* in_sizes, int n_in,
                              void* d_out, int out_size, void* d_ws, size_t ws_size,
                              hipStream_t stream) {
    const float* x   = (const float*)d_in[0];
    const float* ew1 = (const float*)d_in[1];
    const float* eb1 = (const float*)d_in[2];
    const float* ew2 = (const float*)d_in[3];
    const float* eb2 = (const float*)d_in[4];
    const float* cw  = (const float*)d_in[5];
    const float* dw1 = (const float*)d_in[6];
    const float* db1 = (const float*)d_in[7];
    const float* dw2 = (const float*)d_in[8];
    const float* db2 = (const float*)d_in[9];
    float* out = (float*)d_out;
    float* ws  = (float*)d_ws;

    // workspace (float offsets), phase-aliased (~61.5 MB total):
    //  [0,        8388608)  xs half-split (enc1) -> enc[0,4.19M)+Ae[4.19M,6.29M) -> rec_all (dec2+)
    //  [8388608, 12582912)  Hs (enc1->enc2) -> part (vq->rescore); Gs [8.39M,10.49M) (dec1->dec2)
    //  [12582912,14680064)  Be (prep->dec1)
    //  [14680064,14942208)  w1ts   [14942208,15007744) ew2t
    //  [15007744,15073280)  dw1t   [15073280,15335424) dw2t
    //  [15335424,...]       c2, x2, idx32
    unsigned short* xs      = (unsigned short*)ws;
    float*          enc     = ws;
    float*          rec_all = ws;
    unsigned short* Ae      = (unsigned short*)(ws + 4194304);
    unsigned short* Hs      = (unsigned short*)(ws + 8388608);
    ulonglong2*     part    = (ulonglong2*)(ws + 8388608);
    unsigned short* Gs      = (unsigned short*)(ws + 8388608);
    unsigned short* Be      = (unsigned short*)(ws + 12582912);
    unsigned short* w1ts    = (unsigned short*)(ws + 14680064);
    unsigned short* ew2t    = (unsigned short*)(ws + 14942208);
    unsigned short* dw1t    = (unsigned short*)(ws + 15007744);
    unsigned short* dw2t    = (unsigned short*)(ws + 15073280);
    float*          c2      = ws + 15335424;
    float*          x2      = ws + 15343616;
    int*            idx32   = (int*)(ws + 15360000);

    float* outIdx  = out;
    float* outDist = out + NROWS;
    float* outRec  = out + 2 * NROWS;
    float* outQ    = out + 2 * NROWS + (size_t)NROWS * IN_DIM;

    // Prep: weight transpose-splits, codeword split, c2
    tsplitK<1024><<<256, 256, 0, stream>>>(ew1, w1ts, 256);
    tsplitK<256><<<64, 256, 0, stream>>>(ew2, ew2t, 256);
    tsplitK<256><<<64, 256, 0, stream>>>(dw1, dw1t, 256);
    tsplitK<256><<<256, 256, 0, stream>>>(dw2, dw2t, 1024);
    splitK<256><<<(KCW * 64) / 256, 256, 0, stream>>>(cw, Be, KCW * 64);
    rownorm2<<<KCW / 4, 256, 0, stream>>>(cw, c2, KCW);

    // Encoder layer 1 (split-bf16 MFMA, two 8192-row halves reusing xs)
    splitK<1024><<<8192, 256, 0, stream>>>(x, xs, 8192 * 256);
    mm_split<2, 16><<<dim3(2, 64), 256, 0, stream>>>(
        xs, w1ts, eb1, nullptr, Hs, 256, 2048, 2048, 512);
    splitK<1024><<<8192, 256, 0, stream>>>(x + (size_t)8192 * 1024, xs, 8192 * 256);
    mm_split<2, 16><<<dim3(2, 64), 256, 0, stream>>>(
        xs, w1ts, eb1, nullptr, Hs + (size_t)8192 * 512, 256, 2048, 2048, 512);

    // Encoder layer 2: enc fp32 + compact hi-only Ae
    mm_split<1, 4><<<dim3(2, 128), 256, 0, stream>>>(
        Hs, ew2t, eb2, enc, Ae, 256, 512, 512, 256);
    rownorm2<<<NROWS / 4, 256, 0, stream>>>(enc, x2, NROWS);

    // VQ approx (hi-only MFMA) + exact rescore
    vq_mfma<<<dim3(NCB, 128), 256, 0, stream>>>(Ae, Be, c2, part);
    vq_combine_rescore<<<NROWS / 4, 256, 0, stream>>>(part, enc, cw, c2, x2,
                                                      outIdx, outDist, idx32);

    // Decoder over codewords: dec1 reuses Be as its A operand
    mm_split<2, 4><<<dim3(2, 64), 256, 0, stream>>>(
        Be, dw1t, db1, nullptr, Gs, 256, 512, 512, 512);
    mm_split<3, 4><<<dim3(8, 64), 256, 0, stream>>>(
        Gs, dw2t, db2, rec_all, nullptr, 1024, 512, 512, 0);

    // Gather final outputs
    gather_out<<<NROWS, 256, 0, stream>>>(idx32, rec_all, cw, outRec, outQ);
}

// Round 7
// 360.456 us; speedup vs baseline: 3.3322x; 1.2522x over previous
//
#include <hip/hip_runtime.h>
#include <hip/hip_bf16.h>

#define NROWS   16384
#define IN_DIM  1024
#define ENC_DIM 256
#define KCW     8192
#define NCB     64          // codeword col-blocks of 128

typedef __attribute__((ext_vector_type(8))) short short8v;
typedef __attribute__((ext_vector_type(4))) float f32x4;
typedef unsigned long long u64;
typedef unsigned int u32;

// ---------------------------------------------------------------------------
// helpers
// ---------------------------------------------------------------------------
__device__ __forceinline__ unsigned short f2bf_rne(float x) {
    unsigned u = __float_as_uint(x);
    unsigned r = (u + 0x7fffu + ((u >> 16) & 1u)) >> 16;
    return (unsigned short)r;
}
__device__ __forceinline__ float bf2f(unsigned short h) {
    return __uint_as_float(((unsigned)h) << 16);
}
__device__ __forceinline__ int lex_lt(float d, int i, float D, int I) {
    return (d < D) || (d == D && i < I);
}
// u64 top-2 merge (combine kernel only)
__device__ __forceinline__ void t2mrg(u64& b1, u64& b2, u64 c1, u64 c2) {
    u64 hi = (b1 > c1) ? b1 : c1;
    u64 lo2 = (b2 < c2) ? b2 : c2;
    b1 = (b1 < c1) ? b1 : c1;
    b2 = (hi < lo2) ? hi : lo2;
}
__device__ __forceinline__ void gload16(const void* g, void* l) {
    __builtin_amdgcn_global_load_lds(
        (__attribute__((address_space(1))) void*)g,
        (__attribute__((address_space(3))) void*)l, 16, 0, 0);
}

// ---------------------------------------------------------------------------
// Row squared-norms (256-wide rows) — codewords only
// ---------------------------------------------------------------------------
__global__ void rownorm2(const float* __restrict__ A, float* __restrict__ out,
                         int rows) {
    int gid = blockIdx.x * blockDim.x + threadIdx.x;
    int wid = gid >> 6, lane = gid & 63;
    if (wid >= rows) return;
    float4 v = *(const float4*)(A + (size_t)wid * 256 + lane * 4);
    float s = (v.x * v.x + v.y * v.y) + (v.z * v.z + v.w * v.w);
#pragma unroll
    for (int off = 1; off < 64; off <<= 1) s += __shfl_xor(s, off);
    if (lane == 0) out[wid] = s;
}

// ---------------------------------------------------------------------------
// splitK: fp32 [rows][K] -> swizzled bf16 hi|lo [rows][2K]
// ---------------------------------------------------------------------------
template<int K>
__global__ void splitK(const float* __restrict__ src,
                       unsigned short* __restrict__ dst, int n4) {
    int e = blockIdx.x * 256 + threadIdx.x;
    if (e >= n4) return;
    int row = e / (K / 4), kq = (e % (K / 4)) * 4;
    float4 v = ((const float4*)src)[e];
    ushort4 hi, lo;
    hi.x = f2bf_rne(v.x); lo.x = f2bf_rne(v.x - bf2f(hi.x));
    hi.y = f2bf_rne(v.y); lo.y = f2bf_rne(v.y - bf2f(hi.y));
    hi.z = f2bf_rne(v.z); lo.z = f2bf_rne(v.z - bf2f(hi.z));
    hi.w = f2bf_rne(v.w); lo.w = f2bf_rne(v.w - bf2f(hi.w));
    const int m = (row & 7) << 4;
    char* rowp = (char*)(dst + (size_t)row * (2 * K));
    int bh = kq * 2, bl = (K + kq) * 2;
    *(ushort4*)(rowp + ((bh & ~127) | ((bh & 127) ^ m))) = hi;
    *(ushort4*)(rowp + ((bl & ~127) | ((bl & 127) ^ m))) = lo;
}

// ---------------------------------------------------------------------------
// tsplitK: W[K][Ncols] fp32 -> Wt[Ncols][2K] swizzled bf16 hi|lo
// ---------------------------------------------------------------------------
template<int K>
__global__ void tsplitK(const float* __restrict__ W,
                        unsigned short* __restrict__ Wt, int Ncols) {
    int idx = blockIdx.x * 256 + threadIdx.x;
    if (idx >= Ncols * (K / 4)) return;
    int n = idx / (K / 4), k4 = (idx % (K / 4)) * 4;
    float vx = W[(size_t)(k4 + 0) * Ncols + n];
    float vy = W[(size_t)(k4 + 1) * Ncols + n];
    float vz = W[(size_t)(k4 + 2) * Ncols + n];
    float vw = W[(size_t)(k4 + 3) * Ncols + n];
    ushort4 hi, lo;
    hi.x = f2bf_rne(vx); lo.x = f2bf_rne(vx - bf2f(hi.x));
    hi.y = f2bf_rne(vy); lo.y = f2bf_rne(vy - bf2f(hi.y));
    hi.z = f2bf_rne(vz); lo.z = f2bf_rne(vz - bf2f(hi.z));
    hi.w = f2bf_rne(vw); lo.w = f2bf_rne(vw - bf2f(hi.w));
    const int m = (n & 7) << 4;
    char* rp = (char*)(Wt + (size_t)n * (2 * K));
    int bh = k4 * 2, bl = (K + k4) * 2;
    *(ushort4*)(rp + ((bh & ~127) | ((bh & 127) ^ m))) = hi;
    *(ushort4*)(rp + ((bl & ~127) | ((bl & 127) ^ m))) = lo;
}

// ---------------------------------------------------------------------------
// Split-bf16 MFMA GEMM: C = act(A@B^T + bias), K = 64*KQ via 3 terms.
// EPI: 1 = relu, C fp32 + Cs hi-only;  2 = relu, Cs hi+lo;  3 = C fp32 only.
// ---------------------------------------------------------------------------
template<int EPI, int KQ>
__global__ __launch_bounds__(256)
void mm_split(const unsigned short* __restrict__ A,
              const unsigned short* __restrict__ Bt,
              const float* __restrict__ bias,
              float* __restrict__ C,
              unsigned short* __restrict__ Cs,
              int N, int ars, int brs, int crs) {
    __shared__ __align__(16) unsigned short As[128][64];
    __shared__ __align__(16) unsigned short Bs[128][64];
    const int tid = threadIdx.x;
    const int lane = tid & 63;
    const int wid = tid >> 6;
    const int wr = wid >> 1, wc = wid & 1;
    const int brow = blockIdx.y * 128;
    const int bcol = blockIdx.x * 128;
    constexpr int K = KQ * 64;

    f32x4 acc[4][4] = {};

    const int fr = tid >> 3;
    const int fk = (tid & 7) * 8;
    const int swz = (lane & 7) << 4;
    const int arow = wr * 64 + (lane & 15);
    const int brw  = wc * 64 + (lane & 15);
    const int klane = (lane >> 4) * 16;

    for (int s = 0; s < 3 * KQ; ++s) {
        const int term = s / KQ, kq = s % KQ;
        const int ka0 = (term == 2 ? K : 0) + kq * 64;
        const int kb0 = (term == 1 ? K : 0) + kq * 64;
        if (s) __syncthreads();
#pragma unroll
        for (int l = 0; l < 4; ++l) {
            gload16(A  + (size_t)(brow + l * 32 + fr) * ars + ka0 + fk,
                    (char*)&As[0][0] + l * 4096 + tid * 16);
            gload16(Bt + (size_t)(bcol + l * 32 + fr) * brs + kb0 + fk,
                    (char*)&Bs[0][0] + l * 4096 + tid * 16);
        }
        __syncthreads();
#pragma unroll
        for (int kk = 0; kk < 2; ++kk) {
            const int kb = (kk * 64 + klane) ^ swz;
            short8v af[4], bfv[4];
#pragma unroll
            for (int mi = 0; mi < 4; mi++)
                af[mi] = *(const short8v*)((const char*)&As[arow + mi * 16][0] + kb);
#pragma unroll
            for (int ni = 0; ni < 4; ni++)
                bfv[ni] = *(const short8v*)((const char*)&Bs[brw + ni * 16][0] + kb);
#pragma unroll
            for (int mi = 0; mi < 4; mi++)
#pragma unroll
                for (int ni = 0; ni < 4; ni++)
                    acc[mi][ni] = __builtin_amdgcn_mfma_f32_16x16x32_bf16(
                        af[mi], bfv[ni], acc[mi][ni], 0, 0, 0);
        }
    }

#pragma unroll
    for (int mi = 0; mi < 4; mi++) {
#pragma unroll
        for (int q = 0; q < 4; q++) {
            int row = brow + wr * 64 + mi * 16 + (lane >> 4) * 4 + q;
            const int m = (row & 7) << 4;
            char* rp = (char*)(Cs + (size_t)row * crs);
#pragma unroll
            for (int ni = 0; ni < 4; ni++) {
                int col = bcol + wc * 64 + ni * 16 + (lane & 15);
                float v = acc[mi][ni][q] + bias[col];
                if (EPI != 3) v = fmaxf(v, 0.f);
                if (EPI == 1 || EPI == 3) C[(size_t)row * N + col] = v;
                if (EPI == 1 || EPI == 2) {
                    unsigned short hi = f2bf_rne(v);
                    int bh = col * 2;
                    *(unsigned short*)(rp + ((bh & ~127) | ((bh & 127) ^ m))) = hi;
                    if (EPI == 2) {
                        unsigned short lo = f2bf_rne(v - bf2f(hi));
                        int bl = (256 + col) * 2;
                        *(unsigned short*)(rp + ((bl & ~127) | ((bl & 127) ^ m))) = lo;
                    }
                }
            }
        }
    }
}

// ---------------------------------------------------------------------------
// VQ MFMA kernel: HI-ONLY bf16 d2-key GEMM (K=256) + per-row top-2.
// u32 packed key: f32 bits of (c2-2dot) [provably positive] with low 7
// mantissa bits replaced by the local col -> bit order = (key, col) lex
// order, quantization ~0.004 << bf16 key error 0.05. Top-2 insert = 3 u32
// min/max; 32-bit shfl merges. Exact fp32 rescore downstream fixes ordering.
// ---------------------------------------------------------------------------
__global__ __launch_bounds__(256)
void vq_mfma(const unsigned short* __restrict__ Ae,
             const unsigned short* __restrict__ Be,
             const float* __restrict__ c2,
             ulonglong2* __restrict__ part) {
    __shared__ __align__(16) unsigned short As[128][64];
    __shared__ __align__(16) unsigned short Bs[128][64];
    __shared__ u32 s1[128][2];
    __shared__ u32 s2[128][2];

    const int tid  = threadIdx.x;
    const int lane = tid & 63;
    const int wid  = tid >> 6;
    const int wr   = wid >> 1, wc = wid & 1;
    const int brow = blockIdx.y * 128;
    const int bcol = blockIdx.x * 128;

    f32x4 acc[4][4] = {};

    const int fr = tid >> 3;
    const int fk = (tid & 7) * 8;
    const int swz   = (lane & 7) << 4;
    const int arow  = wr * 64 + (lane & 15);
    const int brw   = wc * 64 + (lane & 15);
    const int klane = (lane >> 4) * 16;

    for (int s = 0; s < 4; ++s) {
        const int k0 = s * 64;
        if (s) __syncthreads();
#pragma unroll
        for (int l = 0; l < 4; ++l) {
            gload16(Ae + (size_t)(brow + l * 32 + fr) * 256 + k0 + fk,
                    (char*)&As[0][0] + l * 4096 + tid * 16);
            gload16(Be + (size_t)(bcol + l * 32 + fr) * 512 + k0 + fk,
                    (char*)&Bs[0][0] + l * 4096 + tid * 16);
        }
        __syncthreads();
#pragma unroll
        for (int kk = 0; kk < 2; ++kk) {
            const int kb = (kk * 64 + klane) ^ swz;
            short8v af[4], bfv[4];
#pragma unroll
            for (int mi = 0; mi < 4; mi++)
                af[mi] = *(const short8v*)((const char*)&As[arow + mi * 16][0] + kb);
#pragma unroll
            for (int ni = 0; ni < 4; ni++)
                bfv[ni] = *(const short8v*)((const char*)&Bs[brw + ni * 16][0] + kb);
#pragma unroll
            for (int mi = 0; mi < 4; mi++)
#pragma unroll
                for (int ni = 0; ni < 4; ni++)
                    acc[mi][ni] = __builtin_amdgcn_mfma_f32_16x16x32_bf16(
                        af[mi], bfv[ni], acc[mi][ni], 0, 0, 0);
        }
    }

    // ---- epilogue: u32-packed per-row top-2 over this block's 128 cols ----
    float c2v[4];
#pragma unroll
    for (int ni = 0; ni < 4; ni++)
        c2v[ni] = c2[bcol + wc * 64 + ni * 16 + (lane & 15)];
    const u32 lcbase = (u32)(wc * 64 + (lane & 15));

#pragma unroll
    for (int mi = 0; mi < 4; mi++) {
#pragma unroll
        for (int q = 0; q < 4; q++) {
            u32 b1 = 0xFFFFFFFFu, b2 = 0xFFFFFFFFu;
#pragma unroll
            for (int ni = 0; ni < 4; ni++) {
                float dk = fmaf(-2.0f, acc[mi][ni][q], c2v[ni]);
                dk = fmaxf(dk, 0.0f);                        // keep bit-order valid
                u32 k = (__float_as_uint(dk) & ~127u) | (lcbase + ni * 16);
                u32 mx = max(k, b1);
                b1 = min(k, b1);
                b2 = min(mx, b2);
            }
#pragma unroll
            for (int off = 1; off < 16; off <<= 1) {
                u32 o1 = __shfl_xor(b1, off);
                u32 o2 = __shfl_xor(b2, off);
                u32 mx = max(b1, o1);
                b1 = min(b1, o1);
                b2 = min(min(b2, o2), mx);
            }
            if ((lane & 15) == 0) {
                int rl = wr * 64 + mi * 16 + (lane >> 4) * 4 + q;
                s1[rl][wc] = b1;
                s2[rl][wc] = b2;
            }
        }
    }
    __syncthreads();
    if (tid < 128) {
        u32 a1 = s1[tid][0], a2 = s2[tid][0];
        u32 c1 = s1[tid][1], cc2 = s2[tid][1];
        u32 mx = max(a1, c1);
        u32 b1 = min(a1, c1);
        u32 b2 = min(min(a2, cc2), mx);
        ulonglong2 pk;
        pk.x = ((u64)b1 << 32) | (u32)(bcol + (b1 & 127u));
        pk.y = ((u64)b2 << 32) | (u32)(bcol + (b2 & 127u));
        part[(size_t)(brow + tid) * NCB + blockIdx.x] = pk;
    }
}

// ---------------------------------------------------------------------------
// Combine per-colblock top-2s -> global approx top-2 -> exact fp32 rescore.
// Also computes x2 (same reduction tree as rownorm2) from the enc row.
// ---------------------------------------------------------------------------
__global__ __launch_bounds__(256)
void vq_combine_rescore(const ulonglong2* __restrict__ part,
                        const float* __restrict__ enc,
                        const float* __restrict__ cw,
                        const float* __restrict__ c2,
                        float* __restrict__ outIdx,
                        float* __restrict__ outDist,
                        int* __restrict__ idx32) {
    const int row  = blockIdx.x * 4 + (threadIdx.x >> 6);
    const int lane = threadIdx.x & 63;

    ulonglong2 pk = part[(size_t)row * NCB + lane];
    u64 b1 = pk.x, b2 = pk.y;
#pragma unroll
    for (int off = 1; off < 64; off <<= 1) {
        u64 c1 = __shfl_xor(b1, off);
        u64 cc2 = __shfl_xor(b2, off);
        t2mrg(b1, b2, c1, cc2);
    }
    int j1 = (int)(b1 & 0xffffffffu);
    int j2 = (int)(b2 & 0xffffffffu);

    float4 e4 = ((const float4*)(enc + (size_t)row * 256))[lane];
    float4 w1 = ((const float4*)(cw + (size_t)j1 * 256))[lane];
    float4 w2 = ((const float4*)(cw + (size_t)j2 * 256))[lane];
    float s1 = fmaf(e4.x, w1.x, fmaf(e4.y, w1.y, fmaf(e4.z, w1.z, e4.w * w1.w)));
    float s2 = fmaf(e4.x, w2.x, fmaf(e4.y, w2.y, fmaf(e4.z, w2.z, e4.w * w2.w)));
    float sx = (e4.x * e4.x + e4.y * e4.y) + (e4.z * e4.z + e4.w * e4.w);
#pragma unroll
    for (int off = 1; off < 64; off <<= 1) {
        s1 += __shfl_xor(s1, off);
        s2 += __shfl_xor(s2, off);
        sx += __shfl_xor(sx, off);
    }
    float d1 = sqrtf(fmaxf(sx + c2[j1] - 2.0f * s1, 0.f));
    float d2 = sqrtf(fmaxf(sx + c2[j2] - 2.0f * s2, 0.f));
    float bd; int bi;
    if (lex_lt(d1, j1, d2, j2)) { bd = d1; bi = j1; }
    else                        { bd = d2; bi = j2; }
    if (lane == 0) {
        outIdx[row]  = (float)bi;
        outDist[row] = bd;
        idx32[row]   = bi;
    }
}

// ---------------------------------------------------------------------------
// Gather decoded codewords + codewords into output rows.
// ---------------------------------------------------------------------------
__global__ void gather_out(const int* __restrict__ idx32,
                           const float* __restrict__ rec_all,
                           const float* __restrict__ cw,
                           float* __restrict__ outRec,
                           float* __restrict__ outQ) {
    int row = blockIdx.x;
    int j = idx32[row];
    const float4* src = (const float4*)(rec_all + (size_t)j * IN_DIM);
    float4* dst = (float4*)(outRec + (size_t)row * IN_DIM);
    dst[threadIdx.x] = src[threadIdx.x];
    if (threadIdx.x < 64) {
        ((float4*)(outQ + (size_t)row * ENC_DIM))[threadIdx.x] =
            ((const float4*)(cw + (size_t)j * ENC_DIM))[threadIdx.x];
    }
}

extern "C" void kernel_launch(void* const* d_in, const int* in_sizes, int n_in,
                              void* d_out, int out_size, void* d_ws, size_t ws_size,
                              hipStream_t stream) {
    const float* x   = (const float*)d_in[0];
    const float* ew1 = (const float*)d_in[1];
    const float* eb1 = (const float*)d_in[2];
    const float* ew2 = (const float*)d_in[3];
    const float* eb2 = (const float*)d_in[4];
    const float* cw  = (const float*)d_in[5];
    const float* dw1 = (const float*)d_in[6];
    const float* db1 = (const float*)d_in[7];
    const float* dw2 = (const float*)d_in[8];
    const float* db2 = (const float*)d_in[9];
    float* out = (float*)d_out;
    float* ws  = (float*)d_ws;

    unsigned short* xs      = (unsigned short*)ws;
    float*          enc     = ws;
    float*          rec_all = ws;
    unsigned short* Ae      = (unsigned short*)(ws + 4194304);
    unsigned short* Hs      = (unsigned short*)(ws + 8388608);
    ulonglong2*     part    = (ulonglong2*)(ws + 8388608);
    unsigned short* Gs      = (unsigned short*)(ws + 8388608);
    unsigned short* Be      = (unsigned short*)(ws + 12582912);
    unsigned short* w1ts    = (unsigned short*)(ws + 14680064);
    unsigned short* ew2t    = (unsigned short*)(ws + 14942208);
    unsigned short* dw1t    = (unsigned short*)(ws + 15007744);
    unsigned short* dw2t    = (unsigned short*)(ws + 15073280);
    float*          c2      = ws + 15335424;
    int*            idx32   = (int*)(ws + 15343616);

    float* outIdx  = out;
    float* outDist = out + NROWS;
    float* outRec  = out + 2 * NROWS;
    float* outQ    = out + 2 * NROWS + (size_t)NROWS * IN_DIM;

    // Prep: weight transpose-splits, codeword split, c2
    tsplitK<1024><<<256, 256, 0, stream>>>(ew1, w1ts, 256);
    tsplitK<256><<<64, 256, 0, stream>>>(ew2, ew2t, 256);
    tsplitK<256><<<64, 256, 0, stream>>>(dw1, dw1t, 256);
    tsplitK<256><<<256, 256, 0, stream>>>(dw2, dw2t, 1024);
    splitK<256><<<(KCW * 64) / 256, 256, 0, stream>>>(cw, Be, KCW * 64);
    rownorm2<<<KCW / 4, 256, 0, stream>>>(cw, c2, KCW);

    // Encoder layer 1 (split-bf16 MFMA, two 8192-row halves reusing xs)
    splitK<1024><<<8192, 256, 0, stream>>>(x, xs, 8192 * 256);
    mm_split<2, 16><<<dim3(2, 64), 256, 0, stream>>>(
        xs, w1ts, eb1, nullptr, Hs, 256, 2048, 2048, 512);
    splitK<1024><<<8192, 256, 0, stream>>>(x + (size_t)8192 * 1024, xs, 8192 * 256);
    mm_split<2, 16><<<dim3(2, 64), 256, 0, stream>>>(
        xs, w1ts, eb1, nullptr, Hs + (size_t)8192 * 512, 256, 2048, 2048, 512);

    // Encoder layer 2: enc fp32 + compact hi-only Ae
    mm_split<1, 4><<<dim3(2, 128), 256, 0, stream>>>(
        Hs, ew2t, eb2, enc, Ae, 256, 512, 512, 256);

    // VQ approx (hi-only MFMA, u32-packed top-2) + exact rescore (fused x2)
    vq_mfma<<<dim3(NCB, 128), 256, 0, stream>>>(Ae, Be, c2, part);
    vq_combine_rescore<<<NROWS / 4, 256, 0, stream>>>(part, enc, cw, c2,
                                                      outIdx, outDist, idx32);

    // Decoder over codewords: dec1 reuses Be as its A operand
    mm_split<2, 4><<<dim3(2, 64), 256, 0, stream>>>(
        Be, dw1t, db1, nullptr, Gs, 256, 512, 512, 512);
    mm_split<3, 4><<<dim3(8, 64), 256, 0, stream>>>(
        Gs, dw2t, db2, rec_all, nullptr, 1024, 512, 512, 0);

    // Gather final outputs
    gather_out<<<NROWS, 256, 0, stream>>>(idx32, rec_all, cw, outRec, outQ);
}

// Round 8
// 270.384 us; speedup vs baseline: 4.4422x; 1.3331x over previous
//
#include <hip/hip_runtime.h>
#include <hip/hip_bf16.h>

#define NROWS   16384
#define IN_DIM  1024
#define ENC_DIM 256
#define KCW     8192
#define NCB     64          // codeword col-blocks of 128

typedef __attribute__((ext_vector_type(8))) short short8v;
typedef __attribute__((ext_vector_type(4))) float f32x4;
typedef unsigned long long u64;
typedef unsigned int u32;

// ---------------------------------------------------------------------------
// helpers
// ---------------------------------------------------------------------------
__device__ __forceinline__ unsigned short f2bf_rne(float x) {
    unsigned u = __float_as_uint(x);
    unsigned r = (u + 0x7fffu + ((u >> 16) & 1u)) >> 16;
    return (unsigned short)r;
}
__device__ __forceinline__ float bf2f(unsigned short h) {
    return __uint_as_float(((unsigned)h) << 16);
}
__device__ __forceinline__ int lex_lt(float d, int i, float D, int I) {
    return (d < D) || (d == D && i < I);
}
// u64 top-2 merge (combine kernel only)
__device__ __forceinline__ void t2mrg(u64& b1, u64& b2, u64 c1, u64 c2) {
    u64 hi = (b1 > c1) ? b1 : c1;
    u64 lo2 = (b2 < c2) ? b2 : c2;
    b1 = (b1 < c1) ? b1 : c1;
    b2 = (hi < lo2) ? hi : lo2;
}
__device__ __forceinline__ void gload16(const void* g, void* l) {
    __builtin_amdgcn_global_load_lds(
        (__attribute__((address_space(1))) void*)g,
        (__attribute__((address_space(3))) void*)l, 16, 0, 0);
}

// ---------------------------------------------------------------------------
// Row squared-norms (256-wide rows) — codewords only
// ---------------------------------------------------------------------------
__global__ void rownorm2(const float* __restrict__ A, float* __restrict__ out,
                         int rows) {
    int gid = blockIdx.x * blockDim.x + threadIdx.x;
    int wid = gid >> 6, lane = gid & 63;
    if (wid >= rows) return;
    float4 v = *(const float4*)(A + (size_t)wid * 256 + lane * 4);
    float s = (v.x * v.x + v.y * v.y) + (v.z * v.z + v.w * v.w);
#pragma unroll
    for (int off = 1; off < 64; off <<= 1) s += __shfl_xor(s, off);
    if (lane == 0) out[wid] = s;
}

// ---------------------------------------------------------------------------
// splitK: fp32 [rows][K] -> swizzled bf16 hi|lo [rows][2K]
// ---------------------------------------------------------------------------
template<int K>
__global__ void splitK(const float* __restrict__ src,
                       unsigned short* __restrict__ dst, int n4) {
    int e = blockIdx.x * 256 + threadIdx.x;
    if (e >= n4) return;
    int row = e / (K / 4), kq = (e % (K / 4)) * 4;
    float4 v = ((const float4*)src)[e];
    ushort4 hi, lo;
    hi.x = f2bf_rne(v.x); lo.x = f2bf_rne(v.x - bf2f(hi.x));
    hi.y = f2bf_rne(v.y); lo.y = f2bf_rne(v.y - bf2f(hi.y));
    hi.z = f2bf_rne(v.z); lo.z = f2bf_rne(v.z - bf2f(hi.z));
    hi.w = f2bf_rne(v.w); lo.w = f2bf_rne(v.w - bf2f(hi.w));
    const int m = (row & 7) << 4;
    char* rowp = (char*)(dst + (size_t)row * (2 * K));
    int bh = kq * 2, bl = (K + kq) * 2;
    *(ushort4*)(rowp + ((bh & ~127) | ((bh & 127) ^ m))) = hi;
    *(ushort4*)(rowp + ((bl & ~127) | ((bl & 127) ^ m))) = lo;
}

// ---------------------------------------------------------------------------
// tsplitK: W[K][Ncols] fp32 -> Wt[Ncols][2K] swizzled bf16 hi|lo
// ---------------------------------------------------------------------------
template<int K>
__global__ void tsplitK(const float* __restrict__ W,
                        unsigned short* __restrict__ Wt, int Ncols) {
    int idx = blockIdx.x * 256 + threadIdx.x;
    if (idx >= Ncols * (K / 4)) return;
    int n = idx / (K / 4), k4 = (idx % (K / 4)) * 4;
    float vx = W[(size_t)(k4 + 0) * Ncols + n];
    float vy = W[(size_t)(k4 + 1) * Ncols + n];
    float vz = W[(size_t)(k4 + 2) * Ncols + n];
    float vw = W[(size_t)(k4 + 3) * Ncols + n];
    ushort4 hi, lo;
    hi.x = f2bf_rne(vx); lo.x = f2bf_rne(vx - bf2f(hi.x));
    hi.y = f2bf_rne(vy); lo.y = f2bf_rne(vy - bf2f(hi.y));
    hi.z = f2bf_rne(vz); lo.z = f2bf_rne(vz - bf2f(hi.z));
    hi.w = f2bf_rne(vw); lo.w = f2bf_rne(vw - bf2f(hi.w));
    const int m = (n & 7) << 4;
    char* rp = (char*)(Wt + (size_t)n * (2 * K));
    int bh = k4 * 2, bl = (K + k4) * 2;
    *(ushort4*)(rp + ((bh & ~127) | ((bh & 127) ^ m))) = hi;
    *(ushort4*)(rp + ((bl & ~127) | ((bl & 127) ^ m))) = lo;
}

// ---------------------------------------------------------------------------
// Split-bf16 MFMA GEMM: C = act(A@B^T + bias), K = 64*KQ via 3 terms.
// EPI: 1 = relu, C fp32 + Cs hi-only;  2 = relu, Cs hi+lo;  3 = C fp32 only.
// ---------------------------------------------------------------------------
template<int EPI, int KQ>
__global__ __launch_bounds__(256)
void mm_split(const unsigned short* __restrict__ A,
              const unsigned short* __restrict__ Bt,
              const float* __restrict__ bias,
              float* __restrict__ C,
              unsigned short* __restrict__ Cs,
              int N, int ars, int brs, int crs) {
    __shared__ __align__(16) unsigned short As[128][64];
    __shared__ __align__(16) unsigned short Bs[128][64];
    const int tid = threadIdx.x;
    const int lane = tid & 63;
    const int wid = tid >> 6;
    const int wr = wid >> 1, wc = wid & 1;
    const int brow = blockIdx.y * 128;
    const int bcol = blockIdx.x * 128;
    constexpr int K = KQ * 64;

    f32x4 acc[4][4] = {};

    const int fr = tid >> 3;
    const int fk = (tid & 7) * 8;
    const int swz = (lane & 7) << 4;
    const int arow = wr * 64 + (lane & 15);
    const int brw  = wc * 64 + (lane & 15);
    const int klane = (lane >> 4) * 16;

    for (int s = 0; s < 3 * KQ; ++s) {
        const int term = s / KQ, kq = s % KQ;
        const int ka0 = (term == 2 ? K : 0) + kq * 64;
        const int kb0 = (term == 1 ? K : 0) + kq * 64;
        if (s) __syncthreads();
#pragma unroll
        for (int l = 0; l < 4; ++l) {
            gload16(A  + (size_t)(brow + l * 32 + fr) * ars + ka0 + fk,
                    (char*)&As[0][0] + l * 4096 + tid * 16);
            gload16(Bt + (size_t)(bcol + l * 32 + fr) * brs + kb0 + fk,
                    (char*)&Bs[0][0] + l * 4096 + tid * 16);
        }
        __syncthreads();
#pragma unroll
        for (int kk = 0; kk < 2; ++kk) {
            const int kb = (kk * 64 + klane) ^ swz;
            short8v af[4], bfv[4];
#pragma unroll
            for (int mi = 0; mi < 4; mi++)
                af[mi] = *(const short8v*)((const char*)&As[arow + mi * 16][0] + kb);
#pragma unroll
            for (int ni = 0; ni < 4; ni++)
                bfv[ni] = *(const short8v*)((const char*)&Bs[brw + ni * 16][0] + kb);
#pragma unroll
            for (int mi = 0; mi < 4; mi++)
#pragma unroll
                for (int ni = 0; ni < 4; ni++)
                    acc[mi][ni] = __builtin_amdgcn_mfma_f32_16x16x32_bf16(
                        af[mi], bfv[ni], acc[mi][ni], 0, 0, 0);
        }
    }

#pragma unroll
    for (int mi = 0; mi < 4; mi++) {
#pragma unroll
        for (int q = 0; q < 4; q++) {
            int row = brow + wr * 64 + mi * 16 + (lane >> 4) * 4 + q;
            const int m = (row & 7) << 4;
            char* rp = (char*)(Cs + (size_t)row * crs);
#pragma unroll
            for (int ni = 0; ni < 4; ni++) {
                int col = bcol + wc * 64 + ni * 16 + (lane & 15);
                float v = acc[mi][ni][q] + bias[col];
                if (EPI != 3) v = fmaxf(v, 0.f);
                if (EPI == 1 || EPI == 3) C[(size_t)row * N + col] = v;
                if (EPI == 1 || EPI == 2) {
                    unsigned short hi = f2bf_rne(v);
                    int bh = col * 2;
                    *(unsigned short*)(rp + ((bh & ~127) | ((bh & 127) ^ m))) = hi;
                    if (EPI == 2) {
                        unsigned short lo = f2bf_rne(v - bf2f(hi));
                        int bl = (256 + col) * 2;
                        *(unsigned short*)(rp + ((bl & ~127) | ((bl & 127) ^ m))) = lo;
                    }
                }
            }
        }
    }
}

// ---------------------------------------------------------------------------
// VQ MFMA kernel: HI-ONLY bf16 d2-key GEMM (K=256) + per-row top-2.
// SWAPPED-OPERAND MFMA: mfma(B,A) -> lane&15 = query row, (lane>>4)*4+reg =
// codeword. All 16 keys per (lane,row) are in-register -> 16 branchless u32
// inserts + only 2 shfl_xor rounds (off 16,32) per mi. u32 key = f32 bits of
// (c2-2dot, clamped >=0) with low 7 bits = local col (lex tiebreak built in).
// ---------------------------------------------------------------------------
__global__ __launch_bounds__(256)
void vq_mfma(const unsigned short* __restrict__ Ae,
             const unsigned short* __restrict__ Be,
             const float* __restrict__ c2,
             ulonglong2* __restrict__ part) {
    __shared__ __align__(16) unsigned short As[128][64];
    __shared__ __align__(16) unsigned short Bs[128][64];
    __shared__ u32 s1[128][2];
    __shared__ u32 s2[128][2];

    const int tid  = threadIdx.x;
    const int lane = tid & 63;
    const int wid  = tid >> 6;
    const int wr   = wid >> 1, wc = wid & 1;
    const int brow = blockIdx.y * 128;
    const int bcol = blockIdx.x * 128;

    f32x4 acc[4][4] = {};

    const int fr = tid >> 3;
    const int fk = (tid & 7) * 8;
    const int swz   = (lane & 7) << 4;
    const int arow  = wr * 64 + (lane & 15);
    const int brw   = wc * 64 + (lane & 15);
    const int klane = (lane >> 4) * 16;

    for (int s = 0; s < 4; ++s) {
        const int k0 = s * 64;
        if (s) __syncthreads();
#pragma unroll
        for (int l = 0; l < 4; ++l) {
            gload16(Ae + (size_t)(brow + l * 32 + fr) * 256 + k0 + fk,
                    (char*)&As[0][0] + l * 4096 + tid * 16);
            gload16(Be + (size_t)(bcol + l * 32 + fr) * 512 + k0 + fk,
                    (char*)&Bs[0][0] + l * 4096 + tid * 16);
        }
        __syncthreads();
#pragma unroll
        for (int kk = 0; kk < 2; ++kk) {
            const int kb = (kk * 64 + klane) ^ swz;
            short8v af[4], bfv[4];
#pragma unroll
            for (int mi = 0; mi < 4; mi++)
                af[mi] = *(const short8v*)((const char*)&As[arow + mi * 16][0] + kb);
#pragma unroll
            for (int ni = 0; ni < 4; ni++)
                bfv[ni] = *(const short8v*)((const char*)&Bs[brw + ni * 16][0] + kb);
#pragma unroll
            for (int mi = 0; mi < 4; mi++)
#pragma unroll
                for (int ni = 0; ni < 4; ni++)
                    acc[mi][ni] = __builtin_amdgcn_mfma_f32_16x16x32_bf16(
                        bfv[ni], af[mi], acc[mi][ni], 0, 0, 0);
        }
    }

    // ---- epilogue: swapped layout -> in-register inserts, 2 shfl rounds ----
    const int qrow = lane & 15;          // query row within mi-frag
    const int cq   = (lane >> 4) * 4;    // codeword quad base within ni-frag
    float4 c2q[4];
#pragma unroll
    for (int ni = 0; ni < 4; ni++)
        c2q[ni] = *(const float4*)&c2[bcol + wc * 64 + ni * 16 + cq];

#pragma unroll
    for (int mi = 0; mi < 4; mi++) {
        u32 b1 = 0xFFFFFFFFu, b2 = 0xFFFFFFFFu;
#pragma unroll
        for (int ni = 0; ni < 4; ni++) {
            const float* cp = (const float*)&c2q[ni];
#pragma unroll
            for (int r = 0; r < 4; r++) {
                float dk = fmaf(-2.0f, acc[mi][ni][r], cp[r]);
                dk = fmaxf(dk, 0.0f);
                u32 k = (__float_as_uint(dk) & ~127u)
                      | (u32)(wc * 64 + ni * 16 + cq + r);
                u32 mx = max(k, b1);
                b1 = min(k, b1);
                b2 = min(mx, b2);
            }
        }
#pragma unroll
        for (int off = 16; off < 64; off <<= 1) {
            u32 o1 = __shfl_xor(b1, off);
            u32 o2 = __shfl_xor(b2, off);
            u32 mx = max(b1, o1);
            b1 = min(b1, o1);
            b2 = min(min(b2, o2), mx);
        }
        if (lane < 16) {
            int rl = wr * 64 + mi * 16 + qrow;
            s1[rl][wc] = b1;
            s2[rl][wc] = b2;
        }
    }
    __syncthreads();
    if (tid < 128) {
        u32 a1 = s1[tid][0], a2 = s2[tid][0];
        u32 c1 = s1[tid][1], cc2 = s2[tid][1];
        u32 mx = max(a1, c1);
        u32 b1 = min(a1, c1);
        u32 b2 = min(min(a2, cc2), mx);
        ulonglong2 pk;
        pk.x = ((u64)b1 << 32) | (u32)(bcol + (b1 & 127u));
        pk.y = ((u64)b2 << 32) | (u32)(bcol + (b2 & 127u));
        part[(size_t)(brow + tid) * NCB + blockIdx.x] = pk;
    }
}

// ---------------------------------------------------------------------------
// Combine per-colblock top-2s -> global approx top-2 -> exact fp32 rescore.
// Also computes x2 (same reduction tree as rownorm2) from the enc row.
// ---------------------------------------------------------------------------
__global__ __launch_bounds__(256)
void vq_combine_rescore(const ulonglong2* __restrict__ part,
                        const float* __restrict__ enc,
                        const float* __restrict__ cw,
                        const float* __restrict__ c2,
                        float* __restrict__ outIdx,
                        float* __restrict__ outDist,
                        int* __restrict__ idx32) {
    const int row  = blockIdx.x * 4 + (threadIdx.x >> 6);
    const int lane = threadIdx.x & 63;

    ulonglong2 pk = part[(size_t)row * NCB + lane];
    u64 b1 = pk.x, b2 = pk.y;
#pragma unroll
    for (int off = 1; off < 64; off <<= 1) {
        u64 c1 = __shfl_xor(b1, off);
        u64 cc2 = __shfl_xor(b2, off);
        t2mrg(b1, b2, c1, cc2);
    }
    int j1 = (int)(b1 & 0xffffffffu);
    int j2 = (int)(b2 & 0xffffffffu);

    float4 e4 = ((const float4*)(enc + (size_t)row * 256))[lane];
    float4 w1 = ((const float4*)(cw + (size_t)j1 * 256))[lane];
    float4 w2 = ((const float4*)(cw + (size_t)j2 * 256))[lane];
    float s1 = fmaf(e4.x, w1.x, fmaf(e4.y, w1.y, fmaf(e4.z, w1.z, e4.w * w1.w)));
    float s2 = fmaf(e4.x, w2.x, fmaf(e4.y, w2.y, fmaf(e4.z, w2.z, e4.w * w2.w)));
    float sx = (e4.x * e4.x + e4.y * e4.y) + (e4.z * e4.z + e4.w * e4.w);
#pragma unroll
    for (int off = 1; off < 64; off <<= 1) {
        s1 += __shfl_xor(s1, off);
        s2 += __shfl_xor(s2, off);
        sx += __shfl_xor(sx, off);
    }
    float d1 = sqrtf(fmaxf(sx + c2[j1] - 2.0f * s1, 0.f));
    float d2 = sqrtf(fmaxf(sx + c2[j2] - 2.0f * s2, 0.f));
    float bd; int bi;
    if (lex_lt(d1, j1, d2, j2)) { bd = d1; bi = j1; }
    else                        { bd = d2; bi = j2; }
    if (lane == 0) {
        outIdx[row]  = (float)bi;
        outDist[row] = bd;
        idx32[row]   = bi;
    }
}

// ---------------------------------------------------------------------------
// Gather decoded codewords + codewords into output rows.
// ---------------------------------------------------------------------------
__global__ void gather_out(const int* __restrict__ idx32,
                           const float* __restrict__ rec_all,
                           const float* __restrict__ cw,
                           float* __restrict__ outRec,
                           float* __restrict__ outQ) {
    int row = blockIdx.x;
    int j = idx32[row];
    const float4* src = (const float4*)(rec_all + (size_t)j * IN_DIM);
    float4* dst = (float4*)(outRec + (size_t)row * IN_DIM);
    dst[threadIdx.x] = src[threadIdx.x];
    if (threadIdx.x < 64) {
        ((float4*)(outQ + (size_t)row * ENC_DIM))[threadIdx.x] =
            ((const float4*)(cw + (size_t)j * ENC_DIM))[threadIdx.x];
    }
}

extern "C" void kernel_launch(void* const* d_in, const int* in_sizes, int n_in,
                              void* d_out, int out_size, void* d_ws, size_t ws_size,
                              hipStream_t stream) {
    const float* x   = (const float*)d_in[0];
    const float* ew1 = (const float*)d_in[1];
    const float* eb1 = (const float*)d_in[2];
    const float* ew2 = (const float*)d_in[3];
    const float* eb2 = (const float*)d_in[4];
    const float* cw  = (const float*)d_in[5];
    const float* dw1 = (const float*)d_in[6];
    const float* db1 = (const float*)d_in[7];
    const float* dw2 = (const float*)d_in[8];
    const float* db2 = (const float*)d_in[9];
    float* out = (float*)d_out;
    float* ws  = (float*)d_ws;

    float* outIdx  = out;
    float* outDist = out + NROWS;
    float* outRec  = out + 2 * NROWS;
    float* outQ    = out + 2 * NROWS + (size_t)NROWS * IN_DIM;

    if (ws_size >= 95000000ull) {
        // ---- big-ws path: single-pass enc1 over full 64 MB xs split ----
        // liveness: xs[0,16.78M) dead after enc1; Hs[16.78M,20.97M) dead
        // after enc2; enc/Ae/part/Gs/rec_all alias only dead regions.
        unsigned short* xs      = (unsigned short*)ws;            // [16384][2048]
        unsigned short* Hs      = (unsigned short*)(ws + 16777216); // [16384][512]
        unsigned short* Be      = (unsigned short*)(ws + 20971520); // [8192][512]
        unsigned short* w1ts    = (unsigned short*)(ws + 23068672);
        unsigned short* ew2t    = (unsigned short*)(ws + 23330816);
        unsigned short* dw1t    = (unsigned short*)(ws + 23396352);
        unsigned short* dw2t    = (unsigned short*)(ws + 23461888);
        float*          c2      = ws + 23724032;
        int*            idx32   = (int*)(ws + 23732224);
        float*          enc     = ws;                       // [0, 4.19M)
        unsigned short* Ae      = (unsigned short*)(ws + 4194304);
        ulonglong2*     part    = (ulonglong2*)(ws + 6291456);   // ends 10.49M
        unsigned short* Gs      = (unsigned short*)(ws + 10485760);
        float*          rec_all = ws + 12582912;            // ends 20.97M

        tsplitK<1024><<<256, 256, 0, stream>>>(ew1, w1ts, 256);
        tsplitK<256><<<64, 256, 0, stream>>>(ew2, ew2t, 256);
        tsplitK<256><<<64, 256, 0, stream>>>(dw1, dw1t, 256);
        tsplitK<256><<<256, 256, 0, stream>>>(dw2, dw2t, 1024);
        splitK<256><<<(KCW * 64) / 256, 256, 0, stream>>>(cw, Be, KCW * 64);
        rownorm2<<<KCW / 4, 256, 0, stream>>>(cw, c2, KCW);

        splitK<1024><<<16384, 256, 0, stream>>>(x, xs, NROWS * 256);
        mm_split<2, 16><<<dim3(2, 128), 256, 0, stream>>>(
            xs, w1ts, eb1, nullptr, Hs, 256, 2048, 2048, 512);

        mm_split<1, 4><<<dim3(2, 128), 256, 0, stream>>>(
            Hs, ew2t, eb2, enc, Ae, 256, 512, 512, 256);

        vq_mfma<<<dim3(NCB, 128), 256, 0, stream>>>(Ae, Be, c2, part);
        vq_combine_rescore<<<NROWS / 4, 256, 0, stream>>>(part, enc, cw, c2,
                                                          outIdx, outDist, idx32);

        mm_split<2, 4><<<dim3(2, 64), 256, 0, stream>>>(
            Be, dw1t, db1, nullptr, Gs, 256, 512, 512, 512);
        mm_split<3, 4><<<dim3(8, 64), 256, 0, stream>>>(
            Gs, dw2t, db2, rec_all, nullptr, 1024, 512, 512, 0);

        gather_out<<<NROWS, 256, 0, stream>>>(idx32, rec_all, cw, outRec, outQ);
    } else {
        // ---- fallback: round-7 proven layout (~61.5 MB) ----
        unsigned short* xs      = (unsigned short*)ws;
        float*          enc     = ws;
        float*          rec_all = ws;
        unsigned short* Ae      = (unsigned short*)(ws + 4194304);
        unsigned short* Hs      = (unsigned short*)(ws + 8388608);
        ulonglong2*     part    = (ulonglong2*)(ws + 8388608);
        unsigned short* Gs      = (unsigned short*)(ws + 8388608);
        unsigned short* Be      = (unsigned short*)(ws + 12582912);
        unsigned short* w1ts    = (unsigned short*)(ws + 14680064);
        unsigned short* ew2t    = (unsigned short*)(ws + 14942208);
        unsigned short* dw1t    = (unsigned short*)(ws + 15007744);
        unsigned short* dw2t    = (unsigned short*)(ws + 15073280);
        float*          c2      = ws + 15335424;
        int*            idx32   = (int*)(ws + 15343616);

        tsplitK<1024><<<256, 256, 0, stream>>>(ew1, w1ts, 256);
        tsplitK<256><<<64, 256, 0, stream>>>(ew2, ew2t, 256);
        tsplitK<256><<<64, 256, 0, stream>>>(dw1, dw1t, 256);
        tsplitK<256><<<256, 256, 0, stream>>>(dw2, dw2t, 1024);
        splitK<256><<<(KCW * 64) / 256, 256, 0, stream>>>(cw, Be, KCW * 64);
        rownorm2<<<KCW / 4, 256, 0, stream>>>(cw, c2, KCW);

        splitK<1024><<<8192, 256, 0, stream>>>(x, xs, 8192 * 256);
        mm_split<2, 16><<<dim3(2, 64), 256, 0, stream>>>(
            xs, w1ts, eb1, nullptr, Hs, 256, 2048, 2048, 512);
        splitK<1024><<<8192, 256, 0, stream>>>(x + (size_t)8192 * 1024, xs, 8192 * 256);
        mm_split<2, 16><<<dim3(2, 64), 256, 0, stream>>>(
            xs, w1ts, eb1, nullptr, Hs + (size_t)8192 * 512, 256, 2048, 2048, 512);

        mm_split<1, 4><<<dim3(2, 128), 256, 0, stream>>>(
            Hs, ew2t, eb2, enc, Ae, 256, 512, 512, 256);

        vq_mfma<<<dim3(NCB, 128), 256, 0, stream>>>(Ae, Be, c2, part);
        vq_combine_rescore<<<NROWS / 4, 256, 0, stream>>>(part, enc, cw, c2,
                                                          outIdx, outDist, idx32);

        mm_split<2, 4><<<dim3(2, 64), 256, 0, stream>>>(
            Be, dw1t, db1, nullptr, Gs, 256, 512, 512, 512);
        mm_split<3, 4><<<dim3(8, 64), 256, 0, stream>>>(
            Gs, dw2t, db2, rec_all, nullptr, 1024, 512, 512, 0);

        gather_out<<<NROWS, 256, 0, stream>>>(idx32, rec_all, cw, outRec, outQ);
    }
}

// Round 9
// 247.884 us; speedup vs baseline: 4.8454x; 1.0908x over previous
//
#include <hip/hip_runtime.h>
#include <hip/hip_bf16.h>

#define NROWS   16384
#define IN_DIM  1024
#define ENC_DIM 256
#define KCW     8192
#define NCB     32          // codeword col-blocks of 256

typedef __attribute__((ext_vector_type(8))) short short8v;
typedef __attribute__((ext_vector_type(4))) float f32x4;
typedef unsigned long long u64;
typedef unsigned int u32;

// ---------------------------------------------------------------------------
// helpers
// ---------------------------------------------------------------------------
__device__ __forceinline__ unsigned short f2bf_rne(float x) {
    unsigned u = __float_as_uint(x);
    unsigned r = (u + 0x7fffu + ((u >> 16) & 1u)) >> 16;
    return (unsigned short)r;
}
__device__ __forceinline__ float bf2f(unsigned short h) {
    return __uint_as_float(((unsigned)h) << 16);
}
__device__ __forceinline__ int lex_lt(float d, int i, float D, int I) {
    return (d < D) || (d == D && i < I);
}
__device__ __forceinline__ void t2mrg(u64& b1, u64& b2, u64 c1, u64 c2) {
    u64 hi = (b1 > c1) ? b1 : c1;
    u64 lo2 = (b2 < c2) ? b2 : c2;
    b1 = (b1 < c1) ? b1 : c1;
    b2 = (hi < lo2) ? hi : lo2;
}
__device__ __forceinline__ void gload16(const void* g, void* l) {
    __builtin_amdgcn_global_load_lds(
        (__attribute__((address_space(1))) void*)g,
        (__attribute__((address_space(3))) void*)l, 16, 0, 0);
}

// ---------------------------------------------------------------------------
// device bodies reused by prep_all and standalone kernels
// ---------------------------------------------------------------------------
template<int K>
__device__ __forceinline__ void split_body(const float* __restrict__ src,
                                           unsigned short* __restrict__ dst,
                                           int e) {
    int row = e / (K / 4), kq = (e % (K / 4)) * 4;
    float4 v = ((const float4*)src)[e];
    ushort4 hi, lo;
    hi.x = f2bf_rne(v.x); lo.x = f2bf_rne(v.x - bf2f(hi.x));
    hi.y = f2bf_rne(v.y); lo.y = f2bf_rne(v.y - bf2f(hi.y));
    hi.z = f2bf_rne(v.z); lo.z = f2bf_rne(v.z - bf2f(hi.z));
    hi.w = f2bf_rne(v.w); lo.w = f2bf_rne(v.w - bf2f(hi.w));
    const int m = (row & 7) << 4;
    char* rowp = (char*)(dst + (size_t)row * (2 * K));
    int bh = kq * 2, bl = (K + kq) * 2;
    *(ushort4*)(rowp + ((bh & ~127) | ((bh & 127) ^ m))) = hi;
    *(ushort4*)(rowp + ((bl & ~127) | ((bl & 127) ^ m))) = lo;
}

template<int K>
__device__ __forceinline__ void tsplit_body(const float* __restrict__ W,
                                            unsigned short* __restrict__ Wt,
                                            int Ncols, int idx) {
    int n = idx / (K / 4), k4 = (idx % (K / 4)) * 4;
    float vx = W[(size_t)(k4 + 0) * Ncols + n];
    float vy = W[(size_t)(k4 + 1) * Ncols + n];
    float vz = W[(size_t)(k4 + 2) * Ncols + n];
    float vw = W[(size_t)(k4 + 3) * Ncols + n];
    ushort4 hi, lo;
    hi.x = f2bf_rne(vx); lo.x = f2bf_rne(vx - bf2f(hi.x));
    hi.y = f2bf_rne(vy); lo.y = f2bf_rne(vy - bf2f(hi.y));
    hi.z = f2bf_rne(vz); lo.z = f2bf_rne(vz - bf2f(hi.z));
    hi.w = f2bf_rne(vw); lo.w = f2bf_rne(vw - bf2f(hi.w));
    const int m = (n & 7) << 4;
    char* rp = (char*)(Wt + (size_t)n * (2 * K));
    int bh = k4 * 2, bl = (K + k4) * 2;
    *(ushort4*)(rp + ((bh & ~127) | ((bh & 127) ^ m))) = hi;
    *(ushort4*)(rp + ((bl & ~127) | ((bl & 127) ^ m))) = lo;
}

__device__ __forceinline__ void rownorm_body(const float* __restrict__ A,
                                             float* __restrict__ out, int idx) {
    int wid = idx >> 6, lane = idx & 63;
    float4 v = *(const float4*)(A + (size_t)wid * 256 + lane * 4);
    float s = (v.x * v.x + v.y * v.y) + (v.z * v.z + v.w * v.w);
#pragma unroll
    for (int off = 1; off < 64; off <<= 1) s += __shfl_xor(s, off);
    if (lane == 0) out[wid] = s;
}

// ---------------------------------------------------------------------------
// prep_all: all weight/codeword transforms (+ optionally the x split) in ONE
// launch. Section bases are multiples of 256 -> no intra-block divergence.
// ---------------------------------------------------------------------------
template<int WITH_X>
__global__ __launch_bounds__(256)
void prep_all(const float* __restrict__ ew1, const float* __restrict__ ew2,
              const float* __restrict__ dw1, const float* __restrict__ dw2,
              const float* __restrict__ cw,  const float* __restrict__ x,
              unsigned short* __restrict__ w1ts, unsigned short* __restrict__ ew2t,
              unsigned short* __restrict__ dw1t, unsigned short* __restrict__ dw2t,
              unsigned short* __restrict__ Be,   float* __restrict__ c2,
              unsigned short* __restrict__ xs) {
    int idx = blockIdx.x * 256 + threadIdx.x;
    if (idx < 65536)        { tsplit_body<1024>(ew1, w1ts, 256, idx); }
    else if (idx < 81920)   { tsplit_body<256>(ew2, ew2t, 256, idx - 65536); }
    else if (idx < 98304)   { tsplit_body<256>(dw1, dw1t, 256, idx - 81920); }
    else if (idx < 163840)  { tsplit_body<256>(dw2, dw2t, 1024, idx - 98304); }
    else if (idx < 688128)  { split_body<256>(cw, Be, idx - 163840); }
    else if (idx < 1212416) { rownorm_body(cw, c2, idx - 688128); }
    else if (WITH_X)        { split_body<1024>(x, xs, idx - 1212416); }
}

// standalone x-split for the fallback (halved) path
template<int K>
__global__ void splitK(const float* __restrict__ src,
                       unsigned short* __restrict__ dst, int n4) {
    int e = blockIdx.x * 256 + threadIdx.x;
    if (e >= n4) return;
    split_body<K>(src, dst, e);
}

// ---------------------------------------------------------------------------
// Split-bf16 MFMA GEMM: C = act(A@B^T + bias), K = 64*KQ via 3 terms.
// EPI: 1 = relu, C fp32 + Cs hi-only;  2 = relu, Cs hi+lo;  3 = C fp32 only.
// ---------------------------------------------------------------------------
template<int EPI, int KQ>
__global__ __launch_bounds__(256)
void mm_split(const unsigned short* __restrict__ A,
              const unsigned short* __restrict__ Bt,
              const float* __restrict__ bias,
              float* __restrict__ C,
              unsigned short* __restrict__ Cs,
              int N, int ars, int brs, int crs) {
    __shared__ __align__(16) unsigned short As[128][64];
    __shared__ __align__(16) unsigned short Bs[128][64];
    const int tid = threadIdx.x;
    const int lane = tid & 63;
    const int wid = tid >> 6;
    const int wr = wid >> 1, wc = wid & 1;
    const int brow = blockIdx.y * 128;
    const int bcol = blockIdx.x * 128;
    constexpr int K = KQ * 64;

    f32x4 acc[4][4] = {};

    const int fr = tid >> 3;
    const int fk = (tid & 7) * 8;
    const int swz = (lane & 7) << 4;
    const int arow = wr * 64 + (lane & 15);
    const int brw  = wc * 64 + (lane & 15);
    const int klane = (lane >> 4) * 16;

    for (int s = 0; s < 3 * KQ; ++s) {
        const int term = s / KQ, kq = s % KQ;
        const int ka0 = (term == 2 ? K : 0) + kq * 64;
        const int kb0 = (term == 1 ? K : 0) + kq * 64;
        if (s) __syncthreads();
#pragma unroll
        for (int l = 0; l < 4; ++l) {
            gload16(A  + (size_t)(brow + l * 32 + fr) * ars + ka0 + fk,
                    (char*)&As[0][0] + l * 4096 + tid * 16);
            gload16(Bt + (size_t)(bcol + l * 32 + fr) * brs + kb0 + fk,
                    (char*)&Bs[0][0] + l * 4096 + tid * 16);
        }
        __syncthreads();
#pragma unroll
        for (int kk = 0; kk < 2; ++kk) {
            const int kb = (kk * 64 + klane) ^ swz;
            short8v af[4], bfv[4];
#pragma unroll
            for (int mi = 0; mi < 4; mi++)
                af[mi] = *(const short8v*)((const char*)&As[arow + mi * 16][0] + kb);
#pragma unroll
            for (int ni = 0; ni < 4; ni++)
                bfv[ni] = *(const short8v*)((const char*)&Bs[brw + ni * 16][0] + kb);
#pragma unroll
            for (int mi = 0; mi < 4; mi++)
#pragma unroll
                for (int ni = 0; ni < 4; ni++)
                    acc[mi][ni] = __builtin_amdgcn_mfma_f32_16x16x32_bf16(
                        af[mi], bfv[ni], acc[mi][ni], 0, 0, 0);
        }
    }

#pragma unroll
    for (int mi = 0; mi < 4; mi++) {
#pragma unroll
        for (int q = 0; q < 4; q++) {
            int row = brow + wr * 64 + mi * 16 + (lane >> 4) * 4 + q;
            const int m = (row & 7) << 4;
            char* rp = (char*)(Cs + (size_t)row * crs);
#pragma unroll
            for (int ni = 0; ni < 4; ni++) {
                int col = bcol + wc * 64 + ni * 16 + (lane & 15);
                float v = acc[mi][ni][q] + bias[col];
                if (EPI != 3) v = fmaxf(v, 0.f);
                if (EPI == 1 || EPI == 3) C[(size_t)row * N + col] = v;
                if (EPI == 1 || EPI == 2) {
                    unsigned short hi = f2bf_rne(v);
                    int bh = col * 2;
                    *(unsigned short*)(rp + ((bh & ~127) | ((bh & 127) ^ m))) = hi;
                    if (EPI == 2) {
                        unsigned short lo = f2bf_rne(v - bf2f(hi));
                        int bl = (256 + col) * 2;
                        *(unsigned short*)(rp + ((bl & ~127) | ((bl & 127) ^ m))) = lo;
                    }
                }
            }
        }
    }
}

// ---------------------------------------------------------------------------
// VQ MFMA kernel: HI-ONLY bf16 d2-key GEMM (K=256) + per-row top-2.
// 128x256 tile, 512 threads (8 waves 2x4), single-buffered 52KB LDS ->
// ~24 waves/CU. Swapped-operand MFMA; u32 key low 8 bits = local col.
// ---------------------------------------------------------------------------
__global__ __launch_bounds__(512)
void vq_mfma(const unsigned short* __restrict__ Ae,
             const unsigned short* __restrict__ Be,
             const float* __restrict__ c2,
             ulonglong2* __restrict__ part) {
    __shared__ __align__(16) unsigned short As[128][64];
    __shared__ __align__(16) unsigned short Bs[256][64];
    __shared__ u32 s1[128][4];
    __shared__ u32 s2[128][4];

    const int tid  = threadIdx.x;
    const int lane = tid & 63;
    const int wid  = tid >> 6;          // 0..7
    const int wr   = wid >> 2;          // 0..1
    const int wc   = wid & 3;           // 0..3
    const int brow = blockIdx.y * 128;
    const int bcol = blockIdx.x * 256;

    f32x4 acc[4][4] = {};

    const int fr = tid >> 3;            // 0..63
    const int fk = (tid & 7) * 8;
    const int swz   = (lane & 7) << 4;
    const int arow  = wr * 64 + (lane & 15);
    const int brw   = wc * 64 + (lane & 15);
    const int klane = (lane >> 4) * 16;

    for (int s = 0; s < 4; ++s) {
        const int k0 = s * 64;
        if (s) __syncthreads();
#pragma unroll
        for (int l = 0; l < 2; ++l)
            gload16(Ae + (size_t)(brow + l * 64 + fr) * 256 + k0 + fk,
                    (char*)&As[0][0] + l * 8192 + tid * 16);
#pragma unroll
        for (int l = 0; l < 4; ++l)
            gload16(Be + (size_t)(bcol + l * 64 + fr) * 512 + k0 + fk,
                    (char*)&Bs[0][0] + l * 8192 + tid * 16);
        __syncthreads();
#pragma unroll
        for (int kk = 0; kk < 2; ++kk) {
            const int kb = (kk * 64 + klane) ^ swz;
            short8v af[4], bfv[4];
#pragma unroll
            for (int mi = 0; mi < 4; mi++)
                af[mi] = *(const short8v*)((const char*)&As[arow + mi * 16][0] + kb);
#pragma unroll
            for (int ni = 0; ni < 4; ni++)
                bfv[ni] = *(const short8v*)((const char*)&Bs[brw + ni * 16][0] + kb);
#pragma unroll
            for (int mi = 0; mi < 4; mi++)
#pragma unroll
                for (int ni = 0; ni < 4; ni++)
                    acc[mi][ni] = __builtin_amdgcn_mfma_f32_16x16x32_bf16(
                        bfv[ni], af[mi], acc[mi][ni], 0, 0, 0);
        }
    }

    // ---- epilogue: swapped layout -> in-register inserts, 2 shfl rounds ----
    const int qrow = lane & 15;
    const int cq   = (lane >> 4) * 4;
    float4 c2q[4];
#pragma unroll
    for (int ni = 0; ni < 4; ni++)
        c2q[ni] = *(const float4*)&c2[bcol + wc * 64 + ni * 16 + cq];

#pragma unroll
    for (int mi = 0; mi < 4; mi++) {
        u32 b1 = 0xFFFFFFFFu, b2 = 0xFFFFFFFFu;
#pragma unroll
        for (int ni = 0; ni < 4; ni++) {
            const float* cp = (const float*)&c2q[ni];
#pragma unroll
            for (int r = 0; r < 4; r++) {
                float dk = fmaf(-2.0f, acc[mi][ni][r], cp[r]);
                dk = fmaxf(dk, 0.0f);
                u32 k = (__float_as_uint(dk) & ~255u)
                      | (u32)(wc * 64 + ni * 16 + cq + r);
                u32 mx = max(k, b1);
                b1 = min(k, b1);
                b2 = min(mx, b2);
            }
        }
#pragma unroll
        for (int off = 16; off < 64; off <<= 1) {
            u32 o1 = __shfl_xor(b1, off);
            u32 o2 = __shfl_xor(b2, off);
            u32 mx = max(b1, o1);
            b1 = min(b1, o1);
            b2 = min(min(b2, o2), mx);
        }
        if (lane < 16) {
            int rl = wr * 64 + mi * 16 + qrow;
            s1[rl][wc] = b1;
            s2[rl][wc] = b2;
        }
    }
    __syncthreads();
    if (tid < 128) {
        u32 b1 = s1[tid][0], b2 = s2[tid][0];
#pragma unroll
        for (int w = 1; w < 4; w++) {
            u32 c1 = s1[tid][w], cc2 = s2[tid][w];
            u32 mx = max(b1, c1);
            b1 = min(b1, c1);
            b2 = min(min(b2, cc2), mx);
        }
        ulonglong2 pk;
        pk.x = ((u64)b1 << 32) | (u32)(bcol + (b1 & 255u));
        pk.y = ((u64)b2 << 32) | (u32)(bcol + (b2 & 255u));
        part[(size_t)(brow + tid) * NCB + blockIdx.x] = pk;
    }
}

// ---------------------------------------------------------------------------
// Combine per-colblock top-2s -> global approx top-2 -> exact fp32 rescore.
// Also computes x2 from the enc row (same reduction tree as rownorm).
// ---------------------------------------------------------------------------
__global__ __launch_bounds__(256)
void vq_combine_rescore(const ulonglong2* __restrict__ part,
                        const float* __restrict__ enc,
                        const float* __restrict__ cw,
                        const float* __restrict__ c2,
                        float* __restrict__ outIdx,
                        float* __restrict__ outDist,
                        int* __restrict__ idx32) {
    const int row  = blockIdx.x * 4 + (threadIdx.x >> 6);
    const int lane = threadIdx.x & 63;

    u64 b1 = ~0ull, b2 = ~0ull;
    if (lane < NCB) {
        ulonglong2 pk = part[(size_t)row * NCB + lane];
        b1 = pk.x; b2 = pk.y;
    }
#pragma unroll
    for (int off = 1; off < 64; off <<= 1) {
        u64 c1 = __shfl_xor(b1, off);
        u64 cc2 = __shfl_xor(b2, off);
        t2mrg(b1, b2, c1, cc2);
    }
    int j1 = (int)(b1 & 0xffffffffu);
    int j2 = (int)(b2 & 0xffffffffu);

    float4 e4 = ((const float4*)(enc + (size_t)row * 256))[lane];
    float4 w1 = ((const float4*)(cw + (size_t)j1 * 256))[lane];
    float4 w2 = ((const float4*)(cw + (size_t)j2 * 256))[lane];
    float s1 = fmaf(e4.x, w1.x, fmaf(e4.y, w1.y, fmaf(e4.z, w1.z, e4.w * w1.w)));
    float s2 = fmaf(e4.x, w2.x, fmaf(e4.y, w2.y, fmaf(e4.z, w2.z, e4.w * w2.w)));
    float sx = (e4.x * e4.x + e4.y * e4.y) + (e4.z * e4.z + e4.w * e4.w);
#pragma unroll
    for (int off = 1; off < 64; off <<= 1) {
        s1 += __shfl_xor(s1, off);
        s2 += __shfl_xor(s2, off);
        sx += __shfl_xor(sx, off);
    }
    float d1 = sqrtf(fmaxf(sx + c2[j1] - 2.0f * s1, 0.f));
    float d2 = sqrtf(fmaxf(sx + c2[j2] - 2.0f * s2, 0.f));
    float bd; int bi;
    if (lex_lt(d1, j1, d2, j2)) { bd = d1; bi = j1; }
    else                        { bd = d2; bi = j2; }
    if (lane == 0) {
        outIdx[row]  = (float)bi;
        outDist[row] = bd;
        idx32[row]   = bi;
    }
}

// ---------------------------------------------------------------------------
// Gather decoded codewords + codewords into output rows.
// ---------------------------------------------------------------------------
__global__ void gather_out(const int* __restrict__ idx32,
                           const float* __restrict__ rec_all,
                           const float* __restrict__ cw,
                           float* __restrict__ outRec,
                           float* __restrict__ outQ) {
    int row = blockIdx.x;
    int j = idx32[row];
    const float4* src = (const float4*)(rec_all + (size_t)j * IN_DIM);
    float4* dst = (float4*)(outRec + (size_t)row * IN_DIM);
    dst[threadIdx.x] = src[threadIdx.x];
    if (threadIdx.x < 64) {
        ((float4*)(outQ + (size_t)row * ENC_DIM))[threadIdx.x] =
            ((const float4*)(cw + (size_t)j * ENC_DIM))[threadIdx.x];
    }
}

extern "C" void kernel_launch(void* const* d_in, const int* in_sizes, int n_in,
                              void* d_out, int out_size, void* d_ws, size_t ws_size,
                              hipStream_t stream) {
    const float* x   = (const float*)d_in[0];
    const float* ew1 = (const float*)d_in[1];
    const float* eb1 = (const float*)d_in[2];
    const float* ew2 = (const float*)d_in[3];
    const float* eb2 = (const float*)d_in[4];
    const float* cw  = (const float*)d_in[5];
    const float* dw1 = (const float*)d_in[6];
    const float* db1 = (const float*)d_in[7];
    const float* dw2 = (const float*)d_in[8];
    const float* db2 = (const float*)d_in[9];
    float* out = (float*)d_out;
    float* ws  = (float*)d_ws;

    float* outIdx  = out;
    float* outDist = out + NROWS;
    float* outRec  = out + 2 * NROWS;
    float* outQ    = out + 2 * NROWS + (size_t)NROWS * IN_DIM;

    if (ws_size >= 95000000ull) {
        // ---- big-ws path: single prep kernel + single-pass enc1 ----
        unsigned short* xs      = (unsigned short*)ws;              // [16384][2048]
        unsigned short* Hs      = (unsigned short*)(ws + 16777216); // [16384][512]
        unsigned short* Be      = (unsigned short*)(ws + 20971520); // [8192][512]
        unsigned short* w1ts    = (unsigned short*)(ws + 23068672);
        unsigned short* ew2t    = (unsigned short*)(ws + 23330816);
        unsigned short* dw1t    = (unsigned short*)(ws + 23396352);
        unsigned short* dw2t    = (unsigned short*)(ws + 23461888);
        float*          c2      = ws + 23724032;
        int*            idx32   = (int*)(ws + 23732224);
        float*          enc     = ws;                               // [0, 4.19M)
        unsigned short* Ae      = (unsigned short*)(ws + 4194304);
        ulonglong2*     part    = (ulonglong2*)(ws + 6291456);      // 8MB
        unsigned short* Gs      = (unsigned short*)(ws + 10485760);
        float*          rec_all = ws + 12582912;                    // ends 20.97M

        prep_all<1><<<21120, 256, 0, stream>>>(ew1, ew2, dw1, dw2, cw, x,
                                               w1ts, ew2t, dw1t, dw2t, Be, c2, xs);

        mm_split<2, 16><<<dim3(2, 128), 256, 0, stream>>>(
            xs, w1ts, eb1, nullptr, Hs, 256, 2048, 2048, 512);
        mm_split<1, 4><<<dim3(2, 128), 256, 0, stream>>>(
            Hs, ew2t, eb2, enc, Ae, 256, 512, 512, 256);

        vq_mfma<<<dim3(NCB, 128), 512, 0, stream>>>(Ae, Be, c2, part);
        vq_combine_rescore<<<NROWS / 4, 256, 0, stream>>>(part, enc, cw, c2,
                                                          outIdx, outDist, idx32);

        mm_split<2, 4><<<dim3(2, 64), 256, 0, stream>>>(
            Be, dw1t, db1, nullptr, Gs, 256, 512, 512, 512);
        mm_split<3, 4><<<dim3(8, 64), 256, 0, stream>>>(
            Gs, dw2t, db2, rec_all, nullptr, 1024, 512, 512, 0);

        gather_out<<<NROWS, 256, 0, stream>>>(idx32, rec_all, cw, outRec, outQ);
    } else {
        // ---- fallback: ~61.5 MB layout, x split in halves ----
        unsigned short* xs      = (unsigned short*)ws;
        float*          enc     = ws;
        float*          rec_all = ws;
        unsigned short* Ae      = (unsigned short*)(ws + 4194304);
        unsigned short* Hs      = (unsigned short*)(ws + 8388608);
        ulonglong2*     part    = (ulonglong2*)(ws + 8388608);
        unsigned short* Gs      = (unsigned short*)(ws + 8388608);
        unsigned short* Be      = (unsigned short*)(ws + 12582912);
        unsigned short* w1ts    = (unsigned short*)(ws + 14680064);
        unsigned short* ew2t    = (unsigned short*)(ws + 14942208);
        unsigned short* dw1t    = (unsigned short*)(ws + 15007744);
        unsigned short* dw2t    = (unsigned short*)(ws + 15073280);
        float*          c2      = ws + 15335424;
        int*            idx32   = (int*)(ws + 15343616);

        prep_all<0><<<4736, 256, 0, stream>>>(ew1, ew2, dw1, dw2, cw, x,
                                              w1ts, ew2t, dw1t, dw2t, Be, c2,
                                              nullptr);

        splitK<1024><<<8192, 256, 0, stream>>>(x, xs, 8192 * 256);
        mm_split<2, 16><<<dim3(2, 64), 256, 0, stream>>>(
            xs, w1ts, eb1, nullptr, Hs, 256, 2048, 2048, 512);
        splitK<1024><<<8192, 256, 0, stream>>>(x + (size_t)8192 * 1024, xs, 8192 * 256);
        mm_split<2, 16><<<dim3(2, 64), 256, 0, stream>>>(
            xs, w1ts, eb1, nullptr, Hs + (size_t)8192 * 512, 256, 2048, 2048, 512);

        mm_split<1, 4><<<dim3(2, 128), 256, 0, stream>>>(
            Hs, ew2t, eb2, enc, Ae, 256, 512, 512, 256);

        vq_mfma<<<dim3(NCB, 128), 512, 0, stream>>>(Ae, Be, c2, part);
        vq_combine_rescore<<<NROWS / 4, 256, 0, stream>>>(part, enc, cw, c2,
                                                          outIdx, outDist, idx32);

        mm_split<2, 4><<<dim3(2, 64), 256, 0, stream>>>(
            Be, dw1t, db1, nullptr, Gs, 256, 512, 512, 512);
        mm_split<3, 4><<<dim3(8, 64), 256, 0, stream>>>(
            Gs, dw2t, db2, rec_all, nullptr, 1024, 512, 512, 0);

        gather_out<<<NROWS, 256, 0, stream>>>(idx32, rec_all, cw, outRec, outQ);
    }
}

// Round 10
// 245.688 us; speedup vs baseline: 4.8887x; 1.0089x over previous
//
#include <hip/hip_runtime.h>
#include <hip/hip_bf16.h>

#define NROWS   16384
#define IN_DIM  1024
#define ENC_DIM 256
#define KCW     8192
#define NCB     32          // codeword col-blocks of 256

typedef __attribute__((ext_vector_type(8))) short short8v;
typedef __attribute__((ext_vector_type(4))) float f32x4;
typedef unsigned long long u64;
typedef unsigned int u32;

// ---------------------------------------------------------------------------
// helpers
// ---------------------------------------------------------------------------
__device__ __forceinline__ unsigned short f2bf_rne(float x) {
    unsigned u = __float_as_uint(x);
    unsigned r = (u + 0x7fffu + ((u >> 16) & 1u)) >> 16;
    return (unsigned short)r;
}
__device__ __forceinline__ float bf2f(unsigned short h) {
    return __uint_as_float(((unsigned)h) << 16);
}
__device__ __forceinline__ int lex_lt(float d, int i, float D, int I) {
    return (d < D) || (d == D && i < I);
}
__device__ __forceinline__ void t2mrg(u64& b1, u64& b2, u64 c1, u64 c2) {
    u64 hi = (b1 > c1) ? b1 : c1;
    u64 lo2 = (b2 < c2) ? b2 : c2;
    b1 = (b1 < c1) ? b1 : c1;
    b2 = (hi < lo2) ? hi : lo2;
}
__device__ __forceinline__ void gload16(const void* g, void* l) {
    __builtin_amdgcn_global_load_lds(
        (__attribute__((address_space(1))) void*)g,
        (__attribute__((address_space(3))) void*)l, 16, 0, 0);
}

// ---------------------------------------------------------------------------
// prep bodies
// ---------------------------------------------------------------------------
template<int K>
__device__ __forceinline__ void split_body(const float* __restrict__ src,
                                           unsigned short* __restrict__ dst,
                                           int e) {
    int row = e / (K / 4), kq = (e % (K / 4)) * 4;
    float4 v = ((const float4*)src)[e];
    ushort4 hi, lo;
    hi.x = f2bf_rne(v.x); lo.x = f2bf_rne(v.x - bf2f(hi.x));
    hi.y = f2bf_rne(v.y); lo.y = f2bf_rne(v.y - bf2f(hi.y));
    hi.z = f2bf_rne(v.z); lo.z = f2bf_rne(v.z - bf2f(hi.z));
    hi.w = f2bf_rne(v.w); lo.w = f2bf_rne(v.w - bf2f(hi.w));
    const int m = (row & 7) << 4;
    char* rowp = (char*)(dst + (size_t)row * (2 * K));
    int bh = kq * 2, bl = (K + kq) * 2;
    *(ushort4*)(rowp + ((bh & ~127) | ((bh & 127) ^ m))) = hi;
    *(ushort4*)(rowp + ((bl & ~127) | ((bl & 127) ^ m))) = lo;
}

template<int K>
__device__ __forceinline__ void tsplit_body(const float* __restrict__ W,
                                            unsigned short* __restrict__ Wt,
                                            int Ncols, int idx) {
    int n = idx / (K / 4), k4 = (idx % (K / 4)) * 4;
    float vx = W[(size_t)(k4 + 0) * Ncols + n];
    float vy = W[(size_t)(k4 + 1) * Ncols + n];
    float vz = W[(size_t)(k4 + 2) * Ncols + n];
    float vw = W[(size_t)(k4 + 3) * Ncols + n];
    ushort4 hi, lo;
    hi.x = f2bf_rne(vx); lo.x = f2bf_rne(vx - bf2f(hi.x));
    hi.y = f2bf_rne(vy); lo.y = f2bf_rne(vy - bf2f(hi.y));
    hi.z = f2bf_rne(vz); lo.z = f2bf_rne(vz - bf2f(hi.z));
    hi.w = f2bf_rne(vw); lo.w = f2bf_rne(vw - bf2f(hi.w));
    const int m = (n & 7) << 4;
    char* rp = (char*)(Wt + (size_t)n * (2 * K));
    int bh = k4 * 2, bl = (K + k4) * 2;
    *(ushort4*)(rp + ((bh & ~127) | ((bh & 127) ^ m))) = hi;
    *(ushort4*)(rp + ((bl & ~127) | ((bl & 127) ^ m))) = lo;
}

__device__ __forceinline__ void rownorm_body(const float* __restrict__ A,
                                             float* __restrict__ out, int idx) {
    int wid = idx >> 6, lane = idx & 63;
    float4 v = *(const float4*)(A + (size_t)wid * 256 + lane * 4);
    float s = (v.x * v.x + v.y * v.y) + (v.z * v.z + v.w * v.w);
#pragma unroll
    for (int off = 1; off < 64; off <<= 1) s += __shfl_xor(s, off);
    if (lane == 0) out[wid] = s;
}

template<int WITH_X>
__global__ __launch_bounds__(256)
void prep_all(const float* __restrict__ ew1, const float* __restrict__ ew2,
              const float* __restrict__ dw1, const float* __restrict__ dw2,
              const float* __restrict__ cw,  const float* __restrict__ x,
              unsigned short* __restrict__ w1ts, unsigned short* __restrict__ ew2t,
              unsigned short* __restrict__ dw1t, unsigned short* __restrict__ dw2t,
              unsigned short* __restrict__ Be,   float* __restrict__ c2,
              unsigned short* __restrict__ xs) {
    int idx = blockIdx.x * 256 + threadIdx.x;
    if (idx < 65536)        { tsplit_body<1024>(ew1, w1ts, 256, idx); }
    else if (idx < 81920)   { tsplit_body<256>(ew2, ew2t, 256, idx - 65536); }
    else if (idx < 98304)   { tsplit_body<256>(dw1, dw1t, 256, idx - 81920); }
    else if (idx < 163840)  { tsplit_body<256>(dw2, dw2t, 1024, idx - 98304); }
    else if (idx < 688128)  { split_body<256>(cw, Be, idx - 163840); }
    else if (idx < 1212416) { rownorm_body(cw, c2, idx - 688128); }
    else if (WITH_X)        { split_body<1024>(x, xs, idx - 1212416); }
}

template<int K>
__global__ void splitK(const float* __restrict__ src,
                       unsigned short* __restrict__ dst, int n4) {
    int e = blockIdx.x * 256 + threadIdx.x;
    if (e >= n4) return;
    split_body<K>(src, dst, e);
}

// ---------------------------------------------------------------------------
// Runtime-parameterized split-bf16 MFMA GEMM body (same structure as proven
// template version; KQ/EPI now runtime, per-block uniform).
// EPI: 1 = relu, C fp32 + Cs hi;  2 = relu, Cs hi+lo;  3 = no relu, C only.
// ---------------------------------------------------------------------------
struct MMP {
    const unsigned short* A;
    const unsigned short* Bt;
    const float* bias;
    float* C;
    unsigned short* Cs;
    int N, ars, brs, crs, KQ, EPI, gx;
};

__device__ void mm_device(const MMP p, int bx, int by, int tid) {
    __shared__ __align__(16) unsigned short As[128][64];
    __shared__ __align__(16) unsigned short Bs[128][64];
    const int lane = tid & 63;
    const int wid = tid >> 6;
    const int wr = wid >> 1, wc = wid & 1;
    const int brow = by * 128;
    const int bcol = bx * 128;
    const int K = p.KQ * 64;

    f32x4 acc[4][4] = {};

    const int fr = tid >> 3;
    const int fk = (tid & 7) * 8;
    const int swz = (lane & 7) << 4;
    const int arow = wr * 64 + (lane & 15);
    const int brw  = wc * 64 + (lane & 15);
    const int klane = (lane >> 4) * 16;

    bool first = true;
#pragma unroll
    for (int term = 0; term < 3; ++term) {
        const int kaT = (term == 2) ? K : 0;
        const int kbT = (term == 1) ? K : 0;
        for (int kq = 0; kq < p.KQ; ++kq) {
            if (!first) __syncthreads();
            first = false;
            const int ka0 = kaT + kq * 64;
            const int kb0 = kbT + kq * 64;
#pragma unroll
            for (int l = 0; l < 4; ++l) {
                gload16(p.A  + (size_t)(brow + l * 32 + fr) * p.ars + ka0 + fk,
                        (char*)&As[0][0] + l * 4096 + tid * 16);
                gload16(p.Bt + (size_t)(bcol + l * 32 + fr) * p.brs + kb0 + fk,
                        (char*)&Bs[0][0] + l * 4096 + tid * 16);
            }
            __syncthreads();
#pragma unroll
            for (int kk = 0; kk < 2; ++kk) {
                const int kb = (kk * 64 + klane) ^ swz;
                short8v af[4], bfv[4];
#pragma unroll
                for (int mi = 0; mi < 4; mi++)
                    af[mi] = *(const short8v*)((const char*)&As[arow + mi * 16][0] + kb);
#pragma unroll
                for (int ni = 0; ni < 4; ni++)
                    bfv[ni] = *(const short8v*)((const char*)&Bs[brw + ni * 16][0] + kb);
#pragma unroll
                for (int mi = 0; mi < 4; mi++)
#pragma unroll
                    for (int ni = 0; ni < 4; ni++)
                        acc[mi][ni] = __builtin_amdgcn_mfma_f32_16x16x32_bf16(
                            af[mi], bfv[ni], acc[mi][ni], 0, 0, 0);
            }
        }
    }

#pragma unroll
    for (int mi = 0; mi < 4; mi++) {
#pragma unroll
        for (int q = 0; q < 4; q++) {
            int row = brow + wr * 64 + mi * 16 + (lane >> 4) * 4 + q;
            const int m = (row & 7) << 4;
            char* rp = (char*)(p.Cs + (size_t)row * p.crs);
#pragma unroll
            for (int ni = 0; ni < 4; ni++) {
                int col = bcol + wc * 64 + ni * 16 + (lane & 15);
                float v = acc[mi][ni][q] + p.bias[col];
                if (p.EPI != 3) v = fmaxf(v, 0.f);
                if (p.EPI & 1) p.C[(size_t)row * p.N + col] = v;
                if (p.EPI != 3) {
                    unsigned short hi = f2bf_rne(v);
                    int bh = col * 2;
                    *(unsigned short*)(rp + ((bh & ~127) | ((bh & 127) ^ m))) = hi;
                    if (p.EPI == 2) {
                        unsigned short lo = f2bf_rne(v - bf2f(hi));
                        int bl = (256 + col) * 2;
                        *(unsigned short*)(rp + ((bl & ~127) | ((bl & 127) ^ m))) = lo;
                    }
                }
            }
        }
    }
}

__global__ __launch_bounds__(256)
void mm_one(MMP p) {
    mm_device(p, blockIdx.x % p.gx, blockIdx.x / p.gx, threadIdx.x);
}

__global__ __launch_bounds__(256)
void mm_pair(MMP p0, MMP p1, int n0) {
    if ((int)blockIdx.x < n0) {
        mm_device(p0, blockIdx.x % p0.gx, blockIdx.x / p0.gx, threadIdx.x);
    } else {
        int b = blockIdx.x - n0;
        mm_device(p1, b % p1.gx, b / p1.gx, threadIdx.x);
    }
}

// ---------------------------------------------------------------------------
// VQ MFMA kernel (unchanged from round 9): hi-only bf16 d2-key GEMM (K=256),
// 128x256 tile, 512 threads, swapped-operand MFMA, u32-packed top-2.
// ---------------------------------------------------------------------------
__global__ __launch_bounds__(512)
void vq_mfma(const unsigned short* __restrict__ Ae,
             const unsigned short* __restrict__ Be,
             const float* __restrict__ c2,
             ulonglong2* __restrict__ part) {
    __shared__ __align__(16) unsigned short As[128][64];
    __shared__ __align__(16) unsigned short Bs[256][64];
    __shared__ u32 s1[128][4];
    __shared__ u32 s2[128][4];

    const int tid  = threadIdx.x;
    const int lane = tid & 63;
    const int wid  = tid >> 6;
    const int wr   = wid >> 2;
    const int wc   = wid & 3;
    const int brow = blockIdx.y * 128;
    const int bcol = blockIdx.x * 256;

    f32x4 acc[4][4] = {};

    const int fr = tid >> 3;
    const int fk = (tid & 7) * 8;
    const int swz   = (lane & 7) << 4;
    const int arow  = wr * 64 + (lane & 15);
    const int brw   = wc * 64 + (lane & 15);
    const int klane = (lane >> 4) * 16;

    for (int s = 0; s < 4; ++s) {
        const int k0 = s * 64;
        if (s) __syncthreads();
#pragma unroll
        for (int l = 0; l < 2; ++l)
            gload16(Ae + (size_t)(brow + l * 64 + fr) * 256 + k0 + fk,
                    (char*)&As[0][0] + l * 8192 + tid * 16);
#pragma unroll
        for (int l = 0; l < 4; ++l)
            gload16(Be + (size_t)(bcol + l * 64 + fr) * 512 + k0 + fk,
                    (char*)&Bs[0][0] + l * 8192 + tid * 16);
        __syncthreads();
#pragma unroll
        for (int kk = 0; kk < 2; ++kk) {
            const int kb = (kk * 64 + klane) ^ swz;
            short8v af[4], bfv[4];
#pragma unroll
            for (int mi = 0; mi < 4; mi++)
                af[mi] = *(const short8v*)((const char*)&As[arow + mi * 16][0] + kb);
#pragma unroll
            for (int ni = 0; ni < 4; ni++)
                bfv[ni] = *(const short8v*)((const char*)&Bs[brw + ni * 16][0] + kb);
#pragma unroll
            for (int mi = 0; mi < 4; mi++)
#pragma unroll
                for (int ni = 0; ni < 4; ni++)
                    acc[mi][ni] = __builtin_amdgcn_mfma_f32_16x16x32_bf16(
                        bfv[ni], af[mi], acc[mi][ni], 0, 0, 0);
        }
    }

    const int qrow = lane & 15;
    const int cq   = (lane >> 4) * 4;
    float4 c2q[4];
#pragma unroll
    for (int ni = 0; ni < 4; ni++)
        c2q[ni] = *(const float4*)&c2[bcol + wc * 64 + ni * 16 + cq];

#pragma unroll
    for (int mi = 0; mi < 4; mi++) {
        u32 b1 = 0xFFFFFFFFu, b2 = 0xFFFFFFFFu;
#pragma unroll
        for (int ni = 0; ni < 4; ni++) {
            const float* cp = (const float*)&c2q[ni];
#pragma unroll
            for (int r = 0; r < 4; r++) {
                float dk = fmaf(-2.0f, acc[mi][ni][r], cp[r]);
                dk = fmaxf(dk, 0.0f);
                u32 k = (__float_as_uint(dk) & ~255u)
                      | (u32)(wc * 64 + ni * 16 + cq + r);
                u32 mx = max(k, b1);
                b1 = min(k, b1);
                b2 = min(mx, b2);
            }
        }
#pragma unroll
        for (int off = 16; off < 64; off <<= 1) {
            u32 o1 = __shfl_xor(b1, off);
            u32 o2 = __shfl_xor(b2, off);
            u32 mx = max(b1, o1);
            b1 = min(b1, o1);
            b2 = min(min(b2, o2), mx);
        }
        if (lane < 16) {
            int rl = wr * 64 + mi * 16 + qrow;
            s1[rl][wc] = b1;
            s2[rl][wc] = b2;
        }
    }
    __syncthreads();
    if (tid < 128) {
        u32 b1 = s1[tid][0], b2 = s2[tid][0];
#pragma unroll
        for (int w = 1; w < 4; w++) {
            u32 c1 = s1[tid][w], cc2 = s2[tid][w];
            u32 mx = max(b1, c1);
            b1 = min(b1, c1);
            b2 = min(min(b2, cc2), mx);
        }
        ulonglong2 pk;
        pk.x = ((u64)b1 << 32) | (u32)(bcol + (b1 & 255u));
        pk.y = ((u64)b2 << 32) | (u32)(bcol + (b2 & 255u));
        part[(size_t)(brow + tid) * NCB + blockIdx.x] = pk;
    }
}

// ---------------------------------------------------------------------------
// combine (+outQ gather, free: lanes hold w1/w2) with optional fused dec2
// blocks appended after `ncomb` combine blocks.
// ---------------------------------------------------------------------------
__global__ __launch_bounds__(256)
void combine_dec2(const ulonglong2* __restrict__ part,
                  const float* __restrict__ enc,
                  const float* __restrict__ cw,
                  const float* __restrict__ c2,
                  float* __restrict__ outIdx,
                  float* __restrict__ outDist,
                  int* __restrict__ idx32,
                  float* __restrict__ outQ,
                  MMP pd, int ncomb) {
    if ((int)blockIdx.x >= ncomb) {
        int b = blockIdx.x - ncomb;
        mm_device(pd, b % pd.gx, b / pd.gx, threadIdx.x);
        return;
    }
    const int row  = blockIdx.x * 4 + (threadIdx.x >> 6);
    const int lane = threadIdx.x & 63;

    u64 b1 = ~0ull, b2 = ~0ull;
    if (lane < NCB) {
        ulonglong2 pk = part[(size_t)row * NCB + lane];
        b1 = pk.x; b2 = pk.y;
    }
#pragma unroll
    for (int off = 1; off < 64; off <<= 1) {
        u64 c1 = __shfl_xor(b1, off);
        u64 cc2 = __shfl_xor(b2, off);
        t2mrg(b1, b2, c1, cc2);
    }
    int j1 = (int)(b1 & 0xffffffffu);
    int j2 = (int)(b2 & 0xffffffffu);

    float4 e4 = ((const float4*)(enc + (size_t)row * 256))[lane];
    float4 w1 = ((const float4*)(cw + (size_t)j1 * 256))[lane];
    float4 w2 = ((const float4*)(cw + (size_t)j2 * 256))[lane];
    float s1 = fmaf(e4.x, w1.x, fmaf(e4.y, w1.y, fmaf(e4.z, w1.z, e4.w * w1.w)));
    float s2 = fmaf(e4.x, w2.x, fmaf(e4.y, w2.y, fmaf(e4.z, w2.z, e4.w * w2.w)));
    float sx = (e4.x * e4.x + e4.y * e4.y) + (e4.z * e4.z + e4.w * e4.w);
#pragma unroll
    for (int off = 1; off < 64; off <<= 1) {
        s1 += __shfl_xor(s1, off);
        s2 += __shfl_xor(s2, off);
        sx += __shfl_xor(sx, off);
    }
    float d1 = sqrtf(fmaxf(sx + c2[j1] - 2.0f * s1, 0.f));
    float d2 = sqrtf(fmaxf(sx + c2[j2] - 2.0f * s2, 0.f));
    float bd; int bi;
    if (lex_lt(d1, j1, d2, j2)) { bd = d1; bi = j1; }
    else                        { bd = d2; bi = j2; }
    float4 wq = (bi == j1) ? w1 : w2;
    ((float4*)(outQ + (size_t)row * ENC_DIM))[lane] = wq;
    if (lane == 0) {
        outIdx[row]  = (float)bi;
        outDist[row] = bd;
        idx32[row]   = bi;
    }
}

// ---------------------------------------------------------------------------
// Gather reconstructed rows (outRec only; outQ handled in combine).
// 4 rows per block.
// ---------------------------------------------------------------------------
__global__ void gather_rec(const int* __restrict__ idx32,
                           const float* __restrict__ rec_all,
                           float* __restrict__ outRec) {
    int row = blockIdx.x * 4 + (threadIdx.x >> 6);
    int lane = threadIdx.x & 63;
    int j = idx32[row];
    const float4* src = (const float4*)(rec_all + (size_t)j * IN_DIM);
    float4* dst = (float4*)(outRec + (size_t)row * IN_DIM);
#pragma unroll
    for (int i = 0; i < 4; i++) dst[lane + 64 * i] = src[lane + 64 * i];
}

extern "C" void kernel_launch(void* const* d_in, const int* in_sizes, int n_in,
                              void* d_out, int out_size, void* d_ws, size_t ws_size,
                              hipStream_t stream) {
    const float* x   = (const float*)d_in[0];
    const float* ew1 = (const float*)d_in[1];
    const float* eb1 = (const float*)d_in[2];
    const float* ew2 = (const float*)d_in[3];
    const float* eb2 = (const float*)d_in[4];
    const float* cw  = (const float*)d_in[5];
    const float* dw1 = (const float*)d_in[6];
    const float* db1 = (const float*)d_in[7];
    const float* dw2 = (const float*)d_in[8];
    const float* db2 = (const float*)d_in[9];
    float* out = (float*)d_out;
    float* ws  = (float*)d_ws;

    float* outIdx  = out;
    float* outDist = out + NROWS;
    float* outRec  = out + 2 * NROWS;
    float* outQ    = out + 2 * NROWS + (size_t)NROWS * IN_DIM;

    if (ws_size >= 95000000ull) {
        // big path. liveness: xs dead after enc1; Hs dead after megaB;
        // Gs/rec_all/part placed in dead regions only (audited per-launch).
        unsigned short* xs      = (unsigned short*)ws;              // [0,16.78M)
        unsigned short* Hs      = (unsigned short*)(ws + 16777216); // [.,20.97M)
        unsigned short* Be      = (unsigned short*)(ws + 20971520); // [.,23.07M)
        unsigned short* w1ts    = (unsigned short*)(ws + 23068672);
        unsigned short* ew2t    = (unsigned short*)(ws + 23330816);
        unsigned short* dw1t    = (unsigned short*)(ws + 23396352);
        unsigned short* dw2t    = (unsigned short*)(ws + 23461888);
        float*          c2      = ws + 23724032;
        int*            idx32   = (int*)(ws + 23732224);
        float*          enc     = ws;                               // [0,4.19M)
        unsigned short* Ae      = (unsigned short*)(ws + 4194304);  // [.,6.29M)
        unsigned short* Gs      = (unsigned short*)(ws + 6291456);  // [.,8.39M)
        ulonglong2*     part    = (ulonglong2*)(ws + 8388608);      // [.,10.49M)
        float*          rec_all = ws + 10485760;                    // [.,18.87M)

        MMP p_enc1 = { xs, w1ts, eb1, nullptr, Hs, 256, 2048, 2048, 512, 16, 2, 2 };
        MMP p_enc2 = { Hs, ew2t, eb2, enc, Ae, 256, 512, 512, 256, 4, 1, 2 };
        MMP p_dec1 = { Be, dw1t, db1, nullptr, Gs, 256, 512, 512, 512, 4, 2, 2 };
        MMP p_dec2 = { Gs, dw2t, db2, rec_all, nullptr, 1024, 512, 512, 0, 4, 3, 8 };

        prep_all<1><<<21120, 256, 0, stream>>>(ew1, ew2, dw1, dw2, cw, x,
                                               w1ts, ew2t, dw1t, dw2t, Be, c2, xs);
        mm_one<<<256, 256, 0, stream>>>(p_enc1);
        mm_pair<<<384, 256, 0, stream>>>(p_enc2, p_dec1, 256);
        vq_mfma<<<dim3(NCB, 128), 512, 0, stream>>>(Ae, Be, c2, part);
        combine_dec2<<<4096 + 512, 256, 0, stream>>>(part, enc, cw, c2,
                                                     outIdx, outDist, idx32, outQ,
                                                     p_dec2, 4096);
        gather_rec<<<NROWS / 4, 256, 0, stream>>>(idx32, rec_all, outRec);
    } else {
        // fallback: fully serial, round-9 proven layout (~61.5 MB)
        unsigned short* xs      = (unsigned short*)ws;
        float*          enc     = ws;
        float*          rec_all = ws;
        unsigned short* Ae      = (unsigned short*)(ws + 4194304);
        unsigned short* Hs      = (unsigned short*)(ws + 8388608);
        ulonglong2*     part    = (ulonglong2*)(ws + 8388608);
        unsigned short* Gs      = (unsigned short*)(ws + 8388608);
        unsigned short* Be      = (unsigned short*)(ws + 12582912);
        unsigned short* w1ts    = (unsigned short*)(ws + 14680064);
        unsigned short* ew2t    = (unsigned short*)(ws + 14942208);
        unsigned short* dw1t    = (unsigned short*)(ws + 15007744);
        unsigned short* dw2t    = (unsigned short*)(ws + 15073280);
        float*          c2      = ws + 15335424;
        int*            idx32   = (int*)(ws + 15343616);

        MMP p_enc1a = { xs, w1ts, eb1, nullptr, Hs, 256, 2048, 2048, 512, 16, 2, 2 };
        MMP p_enc1b = { xs, w1ts, eb1, nullptr, Hs + (size_t)8192 * 512,
                        256, 2048, 2048, 512, 16, 2, 2 };
        MMP p_enc2  = { Hs, ew2t, eb2, enc, Ae, 256, 512, 512, 256, 4, 1, 2 };
        MMP p_dec1  = { Be, dw1t, db1, nullptr, Gs, 256, 512, 512, 512, 4, 2, 2 };
        MMP p_dec2  = { Gs, dw2t, db2, rec_all, nullptr, 1024, 512, 512, 0, 4, 3, 8 };

        prep_all<0><<<4736, 256, 0, stream>>>(ew1, ew2, dw1, dw2, cw, x,
                                              w1ts, ew2t, dw1t, dw2t, Be, c2,
                                              nullptr);
        splitK<1024><<<8192, 256, 0, stream>>>(x, xs, 8192 * 256);
        mm_one<<<128, 256, 0, stream>>>(p_enc1a);
        splitK<1024><<<8192, 256, 0, stream>>>(x + (size_t)8192 * 1024, xs, 8192 * 256);
        mm_one<<<128, 256, 0, stream>>>(p_enc1b);
        mm_one<<<256, 256, 0, stream>>>(p_enc2);
        vq_mfma<<<dim3(NCB, 128), 512, 0, stream>>>(Ae, Be, c2, part);
        combine_dec2<<<4096, 256, 0, stream>>>(part, enc, cw, c2,
                                               outIdx, outDist, idx32, outQ,
                                               p_dec2, 4096);
        mm_one<<<128, 256, 0, stream>>>(p_dec1);
        mm_one<<<512, 256, 0, stream>>>(p_dec2);
        gather_rec<<<NROWS / 4, 256, 0, stream>>>(idx32, rec_all, outRec);
    }
}

// Round 11
// 237.300 us; speedup vs baseline: 5.0615x; 1.0353x over previous
//
#include <hip/hip_runtime.h>
#include <hip/hip_bf16.h>

#define NROWS   16384
#define IN_DIM  1024
#define ENC_DIM 256
#define KCW     8192
#define NCB     32          // codeword col-blocks of 256

typedef __attribute__((ext_vector_type(8))) short short8v;
typedef __attribute__((ext_vector_type(4))) float f32x4;
typedef unsigned long long u64;
typedef unsigned int u32;

// ---------------------------------------------------------------------------
// helpers
// ---------------------------------------------------------------------------
__device__ __forceinline__ unsigned short f2bf_rne(float x) {
    unsigned u = __float_as_uint(x);
    unsigned r = (u + 0x7fffu + ((u >> 16) & 1u)) >> 16;
    return (unsigned short)r;
}
__device__ __forceinline__ float bf2f(unsigned short h) {
    return __uint_as_float(((unsigned)h) << 16);
}
__device__ __forceinline__ int lex_lt(float d, int i, float D, int I) {
    return (d < D) || (d == D && i < I);
}
__device__ __forceinline__ void t2mrg(u64& b1, u64& b2, u64 c1, u64 c2) {
    u64 hi = (b1 > c1) ? b1 : c1;
    u64 lo2 = (b2 < c2) ? b2 : c2;
    b1 = (b1 < c1) ? b1 : c1;
    b2 = (hi < lo2) ? hi : lo2;
}
__device__ __forceinline__ void gload16(const void* g, void* l) {
    __builtin_amdgcn_global_load_lds(
        (__attribute__((address_space(1))) void*)g,
        (__attribute__((address_space(3))) void*)l, 16, 0, 0);
}

// ---------------------------------------------------------------------------
// prep bodies (weights + codewords only; x-split is fused into enc1 now)
// ---------------------------------------------------------------------------
template<int K>
__device__ __forceinline__ void split_body(const float* __restrict__ src,
                                           unsigned short* __restrict__ dst,
                                           int e) {
    int row = e / (K / 4), kq = (e % (K / 4)) * 4;
    float4 v = ((const float4*)src)[e];
    ushort4 hi, lo;
    hi.x = f2bf_rne(v.x); lo.x = f2bf_rne(v.x - bf2f(hi.x));
    hi.y = f2bf_rne(v.y); lo.y = f2bf_rne(v.y - bf2f(hi.y));
    hi.z = f2bf_rne(v.z); lo.z = f2bf_rne(v.z - bf2f(hi.z));
    hi.w = f2bf_rne(v.w); lo.w = f2bf_rne(v.w - bf2f(hi.w));
    const int m = (row & 7) << 4;
    char* rowp = (char*)(dst + (size_t)row * (2 * K));
    int bh = kq * 2, bl = (K + kq) * 2;
    *(ushort4*)(rowp + ((bh & ~127) | ((bh & 127) ^ m))) = hi;
    *(ushort4*)(rowp + ((bl & ~127) | ((bl & 127) ^ m))) = lo;
}

template<int K>
__device__ __forceinline__ void tsplit_body(const float* __restrict__ W,
                                            unsigned short* __restrict__ Wt,
                                            int Ncols, int idx) {
    int n = idx / (K / 4), k4 = (idx % (K / 4)) * 4;
    float vx = W[(size_t)(k4 + 0) * Ncols + n];
    float vy = W[(size_t)(k4 + 1) * Ncols + n];
    float vz = W[(size_t)(k4 + 2) * Ncols + n];
    float vw = W[(size_t)(k4 + 3) * Ncols + n];
    ushort4 hi, lo;
    hi.x = f2bf_rne(vx); lo.x = f2bf_rne(vx - bf2f(hi.x));
    hi.y = f2bf_rne(vy); lo.y = f2bf_rne(vy - bf2f(hi.y));
    hi.z = f2bf_rne(vz); lo.z = f2bf_rne(vz - bf2f(hi.z));
    hi.w = f2bf_rne(vw); lo.w = f2bf_rne(vw - bf2f(hi.w));
    const int m = (n & 7) << 4;
    char* rp = (char*)(Wt + (size_t)n * (2 * K));
    int bh = k4 * 2, bl = (K + k4) * 2;
    *(ushort4*)(rp + ((bh & ~127) | ((bh & 127) ^ m))) = hi;
    *(ushort4*)(rp + ((bl & ~127) | ((bl & 127) ^ m))) = lo;
}

__device__ __forceinline__ void rownorm_body(const float* __restrict__ A,
                                             float* __restrict__ out, int idx) {
    int wid = idx >> 6, lane = idx & 63;
    float4 v = *(const float4*)(A + (size_t)wid * 256 + lane * 4);
    float s = (v.x * v.x + v.y * v.y) + (v.z * v.z + v.w * v.w);
#pragma unroll
    for (int off = 1; off < 64; off <<= 1) s += __shfl_xor(s, off);
    if (lane == 0) out[wid] = s;
}

__global__ __launch_bounds__(256)
void prep_all(const float* __restrict__ ew1, const float* __restrict__ ew2,
              const float* __restrict__ dw1, const float* __restrict__ dw2,
              const float* __restrict__ cw,
              unsigned short* __restrict__ w1ts, unsigned short* __restrict__ ew2t,
              unsigned short* __restrict__ dw1t, unsigned short* __restrict__ dw2t,
              unsigned short* __restrict__ Be,   float* __restrict__ c2) {
    int idx = blockIdx.x * 256 + threadIdx.x;
    if (idx < 65536)        { tsplit_body<1024>(ew1, w1ts, 256, idx); }
    else if (idx < 81920)   { tsplit_body<256>(ew2, ew2t, 256, idx - 65536); }
    else if (idx < 98304)   { tsplit_body<256>(dw1, dw1t, 256, idx - 81920); }
    else if (idx < 163840)  { tsplit_body<256>(dw2, dw2t, 1024, idx - 98304); }
    else if (idx < 688128)  { split_body<256>(cw, Be, idx - 163840); }
    else if (idx < 1212416) { rownorm_body(cw, c2, idx - 688128); }
}

// ---------------------------------------------------------------------------
// 512-thread (8-wave) split-bf16 MFMA GEMM body. Tile 128x128, waves 2x4,
// per-wave output 64x32 (acc[4][2]). Accumulation order per output element
// identical to the 256t version -> bit-identical results.
// EPI: 1 = relu, C fp32 + Cs hi;  2 = relu, Cs hi+lo;  3 = no relu, C only.
// ---------------------------------------------------------------------------
struct MMP {
    const unsigned short* A;
    const unsigned short* Bt;
    const float* bias;
    float* C;
    unsigned short* Cs;
    int N, ars, brs, crs, KQ, EPI, gx;
};

__device__ void mm_device512(const MMP p, int bx, int by, int tid) {
    __shared__ __align__(16) unsigned short As[128][64];
    __shared__ __align__(16) unsigned short Bs[128][64];
    const int lane = tid & 63;
    const int wid = tid >> 6;
    const int wr = wid >> 2, wc = wid & 3;
    const int brow = by * 128;
    const int bcol = bx * 128;
    const int K = p.KQ * 64;

    f32x4 acc[4][2] = {};

    const int fr = tid >> 3;            // 0..63
    const int fk = (tid & 7) * 8;
    const int swz = (lane & 7) << 4;
    const int arow = wr * 64 + (lane & 15);
    const int brw  = wc * 32 + (lane & 15);
    const int klane = (lane >> 4) * 16;

    bool first = true;
#pragma unroll
    for (int term = 0; term < 3; ++term) {
        const int kaT = (term == 2) ? K : 0;
        const int kbT = (term == 1) ? K : 0;
        for (int kq = 0; kq < p.KQ; ++kq) {
            if (!first) __syncthreads();
            first = false;
            const int ka0 = kaT + kq * 64;
            const int kb0 = kbT + kq * 64;
#pragma unroll
            for (int l = 0; l < 2; ++l) {
                gload16(p.A  + (size_t)(brow + l * 64 + fr) * p.ars + ka0 + fk,
                        (char*)&As[0][0] + l * 8192 + tid * 16);
                gload16(p.Bt + (size_t)(bcol + l * 64 + fr) * p.brs + kb0 + fk,
                        (char*)&Bs[0][0] + l * 8192 + tid * 16);
            }
            __syncthreads();
#pragma unroll
            for (int kk = 0; kk < 2; ++kk) {
                const int kb = (kk * 64 + klane) ^ swz;
                short8v af[4], bfv[2];
#pragma unroll
                for (int mi = 0; mi < 4; mi++)
                    af[mi] = *(const short8v*)((const char*)&As[arow + mi * 16][0] + kb);
#pragma unroll
                for (int ni = 0; ni < 2; ni++)
                    bfv[ni] = *(const short8v*)((const char*)&Bs[brw + ni * 16][0] + kb);
#pragma unroll
                for (int mi = 0; mi < 4; mi++)
#pragma unroll
                    for (int ni = 0; ni < 2; ni++)
                        acc[mi][ni] = __builtin_amdgcn_mfma_f32_16x16x32_bf16(
                            af[mi], bfv[ni], acc[mi][ni], 0, 0, 0);
            }
        }
    }

#pragma unroll
    for (int mi = 0; mi < 4; mi++) {
#pragma unroll
        for (int q = 0; q < 4; q++) {
            int row = brow + wr * 64 + mi * 16 + (lane >> 4) * 4 + q;
            const int m = (row & 7) << 4;
            char* rp = (char*)(p.Cs + (size_t)row * p.crs);
#pragma unroll
            for (int ni = 0; ni < 2; ni++) {
                int col = bcol + wc * 32 + ni * 16 + (lane & 15);
                float v = acc[mi][ni][q] + p.bias[col];
                if (p.EPI != 3) v = fmaxf(v, 0.f);
                if (p.EPI & 1) p.C[(size_t)row * p.N + col] = v;
                if (p.EPI != 3) {
                    unsigned short hi = f2bf_rne(v);
                    int bh = col * 2;
                    *(unsigned short*)(rp + ((bh & ~127) | ((bh & 127) ^ m))) = hi;
                    if (p.EPI == 2) {
                        unsigned short lo = f2bf_rne(v - bf2f(hi));
                        int bl = (256 + col) * 2;
                        *(unsigned short*)(rp + ((bl & ~127) | ((bl & 127) ^ m))) = lo;
                    }
                }
            }
        }
    }
}

__global__ __launch_bounds__(512)
void mm_pair(MMP p0, MMP p1, int n0) {
    if ((int)blockIdx.x < n0) {
        mm_device512(p0, blockIdx.x % p0.gx, blockIdx.x / p0.gx, threadIdx.x);
    } else {
        int b = blockIdx.x - n0;
        mm_device512(p1, b % p1.gx, b / p1.gx, threadIdx.x);
    }
}

// ---------------------------------------------------------------------------
// enc1 with FUSED x-split: A staged from x fp32 in registers (convert to
// hi/lo bf16, ds_write to the same linear LDS slot gload16 would fill; the
// source-column inverse-swizzle mirrors split_body exactly). B = w1ts via
// global_load_lds. Epilogue: relu + swizzled hi|lo split into Hs (EPI=2).
// ---------------------------------------------------------------------------
__global__ __launch_bounds__(512)
void enc1_fused(const float* __restrict__ x,
                const unsigned short* __restrict__ w1ts,
                const float* __restrict__ bias,
                unsigned short* __restrict__ Hs) {
    __shared__ __align__(16) unsigned short As[128][64];
    __shared__ __align__(16) unsigned short Bs[128][64];
    const int tid = threadIdx.x;
    const int lane = tid & 63;
    const int wid = tid >> 6;
    const int wr = wid >> 2, wc = wid & 3;
    const int bx = blockIdx.x & 1, by = blockIdx.x >> 1;
    const int brow = by * 128;
    const int bcol = bx * 128;

    f32x4 acc[4][2] = {};

    const int fr = tid >> 3;
    const int fk = (tid & 7) * 8;
    const int swz = (lane & 7) << 4;
    const int arow = wr * 64 + (lane & 15);
    const int brw  = wc * 32 + (lane & 15);
    const int klane = (lane >> 4) * 16;

    for (int s = 0; s < 48; ++s) {
        const int term = s >> 4, kq = s & 15;
        const int ka0 = (term == 2 ? 1024 : 0) + kq * 64;
        const int kb0 = (term == 1 ? 1024 : 0) + kq * 64;
        const bool loreg = (term == 2);
        if (s) __syncthreads();
        // B: async global->LDS from pre-split weights
#pragma unroll
        for (int l = 0; l < 2; ++l)
            gload16(w1ts + (size_t)(bcol + l * 64 + fr) * 2048 + kb0 + fk,
                    (char*)&Bs[0][0] + l * 8192 + tid * 16);
        // A: reg-staged from x with in-flight split (inverse-swizzled source)
#pragma unroll
        for (int l = 0; l < 2; ++l) {
            int row = brow + l * 64 + fr;
            int b = (ka0 + fk) * 2;
            int sb = (b & ~127) | ((b & 127) ^ ((row & 7) << 4));
            int sc = (sb >> 1) - (loreg ? 1024 : 0);
            const float* xp = x + (size_t)row * 1024 + sc;
            float4 v0 = *(const float4*)xp;
            float4 v1 = *(const float4*)(xp + 4);
            float vv[8] = { v0.x, v0.y, v0.z, v0.w, v1.x, v1.y, v1.z, v1.w };
            short8v u;
#pragma unroll
            for (int i = 0; i < 8; i++) {
                unsigned short h = f2bf_rne(vv[i]);
                u[i] = (short)(loreg ? f2bf_rne(vv[i] - bf2f(h)) : h);
            }
            *(short8v*)((char*)&As[0][0] + l * 8192 + tid * 16) = u;
        }
        __syncthreads();
#pragma unroll
        for (int kk = 0; kk < 2; ++kk) {
            const int kb = (kk * 64 + klane) ^ swz;
            short8v af[4], bfv[2];
#pragma unroll
            for (int mi = 0; mi < 4; mi++)
                af[mi] = *(const short8v*)((const char*)&As[arow + mi * 16][0] + kb);
#pragma unroll
            for (int ni = 0; ni < 2; ni++)
                bfv[ni] = *(const short8v*)((const char*)&Bs[brw + ni * 16][0] + kb);
#pragma unroll
            for (int mi = 0; mi < 4; mi++)
#pragma unroll
                for (int ni = 0; ni < 2; ni++)
                    acc[mi][ni] = __builtin_amdgcn_mfma_f32_16x16x32_bf16(
                        af[mi], bfv[ni], acc[mi][ni], 0, 0, 0);
        }
    }

#pragma unroll
    for (int mi = 0; mi < 4; mi++) {
#pragma unroll
        for (int q = 0; q < 4; q++) {
            int row = brow + wr * 64 + mi * 16 + (lane >> 4) * 4 + q;
            const int m = (row & 7) << 4;
            char* rp = (char*)(Hs + (size_t)row * 512);
#pragma unroll
            for (int ni = 0; ni < 2; ni++) {
                int col = bcol + wc * 32 + ni * 16 + (lane & 15);
                float v = fmaxf(acc[mi][ni][q] + bias[col], 0.f);
                unsigned short hi = f2bf_rne(v);
                unsigned short lo = f2bf_rne(v - bf2f(hi));
                int bh = col * 2, bl = (256 + col) * 2;
                *(unsigned short*)(rp + ((bh & ~127) | ((bh & 127) ^ m))) = hi;
                *(unsigned short*)(rp + ((bl & ~127) | ((bl & 127) ^ m))) = lo;
            }
        }
    }
}

// ---------------------------------------------------------------------------
// VQ MFMA kernel (unchanged): hi-only bf16 d2-key GEMM (K=256), 128x256
// tile, 512 threads, swapped-operand MFMA, u32-packed top-2.
// ---------------------------------------------------------------------------
__global__ __launch_bounds__(512)
void vq_mfma(const unsigned short* __restrict__ Ae,
             const unsigned short* __restrict__ Be,
             const float* __restrict__ c2,
             ulonglong2* __restrict__ part) {
    __shared__ __align__(16) unsigned short As[128][64];
    __shared__ __align__(16) unsigned short Bs[256][64];
    __shared__ u32 s1[128][4];
    __shared__ u32 s2[128][4];

    const int tid  = threadIdx.x;
    const int lane = tid & 63;
    const int wid  = tid >> 6;
    const int wr   = wid >> 2;
    const int wc   = wid & 3;
    const int brow = blockIdx.y * 128;
    const int bcol = blockIdx.x * 256;

    f32x4 acc[4][4] = {};

    const int fr = tid >> 3;
    const int fk = (tid & 7) * 8;
    const int swz   = (lane & 7) << 4;
    const int arow  = wr * 64 + (lane & 15);
    const int brw   = wc * 64 + (lane & 15);
    const int klane = (lane >> 4) * 16;

    for (int s = 0; s < 4; ++s) {
        const int k0 = s * 64;
        if (s) __syncthreads();
#pragma unroll
        for (int l = 0; l < 2; ++l)
            gload16(Ae + (size_t)(brow + l * 64 + fr) * 256 + k0 + fk,
                    (char*)&As[0][0] + l * 8192 + tid * 16);
#pragma unroll
        for (int l = 0; l < 4; ++l)
            gload16(Be + (size_t)(bcol + l * 64 + fr) * 512 + k0 + fk,
                    (char*)&Bs[0][0] + l * 8192 + tid * 16);
        __syncthreads();
#pragma unroll
        for (int kk = 0; kk < 2; ++kk) {
            const int kb = (kk * 64 + klane) ^ swz;
            short8v af[4], bfv[4];
#pragma unroll
            for (int mi = 0; mi < 4; mi++)
                af[mi] = *(const short8v*)((const char*)&As[arow + mi * 16][0] + kb);
#pragma unroll
            for (int ni = 0; ni < 4; ni++)
                bfv[ni] = *(const short8v*)((const char*)&Bs[brw + ni * 16][0] + kb);
#pragma unroll
            for (int mi = 0; mi < 4; mi++)
#pragma unroll
                for (int ni = 0; ni < 4; ni++)
                    acc[mi][ni] = __builtin_amdgcn_mfma_f32_16x16x32_bf16(
                        bfv[ni], af[mi], acc[mi][ni], 0, 0, 0);
        }
    }

    const int qrow = lane & 15;
    const int cq   = (lane >> 4) * 4;
    float4 c2q[4];
#pragma unroll
    for (int ni = 0; ni < 4; ni++)
        c2q[ni] = *(const float4*)&c2[bcol + wc * 64 + ni * 16 + cq];

#pragma unroll
    for (int mi = 0; mi < 4; mi++) {
        u32 b1 = 0xFFFFFFFFu, b2 = 0xFFFFFFFFu;
#pragma unroll
        for (int ni = 0; ni < 4; ni++) {
            const float* cp = (const float*)&c2q[ni];
#pragma unroll
            for (int r = 0; r < 4; r++) {
                float dk = fmaf(-2.0f, acc[mi][ni][r], cp[r]);
                dk = fmaxf(dk, 0.0f);
                u32 k = (__float_as_uint(dk) & ~255u)
                      | (u32)(wc * 64 + ni * 16 + cq + r);
                u32 mx = max(k, b1);
                b1 = min(k, b1);
                b2 = min(mx, b2);
            }
        }
#pragma unroll
        for (int off = 16; off < 64; off <<= 1) {
            u32 o1 = __shfl_xor(b1, off);
            u32 o2 = __shfl_xor(b2, off);
            u32 mx = max(b1, o1);
            b1 = min(b1, o1);
            b2 = min(min(b2, o2), mx);
        }
        if (lane < 16) {
            int rl = wr * 64 + mi * 16 + qrow;
            s1[rl][wc] = b1;
            s2[rl][wc] = b2;
        }
    }
    __syncthreads();
    if (tid < 128) {
        u32 b1 = s1[tid][0], b2 = s2[tid][0];
#pragma unroll
        for (int w = 1; w < 4; w++) {
            u32 c1 = s1[tid][w], cc2 = s2[tid][w];
            u32 mx = max(b1, c1);
            b1 = min(b1, c1);
            b2 = min(min(b2, cc2), mx);
        }
        ulonglong2 pk;
        pk.x = ((u64)b1 << 32) | (u32)(bcol + (b1 & 255u));
        pk.y = ((u64)b2 << 32) | (u32)(bcol + (b2 & 255u));
        part[(size_t)(brow + tid) * NCB + blockIdx.x] = pk;
    }
}

// ---------------------------------------------------------------------------
// combine (8 rows/block, fused outQ + exact rescore) with dec2 blocks FIRST
// (blocks [0, nd2) run dec2 so the long pole starts immediately).
// ---------------------------------------------------------------------------
__global__ __launch_bounds__(512)
void combine_dec2(const ulonglong2* __restrict__ part,
                  const float* __restrict__ enc,
                  const float* __restrict__ cw,
                  const float* __restrict__ c2,
                  float* __restrict__ outIdx,
                  float* __restrict__ outDist,
                  int* __restrict__ idx32,
                  float* __restrict__ outQ,
                  MMP pd, int nd2) {
    if ((int)blockIdx.x < nd2) {
        mm_device512(pd, blockIdx.x % pd.gx, blockIdx.x / pd.gx, threadIdx.x);
        return;
    }
    const int row  = (blockIdx.x - nd2) * 8 + (threadIdx.x >> 6);
    const int lane = threadIdx.x & 63;

    u64 b1 = ~0ull, b2 = ~0ull;
    if (lane < NCB) {
        ulonglong2 pk = part[(size_t)row * NCB + lane];
        b1 = pk.x; b2 = pk.y;
    }
#pragma unroll
    for (int off = 1; off < 64; off <<= 1) {
        u64 c1 = __shfl_xor(b1, off);
        u64 cc2 = __shfl_xor(b2, off);
        t2mrg(b1, b2, c1, cc2);
    }
    int j1 = (int)(b1 & 0xffffffffu);
    int j2 = (int)(b2 & 0xffffffffu);

    float4 e4 = ((const float4*)(enc + (size_t)row * 256))[lane];
    float4 w1 = ((const float4*)(cw + (size_t)j1 * 256))[lane];
    float4 w2 = ((const float4*)(cw + (size_t)j2 * 256))[lane];
    float s1 = fmaf(e4.x, w1.x, fmaf(e4.y, w1.y, fmaf(e4.z, w1.z, e4.w * w1.w)));
    float s2 = fmaf(e4.x, w2.x, fmaf(e4.y, w2.y, fmaf(e4.z, w2.z, e4.w * w2.w)));
    float sx = (e4.x * e4.x + e4.y * e4.y) + (e4.z * e4.z + e4.w * e4.w);
#pragma unroll
    for (int off = 1; off < 64; off <<= 1) {
        s1 += __shfl_xor(s1, off);
        s2 += __shfl_xor(s2, off);
        sx += __shfl_xor(sx, off);
    }
    float d1 = sqrtf(fmaxf(sx + c2[j1] - 2.0f * s1, 0.f));
    float d2 = sqrtf(fmaxf(sx + c2[j2] - 2.0f * s2, 0.f));
    float bd; int bi;
    if (lex_lt(d1, j1, d2, j2)) { bd = d1; bi = j1; }
    else                        { bd = d2; bi = j2; }
    float4 wq = (bi == j1) ? w1 : w2;
    ((float4*)(outQ + (size_t)row * ENC_DIM))[lane] = wq;
    if (lane == 0) {
        outIdx[row]  = (float)bi;
        outDist[row] = bd;
        idx32[row]   = bi;
    }
}

// ---------------------------------------------------------------------------
// Gather reconstructed rows (outRec only). 4 rows per block.
// ---------------------------------------------------------------------------
__global__ void gather_rec(const int* __restrict__ idx32,
                           const float* __restrict__ rec_all,
                           float* __restrict__ outRec) {
    int row = blockIdx.x * 4 + (threadIdx.x >> 6);
    int lane = threadIdx.x & 63;
    int j = idx32[row];
    const float4* src = (const float4*)(rec_all + (size_t)j * IN_DIM);
    float4* dst = (float4*)(outRec + (size_t)row * IN_DIM);
#pragma unroll
    for (int i = 0; i < 4; i++) dst[lane + 64 * i] = src[lane + 64 * i];
}

extern "C" void kernel_launch(void* const* d_in, const int* in_sizes, int n_in,
                              void* d_out, int out_size, void* d_ws, size_t ws_size,
                              hipStream_t stream) {
    const float* x   = (const float*)d_in[0];
    const float* ew1 = (const float*)d_in[1];
    const float* eb1 = (const float*)d_in[2];
    const float* ew2 = (const float*)d_in[3];
    const float* eb2 = (const float*)d_in[4];
    const float* cw  = (const float*)d_in[5];
    const float* dw1 = (const float*)d_in[6];
    const float* db1 = (const float*)d_in[7];
    const float* dw2 = (const float*)d_in[8];
    const float* db2 = (const float*)d_in[9];
    float* out = (float*)d_out;
    float* ws  = (float*)d_ws;

    float* outIdx  = out;
    float* outDist = out + NROWS;
    float* outRec  = out + 2 * NROWS;
    float* outQ    = out + 2 * NROWS + (size_t)NROWS * IN_DIM;

    // unified layout (~86.6 MB; ws >= 95 MB confirmed rounds 8-10).
    // liveness: Hs (enc1->pair) aliased by part (vq+) and rec_all head
    // (combine_dec2+); all serial-launch ordered.
    float*          enc     = ws;                               // [0, 4.19M)
    unsigned short* Ae      = (unsigned short*)(ws + 4194304);  // [., 6.29M)
    unsigned short* Gs      = (unsigned short*)(ws + 6291456);  // [., 8.39M)
    unsigned short* Hs      = (unsigned short*)(ws + 8388608);  // [., 12.58M) dead after pair
    ulonglong2*     part    = (ulonglong2*)(ws + 8388608);      // [., 10.49M) vq+
    float*          rec_all = ws + 10485760;                    // [., 18.87M) combine+
    unsigned short* Be      = (unsigned short*)(ws + 18874368); // [., 20.97M)
    unsigned short* w1ts    = (unsigned short*)(ws + 20971520); // 1 MB
    unsigned short* ew2t    = (unsigned short*)(ws + 21233664);
    unsigned short* dw1t    = (unsigned short*)(ws + 21299200);
    unsigned short* dw2t    = (unsigned short*)(ws + 21364736);
    float*          c2      = ws + 21626880;
    int*            idx32   = (int*)(ws + 21635072);

    MMP p_enc2 = { Hs, ew2t, eb2, enc, Ae, 256, 512, 512, 256, 4, 1, 2 };
    MMP p_dec1 = { Be, dw1t, db1, nullptr, Gs, 256, 512, 512, 512, 4, 2, 2 };
    MMP p_dec2 = { Gs, dw2t, db2, rec_all, nullptr, 1024, 512, 512, 0, 4, 3, 8 };

    prep_all<<<4736, 256, 0, stream>>>(ew1, ew2, dw1, dw2, cw,
                                       w1ts, ew2t, dw1t, dw2t, Be, c2);
    enc1_fused<<<256, 512, 0, stream>>>(x, w1ts, eb1, Hs);
    mm_pair<<<384, 512, 0, stream>>>(p_enc2, p_dec1, 256);
    vq_mfma<<<dim3(NCB, 128), 512, 0, stream>>>(Ae, Be, c2, part);
    combine_dec2<<<512 + 2048, 512, 0, stream>>>(part, enc, cw, c2,
                                                 outIdx, outDist, idx32, outQ,
                                                 p_dec2, 512);
    gather_rec<<<NROWS / 4, 256, 0, stream>>>(idx32, rec_all, outRec);
}

// Round 12
// 194.583 us; speedup vs baseline: 6.1727x; 1.2195x over previous
//
#include <hip/hip_runtime.h>
#include <hip/hip_bf16.h>

#define NROWS   16384
#define IN_DIM  1024
#define ENC_DIM 256
#define KCW     8192
#define NCB     32          // codeword col-blocks of 256

typedef __attribute__((ext_vector_type(8))) short short8v;
typedef __attribute__((ext_vector_type(4))) float f32x4;
typedef unsigned long long u64;
typedef unsigned int u32;

// ---------------------------------------------------------------------------
// helpers
// ---------------------------------------------------------------------------
__device__ __forceinline__ unsigned short f2bf_rne(float x) {
    unsigned u = __float_as_uint(x);
    unsigned r = (u + 0x7fffu + ((u >> 16) & 1u)) >> 16;
    return (unsigned short)r;
}
__device__ __forceinline__ float bf2f(unsigned short h) {
    return __uint_as_float(((unsigned)h) << 16);
}
__device__ __forceinline__ int lex_lt(float d, int i, float D, int I) {
    return (d < D) || (d == D && i < I);
}
__device__ __forceinline__ void t2mrg(u64& b1, u64& b2, u64 c1, u64 c2) {
    u64 hi = (b1 > c1) ? b1 : c1;
    u64 lo2 = (b2 < c2) ? b2 : c2;
    b1 = (b1 < c1) ? b1 : c1;
    b2 = (hi < lo2) ? hi : lo2;
}
__device__ __forceinline__ void gload16(const void* g, void* l) {
    __builtin_amdgcn_global_load_lds(
        (__attribute__((address_space(1))) void*)g,
        (__attribute__((address_space(3))) void*)l, 16, 0, 0);
}

// ---------------------------------------------------------------------------
// prep bodies (weights + codewords only)
// ---------------------------------------------------------------------------
template<int K>
__device__ __forceinline__ void split_body(const float* __restrict__ src,
                                           unsigned short* __restrict__ dst,
                                           int e) {
    int row = e / (K / 4), kq = (e % (K / 4)) * 4;
    float4 v = ((const float4*)src)[e];
    ushort4 hi, lo;
    hi.x = f2bf_rne(v.x); lo.x = f2bf_rne(v.x - bf2f(hi.x));
    hi.y = f2bf_rne(v.y); lo.y = f2bf_rne(v.y - bf2f(hi.y));
    hi.z = f2bf_rne(v.z); lo.z = f2bf_rne(v.z - bf2f(hi.z));
    hi.w = f2bf_rne(v.w); lo.w = f2bf_rne(v.w - bf2f(hi.w));
    const int m = (row & 7) << 4;
    char* rowp = (char*)(dst + (size_t)row * (2 * K));
    int bh = kq * 2, bl = (K + kq) * 2;
    *(ushort4*)(rowp + ((bh & ~127) | ((bh & 127) ^ m))) = hi;
    *(ushort4*)(rowp + ((bl & ~127) | ((bl & 127) ^ m))) = lo;
}

template<int K>
__device__ __forceinline__ void tsplit_body(const float* __restrict__ W,
                                            unsigned short* __restrict__ Wt,
                                            int Ncols, int idx) {
    int n = idx / (K / 4), k4 = (idx % (K / 4)) * 4;
    float vx = W[(size_t)(k4 + 0) * Ncols + n];
    float vy = W[(size_t)(k4 + 1) * Ncols + n];
    float vz = W[(size_t)(k4 + 2) * Ncols + n];
    float vw = W[(size_t)(k4 + 3) * Ncols + n];
    ushort4 hi, lo;
    hi.x = f2bf_rne(vx); lo.x = f2bf_rne(vx - bf2f(hi.x));
    hi.y = f2bf_rne(vy); lo.y = f2bf_rne(vy - bf2f(hi.y));
    hi.z = f2bf_rne(vz); lo.z = f2bf_rne(vz - bf2f(hi.z));
    hi.w = f2bf_rne(vw); lo.w = f2bf_rne(vw - bf2f(hi.w));
    const int m = (n & 7) << 4;
    char* rp = (char*)(Wt + (size_t)n * (2 * K));
    int bh = k4 * 2, bl = (K + k4) * 2;
    *(ushort4*)(rp + ((bh & ~127) | ((bh & 127) ^ m))) = hi;
    *(ushort4*)(rp + ((bl & ~127) | ((bl & 127) ^ m))) = lo;
}

__device__ __forceinline__ void rownorm_body(const float* __restrict__ A,
                                             float* __restrict__ out, int idx) {
    int wid = idx >> 6, lane = idx & 63;
    float4 v = *(const float4*)(A + (size_t)wid * 256 + lane * 4);
    float s = (v.x * v.x + v.y * v.y) + (v.z * v.z + v.w * v.w);
#pragma unroll
    for (int off = 1; off < 64; off <<= 1) s += __shfl_xor(s, off);
    if (lane == 0) out[wid] = s;
}

__global__ __launch_bounds__(256)
void prep_all(const float* __restrict__ ew1, const float* __restrict__ ew2,
              const float* __restrict__ dw1, const float* __restrict__ dw2,
              const float* __restrict__ cw,
              unsigned short* __restrict__ w1ts, unsigned short* __restrict__ ew2t,
              unsigned short* __restrict__ dw1t, unsigned short* __restrict__ dw2t,
              unsigned short* __restrict__ Be,   float* __restrict__ c2) {
    int idx = blockIdx.x * 256 + threadIdx.x;
    if (idx < 65536)        { tsplit_body<1024>(ew1, w1ts, 256, idx); }
    else if (idx < 81920)   { tsplit_body<256>(ew2, ew2t, 256, idx - 65536); }
    else if (idx < 98304)   { tsplit_body<256>(dw1, dw1t, 256, idx - 81920); }
    else if (idx < 163840)  { tsplit_body<256>(dw2, dw2t, 1024, idx - 98304); }
    else if (idx < 688128)  { split_body<256>(cw, Be, idx - 163840); }
    else if (idx < 1212416) { rownorm_body(cw, c2, idx - 688128); }
}

// ---------------------------------------------------------------------------
// 512-thread (8-wave) split-bf16 MFMA GEMM body. Tile 128x128, waves 2x4,
// per-wave output 64x32 (acc[4][2]).
// EPI: 1 = relu, C fp32 + Cs hi;  2 = relu, Cs hi+lo;  3 = no relu, C only.
// ---------------------------------------------------------------------------
struct MMP {
    const unsigned short* A;
    const unsigned short* Bt;
    const float* bias;
    float* C;
    unsigned short* Cs;
    int N, ars, brs, crs, KQ, EPI, gx;
};

__device__ void mm_device512(const MMP p, int bx, int by, int tid) {
    __shared__ __align__(16) unsigned short As[128][64];
    __shared__ __align__(16) unsigned short Bs[128][64];
    const int lane = tid & 63;
    const int wid = tid >> 6;
    const int wr = wid >> 2, wc = wid & 3;
    const int brow = by * 128;
    const int bcol = bx * 128;
    const int K = p.KQ * 64;

    f32x4 acc[4][2] = {};

    const int fr = tid >> 3;
    const int fk = (tid & 7) * 8;
    const int swz = (lane & 7) << 4;
    const int arow = wr * 64 + (lane & 15);
    const int brw  = wc * 32 + (lane & 15);
    const int klane = (lane >> 4) * 16;

    bool first = true;
#pragma unroll
    for (int term = 0; term < 3; ++term) {
        const int kaT = (term == 2) ? K : 0;
        const int kbT = (term == 1) ? K : 0;
        for (int kq = 0; kq < p.KQ; ++kq) {
            if (!first) __syncthreads();
            first = false;
            const int ka0 = kaT + kq * 64;
            const int kb0 = kbT + kq * 64;
#pragma unroll
            for (int l = 0; l < 2; ++l) {
                gload16(p.A  + (size_t)(brow + l * 64 + fr) * p.ars + ka0 + fk,
                        (char*)&As[0][0] + l * 8192 + tid * 16);
                gload16(p.Bt + (size_t)(bcol + l * 64 + fr) * p.brs + kb0 + fk,
                        (char*)&Bs[0][0] + l * 8192 + tid * 16);
            }
            __syncthreads();
#pragma unroll
            for (int kk = 0; kk < 2; ++kk) {
                const int kb = (kk * 64 + klane) ^ swz;
                short8v af[4], bfv[2];
#pragma unroll
                for (int mi = 0; mi < 4; mi++)
                    af[mi] = *(const short8v*)((const char*)&As[arow + mi * 16][0] + kb);
#pragma unroll
                for (int ni = 0; ni < 2; ni++)
                    bfv[ni] = *(const short8v*)((const char*)&Bs[brw + ni * 16][0] + kb);
#pragma unroll
                for (int mi = 0; mi < 4; mi++)
#pragma unroll
                    for (int ni = 0; ni < 2; ni++)
                        acc[mi][ni] = __builtin_amdgcn_mfma_f32_16x16x32_bf16(
                            af[mi], bfv[ni], acc[mi][ni], 0, 0, 0);
            }
        }
    }

#pragma unroll
    for (int mi = 0; mi < 4; mi++) {
#pragma unroll
        for (int q = 0; q < 4; q++) {
            int row = brow + wr * 64 + mi * 16 + (lane >> 4) * 4 + q;
            const int m = (row & 7) << 4;
            char* rp = (char*)(p.Cs + (size_t)row * p.crs);
#pragma unroll
            for (int ni = 0; ni < 2; ni++) {
                int col = bcol + wc * 32 + ni * 16 + (lane & 15);
                float v = acc[mi][ni][q] + p.bias[col];
                if (p.EPI != 3) v = fmaxf(v, 0.f);
                if (p.EPI & 1) p.C[(size_t)row * p.N + col] = v;
                if (p.EPI != 3) {
                    unsigned short hi = f2bf_rne(v);
                    int bh = col * 2;
                    *(unsigned short*)(rp + ((bh & ~127) | ((bh & 127) ^ m))) = hi;
                    if (p.EPI == 2) {
                        unsigned short lo = f2bf_rne(v - bf2f(hi));
                        int bl = (256 + col) * 2;
                        *(unsigned short*)(rp + ((bl & ~127) | ((bl & 127) ^ m))) = lo;
                    }
                }
            }
        }
    }
}

__global__ __launch_bounds__(512)
void mm_pair(MMP p0, MMP p1, int n0) {
    if ((int)blockIdx.x < n0) {
        mm_device512(p0, blockIdx.x % p0.gx, blockIdx.x / p0.gx, threadIdx.x);
    } else {
        int b = blockIdx.x - n0;
        mm_device512(p1, b % p1.gx, b / p1.gx, threadIdx.x);
    }
}

// ---------------------------------------------------------------------------
// enc1 v2: SINGLE PASS over x. Tile 64 rows x 256 cols (full N), K=1024 in
// 16 steps of 64, ALL 3 split-terms interleaved per k-step:
//   acc += Ah*Bh + Ah*Bl + Al*Bh
// A hi/lo computed in-register from one x read, ds_written to the
// XOR-swizzled slot (write-side swizzle is free). B hi/lo via gload16 from
// pre-split w1ts (1 MB, L2-resident). x FETCH = 64 MB exactly once.
// ---------------------------------------------------------------------------
__global__ __launch_bounds__(512)
void enc1_fused(const float* __restrict__ x,
                const unsigned short* __restrict__ w1ts,
                const float* __restrict__ bias,
                unsigned short* __restrict__ Hs) {
    __shared__ __align__(16) unsigned short Ah[64][64];
    __shared__ __align__(16) unsigned short Al[64][64];
    __shared__ __align__(16) unsigned short Bh[256][64];
    __shared__ __align__(16) unsigned short Bl[256][64];
    const int tid = threadIdx.x;
    const int lane = tid & 63;
    const int wid = tid >> 6;
    const int wr = wid >> 2, wc = wid & 3;    // wr: row half, wc: col quarter
    const int brow = blockIdx.x * 64;

    f32x4 acc[2][4] = {};

    const int fr = tid >> 3;                  // 0..63 (row within tile)
    const int fk = (tid & 7) * 8;             // 0..56 (k within 64-chunk)
    const int swz = (lane & 7) << 4;
    const int arow = wr * 32 + (lane & 15);
    const int brw  = wc * 64 + (lane & 15);
    const int klane = (lane >> 4) * 16;
    const int aoff = fr * 128 + ((fk * 2) ^ ((fr & 7) << 4));

    float4 c0, c1, n0, n1;
    {
        const float* xp = x + (size_t)(brow + fr) * 1024 + fk;
        c0 = *(const float4*)xp; c1 = *(const float4*)(xp + 4);
    }

    for (int s = 0; s < 16; ++s) {
        const int k0 = s * 64;
        if (s) __syncthreads();
        // A: in-register hi/lo split, swizzled ds_write
        {
            float vv[8] = { c0.x, c0.y, c0.z, c0.w, c1.x, c1.y, c1.z, c1.w };
            short8v uh, ul;
#pragma unroll
            for (int i = 0; i < 8; i++) {
                unsigned short h = f2bf_rne(vv[i]);
                uh[i] = (short)h;
                ul[i] = (short)f2bf_rne(vv[i] - bf2f(h));
            }
            *(short8v*)((char*)&Ah[0][0] + aoff) = uh;
            *(short8v*)((char*)&Al[0][0] + aoff) = ul;
        }
        // B: async global->LDS, hi and lo sections (both pre-swizzled)
#pragma unroll
        for (int l = 0; l < 4; ++l) {
            gload16(w1ts + (size_t)(l * 64 + fr) * 2048 + k0 + fk,
                    (char*)&Bh[0][0] + l * 8192 + tid * 16);
            gload16(w1ts + (size_t)(l * 64 + fr) * 2048 + 1024 + k0 + fk,
                    (char*)&Bl[0][0] + l * 8192 + tid * 16);
        }
        // prefetch next x chunk (overlaps with B loads)
        if (s + 1 < 16) {
            const float* xp = x + (size_t)(brow + fr) * 1024 + k0 + 64 + fk;
            n0 = *(const float4*)xp; n1 = *(const float4*)(xp + 4);
        }
        __syncthreads();
#pragma unroll
        for (int kk = 0; kk < 2; ++kk) {
            const int kb = (kk * 64 + klane) ^ swz;
            short8v ah[2], al[2], bh[4], bl[4];
#pragma unroll
            for (int mi = 0; mi < 2; mi++) {
                ah[mi] = *(const short8v*)((const char*)&Ah[arow + mi * 16][0] + kb);
                al[mi] = *(const short8v*)((const char*)&Al[arow + mi * 16][0] + kb);
            }
#pragma unroll
            for (int ni = 0; ni < 4; ni++) {
                bh[ni] = *(const short8v*)((const char*)&Bh[brw + ni * 16][0] + kb);
                bl[ni] = *(const short8v*)((const char*)&Bl[brw + ni * 16][0] + kb);
            }
#pragma unroll
            for (int mi = 0; mi < 2; mi++)
#pragma unroll
                for (int ni = 0; ni < 4; ni++) {
                    acc[mi][ni] = __builtin_amdgcn_mfma_f32_16x16x32_bf16(
                        ah[mi], bh[ni], acc[mi][ni], 0, 0, 0);
                    acc[mi][ni] = __builtin_amdgcn_mfma_f32_16x16x32_bf16(
                        ah[mi], bl[ni], acc[mi][ni], 0, 0, 0);
                    acc[mi][ni] = __builtin_amdgcn_mfma_f32_16x16x32_bf16(
                        al[mi], bh[ni], acc[mi][ni], 0, 0, 0);
                }
        }
        c0 = n0; c1 = n1;
    }

    // epilogue: relu + swizzled hi|lo split into Hs
#pragma unroll
    for (int mi = 0; mi < 2; mi++) {
#pragma unroll
        for (int q = 0; q < 4; q++) {
            int row = brow + wr * 32 + mi * 16 + (lane >> 4) * 4 + q;
            const int m = (row & 7) << 4;
            char* rp = (char*)(Hs + (size_t)row * 512);
#pragma unroll
            for (int ni = 0; ni < 4; ni++) {
                int col = wc * 64 + ni * 16 + (lane & 15);
                float v = fmaxf(acc[mi][ni][q] + bias[col], 0.f);
                unsigned short hi = f2bf_rne(v);
                unsigned short lo = f2bf_rne(v - bf2f(hi));
                int bh_ = col * 2, bl_ = (256 + col) * 2;
                *(unsigned short*)(rp + ((bh_ & ~127) | ((bh_ & 127) ^ m))) = hi;
                *(unsigned short*)(rp + ((bl_ & ~127) | ((bl_ & 127) ^ m))) = lo;
            }
        }
    }
}

// ---------------------------------------------------------------------------
// VQ MFMA kernel (unchanged): hi-only bf16 d2-key GEMM (K=256), 128x256
// tile, 512 threads, swapped-operand MFMA, u32-packed top-2.
// ---------------------------------------------------------------------------
__global__ __launch_bounds__(512)
void vq_mfma(const unsigned short* __restrict__ Ae,
             const unsigned short* __restrict__ Be,
             const float* __restrict__ c2,
             ulonglong2* __restrict__ part) {
    __shared__ __align__(16) unsigned short As[128][64];
    __shared__ __align__(16) unsigned short Bs[256][64];
    __shared__ u32 s1[128][4];
    __shared__ u32 s2[128][4];

    const int tid  = threadIdx.x;
    const int lane = tid & 63;
    const int wid  = tid >> 6;
    const int wr   = wid >> 2;
    const int wc   = wid & 3;
    const int brow = blockIdx.y * 128;
    const int bcol = blockIdx.x * 256;

    f32x4 acc[4][4] = {};

    const int fr = tid >> 3;
    const int fk = (tid & 7) * 8;
    const int swz   = (lane & 7) << 4;
    const int arow  = wr * 64 + (lane & 15);
    const int brw   = wc * 64 + (lane & 15);
    const int klane = (lane >> 4) * 16;

    for (int s = 0; s < 4; ++s) {
        const int k0 = s * 64;
        if (s) __syncthreads();
#pragma unroll
        for (int l = 0; l < 2; ++l)
            gload16(Ae + (size_t)(brow + l * 64 + fr) * 256 + k0 + fk,
                    (char*)&As[0][0] + l * 8192 + tid * 16);
#pragma unroll
        for (int l = 0; l < 4; ++l)
            gload16(Be + (size_t)(bcol + l * 64 + fr) * 512 + k0 + fk,
                    (char*)&Bs[0][0] + l * 8192 + tid * 16);
        __syncthreads();
#pragma unroll
        for (int kk = 0; kk < 2; ++kk) {
            const int kb = (kk * 64 + klane) ^ swz;
            short8v af[4], bfv[4];
#pragma unroll
            for (int mi = 0; mi < 4; mi++)
                af[mi] = *(const short8v*)((const char*)&As[arow + mi * 16][0] + kb);
#pragma unroll
            for (int ni = 0; ni < 4; ni++)
                bfv[ni] = *(const short8v*)((const char*)&Bs[brw + ni * 16][0] + kb);
#pragma unroll
            for (int mi = 0; mi < 4; mi++)
#pragma unroll
                for (int ni = 0; ni < 4; ni++)
                    acc[mi][ni] = __builtin_amdgcn_mfma_f32_16x16x32_bf16(
                        bfv[ni], af[mi], acc[mi][ni], 0, 0, 0);
        }
    }

    const int qrow = lane & 15;
    const int cq   = (lane >> 4) * 4;
    float4 c2q[4];
#pragma unroll
    for (int ni = 0; ni < 4; ni++)
        c2q[ni] = *(const float4*)&c2[bcol + wc * 64 + ni * 16 + cq];

#pragma unroll
    for (int mi = 0; mi < 4; mi++) {
        u32 b1 = 0xFFFFFFFFu, b2 = 0xFFFFFFFFu;
#pragma unroll
        for (int ni = 0; ni < 4; ni++) {
            const float* cp = (const float*)&c2q[ni];
#pragma unroll
            for (int r = 0; r < 4; r++) {
                float dk = fmaf(-2.0f, acc[mi][ni][r], cp[r]);
                dk = fmaxf(dk, 0.0f);
                u32 k = (__float_as_uint(dk) & ~255u)
                      | (u32)(wc * 64 + ni * 16 + cq + r);
                u32 mx = max(k, b1);
                b1 = min(k, b1);
                b2 = min(mx, b2);
            }
        }
#pragma unroll
        for (int off = 16; off < 64; off <<= 1) {
            u32 o1 = __shfl_xor(b1, off);
            u32 o2 = __shfl_xor(b2, off);
            u32 mx = max(b1, o1);
            b1 = min(b1, o1);
            b2 = min(min(b2, o2), mx);
        }
        if (lane < 16) {
            int rl = wr * 64 + mi * 16 + qrow;
            s1[rl][wc] = b1;
            s2[rl][wc] = b2;
        }
    }
    __syncthreads();
    if (tid < 128) {
        u32 b1 = s1[tid][0], b2 = s2[tid][0];
#pragma unroll
        for (int w = 1; w < 4; w++) {
            u32 c1 = s1[tid][w], cc2 = s2[tid][w];
            u32 mx = max(b1, c1);
            b1 = min(b1, c1);
            b2 = min(min(b2, cc2), mx);
        }
        ulonglong2 pk;
        pk.x = ((u64)b1 << 32) | (u32)(bcol + (b1 & 255u));
        pk.y = ((u64)b2 << 32) | (u32)(bcol + (b2 & 255u));
        part[(size_t)(brow + tid) * NCB + blockIdx.x] = pk;
    }
}

// ---------------------------------------------------------------------------
// combine (8 rows/block, fused outQ + exact rescore) with dec2 blocks FIRST.
// ---------------------------------------------------------------------------
__global__ __launch_bounds__(512)
void combine_dec2(const ulonglong2* __restrict__ part,
                  const float* __restrict__ enc,
                  const float* __restrict__ cw,
                  const float* __restrict__ c2,
                  float* __restrict__ outIdx,
                  float* __restrict__ outDist,
                  int* __restrict__ idx32,
                  float* __restrict__ outQ,
                  MMP pd, int nd2) {
    if ((int)blockIdx.x < nd2) {
        mm_device512(pd, blockIdx.x % pd.gx, blockIdx.x / pd.gx, threadIdx.x);
        return;
    }
    const int row  = (blockIdx.x - nd2) * 8 + (threadIdx.x >> 6);
    const int lane = threadIdx.x & 63;

    u64 b1 = ~0ull, b2 = ~0ull;
    if (lane < NCB) {
        ulonglong2 pk = part[(size_t)row * NCB + lane];
        b1 = pk.x; b2 = pk.y;
    }
#pragma unroll
    for (int off = 1; off < 64; off <<= 1) {
        u64 c1 = __shfl_xor(b1, off);
        u64 cc2 = __shfl_xor(b2, off);
        t2mrg(b1, b2, c1, cc2);
    }
    int j1 = (int)(b1 & 0xffffffffu);
    int j2 = (int)(b2 & 0xffffffffu);

    float4 e4 = ((const float4*)(enc + (size_t)row * 256))[lane];
    float4 w1 = ((const float4*)(cw + (size_t)j1 * 256))[lane];
    float4 w2 = ((const float4*)(cw + (size_t)j2 * 256))[lane];
    float s1 = fmaf(e4.x, w1.x, fmaf(e4.y, w1.y, fmaf(e4.z, w1.z, e4.w * w1.w)));
    float s2 = fmaf(e4.x, w2.x, fmaf(e4.y, w2.y, fmaf(e4.z, w2.z, e4.w * w2.w)));
    float sx = (e4.x * e4.x + e4.y * e4.y) + (e4.z * e4.z + e4.w * e4.w);
#pragma unroll
    for (int off = 1; off < 64; off <<= 1) {
        s1 += __shfl_xor(s1, off);
        s2 += __shfl_xor(s2, off);
        sx += __shfl_xor(sx, off);
    }
    float d1 = sqrtf(fmaxf(sx + c2[j1] - 2.0f * s1, 0.f));
    float d2 = sqrtf(fmaxf(sx + c2[j2] - 2.0f * s2, 0.f));
    float bd; int bi;
    if (lex_lt(d1, j1, d2, j2)) { bd = d1; bi = j1; }
    else                        { bd = d2; bi = j2; }
    float4 wq = (bi == j1) ? w1 : w2;
    ((float4*)(outQ + (size_t)row * ENC_DIM))[lane] = wq;
    if (lane == 0) {
        outIdx[row]  = (float)bi;
        outDist[row] = bd;
        idx32[row]   = bi;
    }
}

// ---------------------------------------------------------------------------
// Gather reconstructed rows (outRec only). 4 rows per block.
// ---------------------------------------------------------------------------
__global__ void gather_rec(const int* __restrict__ idx32,
                           const float* __restrict__ rec_all,
                           float* __restrict__ outRec) {
    int row = blockIdx.x * 4 + (threadIdx.x >> 6);
    int lane = threadIdx.x & 63;
    int j = idx32[row];
    const float4* src = (const float4*)(rec_all + (size_t)j * IN_DIM);
    float4* dst = (float4*)(outRec + (size_t)row * IN_DIM);
#pragma unroll
    for (int i = 0; i < 4; i++) dst[lane + 64 * i] = src[lane + 64 * i];
}

extern "C" void kernel_launch(void* const* d_in, const int* in_sizes, int n_in,
                              void* d_out, int out_size, void* d_ws, size_t ws_size,
                              hipStream_t stream) {
    const float* x   = (const float*)d_in[0];
    const float* ew1 = (const float*)d_in[1];
    const float* eb1 = (const float*)d_in[2];
    const float* ew2 = (const float*)d_in[3];
    const float* eb2 = (const float*)d_in[4];
    const float* cw  = (const float*)d_in[5];
    const float* dw1 = (const float*)d_in[6];
    const float* db1 = (const float*)d_in[7];
    const float* dw2 = (const float*)d_in[8];
    const float* db2 = (const float*)d_in[9];
    float* out = (float*)d_out;
    float* ws  = (float*)d_ws;

    float* outIdx  = out;
    float* outDist = out + NROWS;
    float* outRec  = out + 2 * NROWS;
    float* outQ    = out + 2 * NROWS + (size_t)NROWS * IN_DIM;

    // layout (~21.7M floats used). liveness: Hs (enc1->pair) aliased by
    // part (vq+) and rec_all head (combine_dec2+); serial-launch ordered.
    float*          enc     = ws;                               // [0, 4.19M)
    unsigned short* Ae      = (unsigned short*)(ws + 4194304);  // [., 6.29M)
    unsigned short* Gs      = (unsigned short*)(ws + 6291456);  // [., 8.39M)
    unsigned short* Hs      = (unsigned short*)(ws + 8388608);  // [., 12.58M) dead after pair
    ulonglong2*     part    = (ulonglong2*)(ws + 8388608);      // [., 10.49M) vq+
    float*          rec_all = ws + 10485760;                    // [., 18.87M) combine+
    unsigned short* Be      = (unsigned short*)(ws + 18874368); // [., 20.97M)
    unsigned short* w1ts    = (unsigned short*)(ws + 20971520); // 1 MB
    unsigned short* ew2t    = (unsigned short*)(ws + 21233664);
    unsigned short* dw1t    = (unsigned short*)(ws + 21299200);
    unsigned short* dw2t    = (unsigned short*)(ws + 21364736);
    float*          c2      = ws + 21626880;
    int*            idx32   = (int*)(ws + 21635072);

    MMP p_enc2 = { Hs, ew2t, eb2, enc, Ae, 256, 512, 512, 256, 4, 1, 2 };
    MMP p_dec1 = { Be, dw1t, db1, nullptr, Gs, 256, 512, 512, 512, 4, 2, 2 };
    MMP p_dec2 = { Gs, dw2t, db2, rec_all, nullptr, 1024, 512, 512, 0, 4, 3, 8 };

    prep_all<<<4736, 256, 0, stream>>>(ew1, ew2, dw1, dw2, cw,
                                       w1ts, ew2t, dw1t, dw2t, Be, c2);
    enc1_fused<<<256, 512, 0, stream>>>(x, w1ts, eb1, Hs);
    mm_pair<<<384, 512, 0, stream>>>(p_enc2, p_dec1, 256);
    vq_mfma<<<dim3(NCB, 128), 512, 0, stream>>>(Ae, Be, c2, part);
    combine_dec2<<<512 + 2048, 512, 0, stream>>>(part, enc, cw, c2,
                                                 outIdx, outDist, idx32, outQ,
                                                 p_dec2, 512);
    gather_rec<<<NROWS / 4, 256, 0, stream>>>(idx32, rec_all, outRec);
}